// Round 1
// baseline (8018.703 us; speedup 1.0000x reference)
//
#include <hip/hip_runtime.h>

#define HD 128

constexpr int N_ATOMS = 20000;
constexpr int N_EDGES = 320000;
constexpr int NLAY   = 4;
constexpr int NMOL   = 200;
constexpr float FCUT  = 5.0f;
constexpr float DELTA = FCUT / 127.0f;
constexpr float GCOEFF = -0.5f / (DELTA * DELTA);
constexpr float PI_F  = 3.14159265358979323846f;
constexpr float LN2F  = 0.6931471805599453f;

__device__ __forceinline__ float sspf(float x) {
  // softplus(x) - log(2), numerically stable
  return fmaxf(x, 0.0f) + log1pf(expf(-fabsf(x))) - LN2F;
}
__device__ __forceinline__ float sigmf(float x) {
  return 1.0f / (1.0f + expf(-x));
}

// ------------------------------------------------------------------
// small elementwise kernels
// ------------------------------------------------------------------

__global__ __launch_bounds__(256) void geom_k(
    const float* __restrict__ pos, const int* __restrict__ row,
    const int* __restrict__ col, float* __restrict__ dist,
    float* __restrict__ ccut)
{
  int e = blockIdx.x * 256 + threadIdx.x;
  if (e >= N_EDGES) return;
  int r = row[e], c = col[e];
  float dx = pos[3*r+0] - pos[3*c+0];
  float dy = pos[3*r+1] - pos[3*c+1];
  float dz = pos[3*r+2] - pos[3*c+2];
  float d = sqrtf(dx*dx + dy*dy + dz*dz);
  dist[e] = d;
  ccut[e] = 0.5f * cosf(d * (PI_F / FCUT)) + 0.5f;
}

__global__ __launch_bounds__(256) void h0_k(
    const float* __restrict__ emb, const int* __restrict__ z,
    float* __restrict__ h0)
{
  int i = blockIdx.x * 256 + threadIdx.x;
  if (i >= N_ATOMS * HD) return;
  int n = i >> 7, k = i & 127;
  h0[i] = emb[z[n] * HD + k];
}

__global__ __launch_bounds__(256) void abuild_k(
    const float* __restrict__ dist, float* __restrict__ Ab, int ce, int e0)
{
  int i = blockIdx.x * 256 + threadIdx.x;
  if (i >= ce * HD) return;
  int le = i >> 7, g = i & 127;
  float t = dist[e0 + le] - (float)g * DELTA;
  Ab[i] = expf(GCOEFF * t * t);
}

// ------------------------------------------------------------------
// generic fp32 GEMM: C[M,128] = epi( op_a(A)[M,128] @ B(^T) + bias )
// MODE_A: 0 plain load, 1 ssp(A) on load
// EPI:    0: acc+bias   1: acc+bias+EP1   2: acc*sigmoid(EP1)
// BT:     B accessed as B[ncol][k] (transposed use)
// ------------------------------------------------------------------
template<int MODE_A, int EPI, bool BT>
__global__ __launch_bounds__(256) void gemm128_k(
    const float* __restrict__ A, const float* __restrict__ B,
    const float* __restrict__ bias, const float* __restrict__ EP1,
    float* __restrict__ C, int M)
{
  __shared__ float As[16][68];
  __shared__ float Bs[16][132];
  int t = threadIdx.x;
  int tx = t & 15, ty = t >> 4;
  int m0 = blockIdx.x * 64;

  float acc[4][8];
#pragma unroll
  for (int r = 0; r < 4; r++)
#pragma unroll
    for (int c = 0; c < 8; c++) acc[r][c] = 0.0f;

  for (int k0 = 0; k0 < HD; k0 += 16) {
    // A tile (transposed into LDS): 64 rows x 16 k
    {
      int rrow = t >> 2;
      int kg = (t & 3) * 4;
      int gm = m0 + rrow;
      float4 av = make_float4(0.f, 0.f, 0.f, 0.f);
      if (gm < M) av = *(const float4*)(A + (size_t)gm * HD + k0 + kg);
      if (MODE_A == 1) { av.x = sspf(av.x); av.y = sspf(av.y); av.z = sspf(av.z); av.w = sspf(av.w); }
      As[kg+0][rrow] = av.x; As[kg+1][rrow] = av.y;
      As[kg+2][rrow] = av.z; As[kg+3][rrow] = av.w;
    }
    // B tile: 16 k x 128 n
    if (!BT) {
#pragma unroll
      for (int it = 0; it < 2; it++) {
        int f4 = t + it * 256;          // 0..511
        int kk = f4 >> 5;
        int n4 = (f4 & 31) * 4;
        float4 bv = *(const float4*)(B + (size_t)(k0 + kk) * HD + n4);
        *(float4*)&Bs[kk][n4] = bv;
      }
    } else {
#pragma unroll
      for (int it = 0; it < 2; it++) {
        int idx = t + it * 256;         // 0..511
        int n = idx >> 2;
        int kg = (idx & 3) * 4;
        float4 bv = *(const float4*)(B + (size_t)n * HD + k0 + kg);
        Bs[kg+0][n] = bv.x; Bs[kg+1][n] = bv.y;
        Bs[kg+2][n] = bv.z; Bs[kg+3][n] = bv.w;
      }
    }
    __syncthreads();
#pragma unroll
    for (int kk = 0; kk < 16; kk++) {
      float a[4], b[8];
#pragma unroll
      for (int r = 0; r < 4; r++) a[r] = As[kk][ty * 4 + r];
#pragma unroll
      for (int c = 0; c < 8; c++) b[c] = Bs[kk][tx * 8 + c];
#pragma unroll
      for (int r = 0; r < 4; r++)
#pragma unroll
        for (int c = 0; c < 8; c++) acc[r][c] = fmaf(a[r], b[c], acc[r][c]);
    }
    __syncthreads();
  }

  int n0 = tx * 8;
  float bv[8];
#pragma unroll
  for (int c = 0; c < 8; c++) bv[c] = bias ? bias[n0 + c] : 0.0f;
#pragma unroll
  for (int r = 0; r < 4; r++) {
    int gm = m0 + ty * 4 + r;
    if (gm >= M) continue;
    float out[8];
#pragma unroll
    for (int c = 0; c < 8; c++) {
      float x = acc[r][c] + bv[c];
      if (EPI == 1) x += EP1[(size_t)gm * HD + n0 + c];
      if (EPI == 2) x = acc[r][c] * sigmf(EP1[(size_t)gm * HD + n0 + c]);
      out[c] = x;
    }
    *(float4*)(C + (size_t)gm * HD + n0)     = *(float4*)&out[0];
    *(float4*)(C + (size_t)gm * HD + n0 + 4) = *(float4*)&out[4];
  }
}

// ------------------------------------------------------------------
// dd[e0+m] += sum_g (sum_j dt1[m][j] * w1[g][j]) * A[m][g] * 2*GCOEFF*(d-off_g)
// ------------------------------------------------------------------
__global__ __launch_bounds__(256) void ddreduce_k(
    const float* __restrict__ dt1, const float* __restrict__ w1,
    const float* __restrict__ Ab, const float* __restrict__ dist,
    float* __restrict__ dd, int M, int e0)
{
  __shared__ float As[16][68];
  __shared__ float Bs[16][132];
  __shared__ float red[64][17];
  int t = threadIdx.x;
  int tx = t & 15, ty = t >> 4;
  int m0 = blockIdx.x * 64;

  float acc[4][8];
#pragma unroll
  for (int r = 0; r < 4; r++)
#pragma unroll
    for (int c = 0; c < 8; c++) acc[r][c] = 0.0f;

  for (int k0 = 0; k0 < HD; k0 += 16) {
    {
      int rrow = t >> 2;
      int kg = (t & 3) * 4;
      int gm = m0 + rrow;
      float4 av = make_float4(0.f, 0.f, 0.f, 0.f);
      if (gm < M) av = *(const float4*)(dt1 + (size_t)gm * HD + k0 + kg);
      As[kg+0][rrow] = av.x; As[kg+1][rrow] = av.y;
      As[kg+2][rrow] = av.z; As[kg+3][rrow] = av.w;
    }
#pragma unroll
    for (int it = 0; it < 2; it++) {
      int idx = t + it * 256;
      int n = idx >> 2;
      int kg = (idx & 3) * 4;
      float4 bvv = *(const float4*)(w1 + (size_t)n * HD + k0 + kg);  // w1[g][j], BT
      Bs[kg+0][n] = bvv.x; Bs[kg+1][n] = bvv.y;
      Bs[kg+2][n] = bvv.z; Bs[kg+3][n] = bvv.w;
    }
    __syncthreads();
#pragma unroll
    for (int kk = 0; kk < 16; kk++) {
      float a[4], b[8];
#pragma unroll
      for (int r = 0; r < 4; r++) a[r] = As[kk][ty * 4 + r];
#pragma unroll
      for (int c = 0; c < 8; c++) b[c] = Bs[kk][tx * 8 + c];
#pragma unroll
      for (int r = 0; r < 4; r++)
#pragma unroll
        for (int c = 0; c < 8; c++) acc[r][c] = fmaf(a[r], b[c], acc[r][c]);
    }
    __syncthreads();
  }

  int n0 = tx * 8;
#pragma unroll
  for (int r = 0; r < 4; r++) {
    int gm = m0 + ty * 4 + r;
    float p = 0.0f;
    if (gm < M) {
      float d = dist[e0 + gm];
#pragma unroll
      for (int c = 0; c < 8; c++) {
        int g = n0 + c;
        float w = Ab[(size_t)gm * HD + g] * (2.0f * GCOEFF * (d - (float)g * DELTA));
        p += acc[r][c] * w;
      }
    }
    red[ty * 4 + r][tx] = p;
  }
  __syncthreads();
  if (t < 64) {
    float s = 0.0f;
#pragma unroll
    for (int j = 0; j < 16; j++) s += red[t][j];
    int gm = m0 + t;
    if (gm < M) dd[e0 + gm] += s;
  }
}

// ------------------------------------------------------------------
// forward message scatter: agg[col] += hx[row] * Wpre * Ccut
// ------------------------------------------------------------------
__global__ __launch_bounds__(256) void scatter_fwd_k(
    const int* __restrict__ row, const int* __restrict__ col,
    const float* __restrict__ hx, const float* __restrict__ Wpre,
    const float* __restrict__ ccut, float* __restrict__ agg, int ce, int e0)
{
  int el = blockIdx.x * 4 + (threadIdx.x >> 6);
  int lane = threadIdx.x & 63;
  if (el >= ce) return;
  int e = e0 + el;
  int r = row[e], c = col[e];
  float cc = ccut[e];
#pragma unroll
  for (int it = 0; it < 2; it++) {
    int h = lane + it * 64;
    float v = hx[(size_t)r * HD + h] * Wpre[(size_t)el * HD + h] * cc;
    atomicAdd(&agg[(size_t)c * HD + h], v);
  }
}

// ------------------------------------------------------------------
// backward edge pass: dW (=dWpre), dhx scatter, Ccut-path dd contribution
// ------------------------------------------------------------------
__global__ __launch_bounds__(256) void edgegrad_k(
    const int* __restrict__ row, const int* __restrict__ col,
    const float* __restrict__ dagg, const float* __restrict__ hx,
    const float* __restrict__ Wpre, const float* __restrict__ ccut,
    const float* __restrict__ dist, float* __restrict__ dW,
    float* __restrict__ dhx, float* __restrict__ dd, int ce, int e0)
{
  int el = blockIdx.x * 4 + (threadIdx.x >> 6);
  int lane = threadIdx.x & 63;
  if (el >= ce) return;
  int e = e0 + el;
  int r = row[e], c = col[e];
  float cc = ccut[e];
  float dot = 0.0f;
#pragma unroll
  for (int it = 0; it < 2; it++) {
    int h = lane + it * 64;
    float dm = dagg[(size_t)c * HD + h];
    float wp = Wpre[(size_t)el * HD + h];
    float dwf = dm * hx[(size_t)r * HD + h];
    atomicAdd(&dhx[(size_t)r * HD + h], dm * wp * cc);
    dW[(size_t)el * HD + h] = dwf * cc;
    dot += dwf * wp;
  }
#pragma unroll
  for (int off = 32; off > 0; off >>= 1) dot += __shfl_down(dot, off, 64);
  if (lane == 0) {
    float d = dist[e];
    float dccut = -0.5f * sinf(d * (PI_F / FCUT)) * (PI_F / FCUT);
    dd[e] += dot * dccut;
  }
}

// ------------------------------------------------------------------
// head: energy accumulate + dL/dh4 init   (one block of 128 per atom)
// ------------------------------------------------------------------
__global__ __launch_bounds__(128) void head_k(
    const float* __restrict__ h4, const float* __restrict__ w1,
    const float* __restrict__ b1, const float* __restrict__ w2,
    const float* __restrict__ b2, const int* __restrict__ batch,
    float* __restrict__ energy, float* __restrict__ gh)
{
  __shared__ float hsh[128];
  __shared__ float csh[64];
  __shared__ float psh[64];
  int n = blockIdx.x;
  int t = threadIdx.x;
  hsh[t] = h4[(size_t)n * HD + t];
  __syncthreads();
  if (t < 64) {
    float s = b1[t];
    for (int k = 0; k < 128; k++) s = fmaf(hsh[k], w1[k * 64 + t], s);
    float w2v = w2[t];
    psh[t] = sspf(s) * w2v;
    csh[t] = sigmf(s) * w2v;
  }
  __syncthreads();
  if (t == 0) {
    float s = b2[0];
    for (int j = 0; j < 64; j++) s += psh[j];
    atomicAdd(&energy[batch[n]], s);
  }
  float g = 0.0f;
  for (int j = 0; j < 64; j++) g = fmaf(csh[j], w1[t * 64 + j], g);
  gh[(size_t)n * HD + t] = g;
}

// ------------------------------------------------------------------
// final force scatter: force[row] -= dd*u ; force[col] += dd*u
// ------------------------------------------------------------------
__global__ __launch_bounds__(256) void force_k(
    const int* __restrict__ row, const int* __restrict__ col,
    const float* __restrict__ pos, const float* __restrict__ dist,
    const float* __restrict__ dd, float* __restrict__ force)
{
  int e = blockIdx.x * 256 + threadIdx.x;
  if (e >= N_EDGES) return;
  int r = row[e], c = col[e];
  float inv = dd[e] / dist[e];
  float fx = (pos[3*r+0] - pos[3*c+0]) * inv;
  float fy = (pos[3*r+1] - pos[3*c+1]) * inv;
  float fz = (pos[3*r+2] - pos[3*c+2]) * inv;
  atomicAdd(&force[3*r+0], -fx);
  atomicAdd(&force[3*r+1], -fy);
  atomicAdd(&force[3*r+2], -fz);
  atomicAdd(&force[3*c+0],  fx);
  atomicAdd(&force[3*c+1],  fy);
  atomicAdd(&force[3*c+2],  fz);
}

// ------------------------------------------------------------------
// host launch
// ------------------------------------------------------------------
static inline int nblk(int m) { return (m + 63) / 64; }

extern "C" void kernel_launch(void* const* d_in, const int* in_sizes, int n_in,
                              void* d_out, int out_size, void* d_ws, size_t ws_size,
                              hipStream_t stream)
{
  const float* pos   = (const float*)d_in[0];
  const int*   z     = (const int*)d_in[1];
  const int*   batch = (const int*)d_in[2];
  const int*   eidx  = (const int*)d_in[3];
  const float* emb   = (const float*)d_in[4];
  const float* mlp_w1 = (const float*)d_in[5];
  const float* mlp_b1 = (const float*)d_in[6];
  const float* mlp_w2 = (const float*)d_in[7];
  const float* mlp_b2 = (const float*)d_in[8];
  const float* lin1_w = (const float*)d_in[9];
  const float* lin2_w = (const float*)d_in[10];
  const float* lin2_b = (const float*)d_in[11];
  const float* blk_w  = (const float*)d_in[12];
  const float* blk_b  = (const float*)d_in[13];
  const float* hw1 = (const float*)d_in[14];
  const float* hb1 = (const float*)d_in[15];
  const float* hw2 = (const float*)d_in[16];
  const float* hb2 = (const float*)d_in[17];

  float* out = (float*)d_out;          // [NMOL] energies ++ [N,3] forces
  float* ws  = (float*)d_ws;

  const int* row = eidx;
  const int* col = eidx + N_EDGES;

  const size_t NH = (size_t)N_ATOMS * HD;
  size_t o = 0;
  float* dist = ws + o; o += N_EDGES;
  float* ccut = ws + o; o += N_EDGES;
  float* dd   = ws + o; o += N_EDGES;
  float* hbuf[5];
  for (int i = 0; i < 5; i++) { hbuf[i] = ws + o; o += NH; }
  float* vbuf[4];
  for (int i = 0; i < 4; i++) { vbuf[i] = ws + o; o += NH; }
  float* hx   = ws + o; o += NH;
  float* agg  = ws + o; o += NH;
  float* gh0  = ws + o; o += NH;
  float* gh1  = ws + o; o += NH;
  float* dvb  = ws + o; o += NH;
  float* dgb  = ws + o; o += NH;
  float* dhxb = ws + o; o += NH;

  // adaptive edge-chunk size from remaining workspace (4 buffers x CE x 128 fl)
  long long avail = (long long)(ws_size / 4) - (long long)o;
  long long cemax = avail / (4 * HD);
  if (cemax > N_EDGES) cemax = N_EDGES;
  cemax &= ~63LL;
  if (cemax < 64) cemax = 64;
  const int CE = (int)cemax;
  float* Ab   = ws + o; o += (size_t)CE * HD;
  float* t1p  = ws + o; o += (size_t)CE * HD;
  float* wpre = ws + o; o += (size_t)CE * HD;
  float* dWb  = ws + o; o += (size_t)CE * HD;

  hipMemsetAsync(dd, 0, N_EDGES * sizeof(float), stream);
  hipMemsetAsync(out, 0, (size_t)(NMOL + 3 * N_ATOMS) * sizeof(float), stream);

  geom_k<<<(N_EDGES + 255) / 256, 256, 0, stream>>>(pos, row, col, dist, ccut);
  h0_k<<<(N_ATOMS * HD + 255) / 256, 256, 0, stream>>>(emb, z, hbuf[0]);

  // ---------------- forward ----------------
  for (int i = 0; i < NLAY; i++) {
    const float* w1 = mlp_w1 + (size_t)i * HD * HD;
    const float* b1 = mlp_b1 + (size_t)i * HD;
    const float* w2 = mlp_w2 + (size_t)i * HD * HD;
    const float* b2 = mlp_b2 + (size_t)i * HD;
    const float* l1 = lin1_w + (size_t)i * HD * HD;
    const float* l2 = lin2_w + (size_t)i * HD * HD;
    const float* l2b = lin2_b + (size_t)i * HD;
    const float* bw = blk_w + (size_t)i * HD * HD;
    const float* bb = blk_b + (size_t)i * HD;

    gemm128_k<0,0,false><<<nblk(N_ATOMS), 256, 0, stream>>>(hbuf[i], l1, nullptr, nullptr, hx, N_ATOMS);
    hipMemsetAsync(agg, 0, NH * sizeof(float), stream);
    for (int e0 = 0; e0 < N_EDGES; e0 += CE) {
      int ce = (N_EDGES - e0 < CE) ? (N_EDGES - e0) : CE;
      abuild_k<<<((size_t)ce * HD + 255) / 256, 256, 0, stream>>>(dist, Ab, ce, e0);
      gemm128_k<0,0,false><<<nblk(ce), 256, 0, stream>>>(Ab, w1, b1, nullptr, t1p, ce);
      gemm128_k<1,0,false><<<nblk(ce), 256, 0, stream>>>(t1p, w2, b2, nullptr, wpre, ce);
      scatter_fwd_k<<<(ce + 3) / 4, 256, 0, stream>>>(row, col, hx, wpre, ccut, agg, ce, e0);
    }
    gemm128_k<0,0,false><<<nblk(N_ATOMS), 256, 0, stream>>>(agg, l2, l2b, nullptr, vbuf[i], N_ATOMS);
    gemm128_k<1,1,false><<<nblk(N_ATOMS), 256, 0, stream>>>(vbuf[i], bw, bb, hbuf[i], hbuf[i+1], N_ATOMS);
  }

  head_k<<<N_ATOMS, 128, 0, stream>>>(hbuf[4], hw1, hb1, hw2, hb2, batch, out, gh0);

  // ---------------- backward ----------------
  float* g  = gh0;
  float* gn = gh1;
  for (int i = NLAY - 1; i >= 0; i--) {
    const float* w1 = mlp_w1 + (size_t)i * HD * HD;
    const float* b1 = mlp_b1 + (size_t)i * HD;
    const float* w2 = mlp_w2 + (size_t)i * HD * HD;
    const float* b2 = mlp_b2 + (size_t)i * HD;
    const float* l1 = lin1_w + (size_t)i * HD * HD;
    const float* l2 = lin2_w + (size_t)i * HD * HD;
    const float* bw = blk_w + (size_t)i * HD * HD;

    // dv = (g @ bw^T) * sigmoid(v_i)
    gemm128_k<0,2,true><<<nblk(N_ATOMS), 256, 0, stream>>>(g, bw, nullptr, vbuf[i], dvb, N_ATOMS);
    // dagg = dv @ l2^T
    gemm128_k<0,0,true><<<nblk(N_ATOMS), 256, 0, stream>>>(dvb, l2, nullptr, nullptr, dgb, N_ATOMS);
    // recompute hx_i = h_i @ l1
    gemm128_k<0,0,false><<<nblk(N_ATOMS), 256, 0, stream>>>(hbuf[i], l1, nullptr, nullptr, hx, N_ATOMS);
    hipMemsetAsync(dhxb, 0, NH * sizeof(float), stream);

    for (int e0 = 0; e0 < N_EDGES; e0 += CE) {
      int ce = (N_EDGES - e0 < CE) ? (N_EDGES - e0) : CE;
      abuild_k<<<((size_t)ce * HD + 255) / 256, 256, 0, stream>>>(dist, Ab, ce, e0);
      gemm128_k<0,0,false><<<nblk(ce), 256, 0, stream>>>(Ab, w1, b1, nullptr, t1p, ce);
      gemm128_k<1,0,false><<<nblk(ce), 256, 0, stream>>>(t1p, w2, b2, nullptr, wpre, ce);
      edgegrad_k<<<(ce + 3) / 4, 256, 0, stream>>>(row, col, dgb, hx, wpre, ccut, dist, dWb, dhxb, dd, ce, e0);
      // dt1 = (dW @ w2^T) * sigmoid(t1p)  -> stored into wpre buffer
      gemm128_k<0,2,true><<<nblk(ce), 256, 0, stream>>>(dWb, w2, nullptr, t1p, wpre, ce);
      ddreduce_k<<<nblk(ce), 256, 0, stream>>>(wpre, w1, Ab, dist, dd, ce, e0);
    }
    if (i > 0) {
      // dh_i = g + dhx @ l1^T
      gemm128_k<0,1,true><<<nblk(N_ATOMS), 256, 0, stream>>>(dhxb, l1, nullptr, g, gn, N_ATOMS);
      float* tmp = g; g = gn; gn = tmp;
    }
  }

  force_k<<<(N_EDGES + 255) / 256, 256, 0, stream>>>(row, col, pos, dist, dd, out + NMOL);
}

// Round 2
// 3095.928 us; speedup vs baseline: 2.5901x; 2.5901x over previous
//
#include <hip/hip_runtime.h>

#define HD 128

constexpr int N_ATOMS = 20000;
constexpr int N_EDGES = 320000;
constexpr int NLAY   = 4;
constexpr int NMOL   = 200;
constexpr float FCUT  = 5.0f;
constexpr float DELTA = FCUT / 127.0f;
constexpr float GCOEFF = -0.5f / (DELTA * DELTA);
constexpr float PI_F  = 3.14159265358979323846f;
constexpr float LN2F  = 0.6931471805599453f;

__device__ __forceinline__ float sspf(float x) {
  return fmaxf(x, 0.0f) + log1pf(expf(-fabsf(x))) - LN2F;
}
__device__ __forceinline__ float sigmf(float x) {
  return 1.0f / (1.0f + expf(-x));
}

// ------------------------------------------------------------------
// small elementwise kernels
// ------------------------------------------------------------------

__global__ __launch_bounds__(256) void geom_k(
    const float* __restrict__ pos, const int* __restrict__ row,
    const int* __restrict__ col, float* __restrict__ dist)
{
  int e = blockIdx.x * 256 + threadIdx.x;
  if (e >= N_EDGES) return;
  int r = row[e], c = col[e];
  float dx = pos[3*r+0] - pos[3*c+0];
  float dy = pos[3*r+1] - pos[3*c+1];
  float dz = pos[3*r+2] - pos[3*c+2];
  dist[e] = sqrtf(dx*dx + dy*dy + dz*dz);
}

__global__ __launch_bounds__(256) void h0_k(
    const float* __restrict__ emb, const int* __restrict__ z,
    float* __restrict__ h0)
{
  int i = blockIdx.x * 256 + threadIdx.x;
  if (i >= N_ATOMS * HD) return;
  int n = i >> 7, k = i & 127;
  h0[i] = emb[z[n] * HD + k];
}

// ------------------------------------------------------------------
// table build: node gaussians A, dA
// ------------------------------------------------------------------
__global__ __launch_bounds__(256) void nodeA_k(
    float* __restrict__ A, float* __restrict__ dA, int nnode, float hstep)
{
  int i = blockIdx.x * 256 + threadIdx.x;
  if (i >= nnode * HD) return;
  int node = i >> 7, g = i & 127;
  float d = (float)node * hstep;
  float t = d - (float)g * DELTA;
  float a = expf(GCOEFF * t * t);
  A[i] = a;
  dA[i] = a * 2.0f * GCOEFF * t;
}

// s = ssp(t1), sp = sigm(t1)*u      (over 4 layers contiguously)
__global__ __launch_bounds__(256) void nodeact_k(
    const float* __restrict__ t1, const float* __restrict__ u,
    float* __restrict__ s, float* __restrict__ sp, int total)
{
  int i = blockIdx.x * 256 + threadIdx.x;
  if (i >= total) return;
  float x = t1[i];
  s[i] = sspf(x);
  sp[i] = sigmf(x) * u[i];
}

// T[l][node][ch] = { P0*C , D0*C + P0*C' }  interleaved float2
__global__ __launch_bounds__(256) void nodecomb_k(
    const float* __restrict__ P0, const float* __restrict__ D0,
    float* __restrict__ T, int nnode, float hstep)
{
  int i = blockIdx.x * 256 + threadIdx.x;
  int total = NLAY * nnode * HD;
  if (i >= total) return;
  int rem = i % (nnode * HD);
  int node = rem >> 7;
  float d = (float)node * hstep;
  float C  = 0.5f * cosf(d * (PI_F / FCUT)) + 0.5f;
  float Cp = -0.5f * sinf(d * (PI_F / FCUT)) * (PI_F / FCUT);
  float p = P0[i], q = D0[i];
  T[(size_t)i * 2 + 0] = p * C;
  T[(size_t)i * 2 + 1] = q * C + p * Cp;
}

// ------------------------------------------------------------------
// generic fp32 GEMM: C[M,128] = epi( op_a(A)[M,128] @ B(^T) + bias )
// MODE_A: 0 plain, 1 ssp(A) on load
// EPI:    0: acc+bias   1: acc+bias+EP1   2: acc*sigmoid(EP1)
// BT:     B accessed as B[ncol][k]
// ------------------------------------------------------------------
template<int MODE_A, int EPI, bool BT>
__global__ __launch_bounds__(256) void gemm128_k(
    const float* __restrict__ A, const float* __restrict__ B,
    const float* __restrict__ bias, const float* __restrict__ EP1,
    float* __restrict__ C, int M)
{
  __shared__ float As[16][68];
  __shared__ float Bs[16][132];
  int t = threadIdx.x;
  int tx = t & 15, ty = t >> 4;
  int m0 = blockIdx.x * 64;

  float acc[4][8];
#pragma unroll
  for (int r = 0; r < 4; r++)
#pragma unroll
    for (int c = 0; c < 8; c++) acc[r][c] = 0.0f;

  for (int k0 = 0; k0 < HD; k0 += 16) {
    {
      int rrow = t >> 2;
      int kg = (t & 3) * 4;
      int gm = m0 + rrow;
      float4 av = make_float4(0.f, 0.f, 0.f, 0.f);
      if (gm < M) av = *(const float4*)(A + (size_t)gm * HD + k0 + kg);
      if (MODE_A == 1) { av.x = sspf(av.x); av.y = sspf(av.y); av.z = sspf(av.z); av.w = sspf(av.w); }
      As[kg+0][rrow] = av.x; As[kg+1][rrow] = av.y;
      As[kg+2][rrow] = av.z; As[kg+3][rrow] = av.w;
    }
    if (!BT) {
#pragma unroll
      for (int it = 0; it < 2; it++) {
        int f4 = t + it * 256;
        int kk = f4 >> 5;
        int n4 = (f4 & 31) * 4;
        float4 bv = *(const float4*)(B + (size_t)(k0 + kk) * HD + n4);
        *(float4*)&Bs[kk][n4] = bv;
      }
    } else {
#pragma unroll
      for (int it = 0; it < 2; it++) {
        int idx = t + it * 256;
        int n = idx >> 2;
        int kg = (idx & 3) * 4;
        float4 bv = *(const float4*)(B + (size_t)n * HD + k0 + kg);
        Bs[kg+0][n] = bv.x; Bs[kg+1][n] = bv.y;
        Bs[kg+2][n] = bv.z; Bs[kg+3][n] = bv.w;
      }
    }
    __syncthreads();
#pragma unroll
    for (int kk = 0; kk < 16; kk++) {
      float a[4], b[8];
#pragma unroll
      for (int r = 0; r < 4; r++) a[r] = As[kk][ty * 4 + r];
#pragma unroll
      for (int c = 0; c < 8; c++) b[c] = Bs[kk][tx * 8 + c];
#pragma unroll
      for (int r = 0; r < 4; r++)
#pragma unroll
        for (int c = 0; c < 8; c++) acc[r][c] = fmaf(a[r], b[c], acc[r][c]);
    }
    __syncthreads();
  }

  int n0 = tx * 8;
  float bv[8];
#pragma unroll
  for (int c = 0; c < 8; c++) bv[c] = bias ? bias[n0 + c] : 0.0f;
#pragma unroll
  for (int r = 0; r < 4; r++) {
    int gm = m0 + ty * 4 + r;
    if (gm >= M) continue;
    float out[8];
#pragma unroll
    for (int c = 0; c < 8; c++) {
      float x = acc[r][c] + bv[c];
      if (EPI == 1) x += EP1[(size_t)gm * HD + n0 + c];
      if (EPI == 2) x = acc[r][c] * sigmf(EP1[(size_t)gm * HD + n0 + c]);
      out[c] = x;
    }
    *(float4*)(C + (size_t)gm * HD + n0)     = *(float4*)&out[0];
    *(float4*)(C + (size_t)gm * HD + n0 + 4) = *(float4*)&out[4];
  }
}

// batched (over blockIdx.y = layer) plain GEMM with per-layer strides
__global__ __launch_bounds__(256) void gemm128b_k(
    const float* __restrict__ A, size_t astride,
    const float* __restrict__ B, size_t bstride,
    const float* __restrict__ bias, size_t biasstride,
    float* __restrict__ C, size_t cstride, int M)
{
  int l = blockIdx.y;
  A += (size_t)l * astride;
  B += (size_t)l * bstride;
  if (bias) bias += (size_t)l * biasstride;
  C += (size_t)l * cstride;

  __shared__ float As[16][68];
  __shared__ float Bs[16][132];
  int t = threadIdx.x;
  int tx = t & 15, ty = t >> 4;
  int m0 = blockIdx.x * 64;

  float acc[4][8];
#pragma unroll
  for (int r = 0; r < 4; r++)
#pragma unroll
    for (int c = 0; c < 8; c++) acc[r][c] = 0.0f;

  for (int k0 = 0; k0 < HD; k0 += 16) {
    {
      int rrow = t >> 2;
      int kg = (t & 3) * 4;
      int gm = m0 + rrow;
      float4 av = make_float4(0.f, 0.f, 0.f, 0.f);
      if (gm < M) av = *(const float4*)(A + (size_t)gm * HD + k0 + kg);
      As[kg+0][rrow] = av.x; As[kg+1][rrow] = av.y;
      As[kg+2][rrow] = av.z; As[kg+3][rrow] = av.w;
    }
#pragma unroll
    for (int it = 0; it < 2; it++) {
      int f4 = t + it * 256;
      int kk = f4 >> 5;
      int n4 = (f4 & 31) * 4;
      float4 bv = *(const float4*)(B + (size_t)(k0 + kk) * HD + n4);
      *(float4*)&Bs[kk][n4] = bv;
    }
    __syncthreads();
#pragma unroll
    for (int kk = 0; kk < 16; kk++) {
      float a[4], b[8];
#pragma unroll
      for (int r = 0; r < 4; r++) a[r] = As[kk][ty * 4 + r];
#pragma unroll
      for (int c = 0; c < 8; c++) b[c] = Bs[kk][tx * 8 + c];
#pragma unroll
      for (int r = 0; r < 4; r++)
#pragma unroll
        for (int c = 0; c < 8; c++) acc[r][c] = fmaf(a[r], b[c], acc[r][c]);
    }
    __syncthreads();
  }

  int n0 = tx * 8;
  float bv[8];
#pragma unroll
  for (int c = 0; c < 8; c++) bv[c] = bias ? bias[n0 + c] : 0.0f;
#pragma unroll
  for (int r = 0; r < 4; r++) {
    int gm = m0 + ty * 4 + r;
    if (gm >= M) continue;
    float out[8];
#pragma unroll
    for (int c = 0; c < 8; c++) out[c] = acc[r][c] + bv[c];
    *(float4*)(C + (size_t)gm * HD + n0)     = *(float4*)&out[0];
    *(float4*)(C + (size_t)gm * HD + n0 + 4) = *(float4*)&out[4];
  }
}

// ------------------------------------------------------------------
// forward edge pass: agg[col] += hx[row] * P(d)       (table Hermite)
// one wave (64 lanes) per edge, 2 channels per lane
// ------------------------------------------------------------------
__global__ __launch_bounds__(256) void edge_fwd_k(
    const int* __restrict__ row, const int* __restrict__ col,
    const float* __restrict__ dist, const float* __restrict__ T,
    const float* __restrict__ hx, float* __restrict__ agg,
    float inv_h, float hstep)
{
  int e = blockIdx.x * 4 + (threadIdx.x >> 6);
  int lane = threadIdx.x & 63;
  if (e >= N_EDGES) return;
  int r = row[e], c = col[e];
  float d = dist[e];
  float fi = d * inv_h;
  int i0 = (int)fi;
  float t = fi - (float)i0;
  float t2 = t * t, t3 = t2 * t;
  float a00 = 2.f*t3 - 3.f*t2 + 1.f;
  float a10 = (t3 - 2.f*t2 + t) * hstep;
  float a01 = 3.f*t2 - 2.f*t3;
  float a11 = (t3 - t2) * hstep;

  const float4 q0 = *(const float4*)(T + ((size_t)i0 * HD + 2*lane) * 2);
  const float4 q1 = *(const float4*)(T + ((size_t)(i0+1) * HD + 2*lane) * 2);
  float v0 = a00*q0.x + a10*q0.y + a01*q1.x + a11*q1.y;
  float v1 = a00*q0.z + a10*q0.w + a01*q1.z + a11*q1.w;
  float2 hv = *(const float2*)(hx + (size_t)r * HD + 2*lane);
  atomicAdd(&agg[(size_t)c * HD + 2*lane    ], hv.x * v0);
  atomicAdd(&agg[(size_t)c * HD + 2*lane + 1], hv.y * v1);
}

// ------------------------------------------------------------------
// backward edge pass: dhx[row] += dagg[col]*P ; dd[e] += sum dagg*hx*P'
// ------------------------------------------------------------------
__global__ __launch_bounds__(256) void edge_bwd_k(
    const int* __restrict__ row, const int* __restrict__ col,
    const float* __restrict__ dist, const float* __restrict__ T,
    const float* __restrict__ dagg, const float* __restrict__ hx,
    float* __restrict__ dhx, float* __restrict__ dd,
    float inv_h, float hstep)
{
  int e = blockIdx.x * 4 + (threadIdx.x >> 6);
  int lane = threadIdx.x & 63;
  if (e >= N_EDGES) return;
  int r = row[e], c = col[e];
  float d = dist[e];
  float fi = d * inv_h;
  int i0 = (int)fi;
  float t = fi - (float)i0;
  float t2 = t * t, t3 = t2 * t;
  float a00 = 2.f*t3 - 3.f*t2 + 1.f;
  float a10 = (t3 - 2.f*t2 + t) * hstep;
  float a01 = 3.f*t2 - 2.f*t3;
  float a11 = (t3 - t2) * hstep;
  float b00 = (6.f*t2 - 6.f*t) * inv_h;
  float b10 = 3.f*t2 - 4.f*t + 1.f;
  float b01 = -b00;
  float b11 = 3.f*t2 - 2.f*t;

  const float4 q0 = *(const float4*)(T + ((size_t)i0 * HD + 2*lane) * 2);
  const float4 q1 = *(const float4*)(T + ((size_t)(i0+1) * HD + 2*lane) * 2);
  float v0 = a00*q0.x + a10*q0.y + a01*q1.x + a11*q1.y;
  float v1 = a00*q0.z + a10*q0.w + a01*q1.z + a11*q1.w;
  float g0 = b00*q0.x + b10*q0.y + b01*q1.x + b11*q1.y;
  float g1 = b00*q0.z + b10*q0.w + b01*q1.z + b11*q1.w;

  float2 da = *(const float2*)(dagg + (size_t)c * HD + 2*lane);
  float2 hv = *(const float2*)(hx + (size_t)r * HD + 2*lane);
  atomicAdd(&dhx[(size_t)r * HD + 2*lane    ], da.x * v0);
  atomicAdd(&dhx[(size_t)r * HD + 2*lane + 1], da.y * v1);
  float dot = da.x * hv.x * g0 + da.y * hv.y * g1;
#pragma unroll
  for (int off = 32; off > 0; off >>= 1) dot += __shfl_down(dot, off, 64);
  if (lane == 0) dd[e] += dot;
}

// ------------------------------------------------------------------
// head: energy accumulate + dL/dh4 init
// ------------------------------------------------------------------
__global__ __launch_bounds__(128) void head_k(
    const float* __restrict__ h4, const float* __restrict__ w1,
    const float* __restrict__ b1, const float* __restrict__ w2,
    const float* __restrict__ b2, const int* __restrict__ batch,
    float* __restrict__ energy, float* __restrict__ gh)
{
  __shared__ float hsh[128];
  __shared__ float csh[64];
  __shared__ float psh[64];
  int n = blockIdx.x;
  int t = threadIdx.x;
  hsh[t] = h4[(size_t)n * HD + t];
  __syncthreads();
  if (t < 64) {
    float s = b1[t];
    for (int k = 0; k < 128; k++) s = fmaf(hsh[k], w1[k * 64 + t], s);
    float w2v = w2[t];
    psh[t] = sspf(s) * w2v;
    csh[t] = sigmf(s) * w2v;
  }
  __syncthreads();
  if (t == 0) {
    float s = b2[0];
    for (int j = 0; j < 64; j++) s += psh[j];
    atomicAdd(&energy[batch[n]], s);
  }
  float g = 0.0f;
  for (int j = 0; j < 64; j++) g = fmaf(csh[j], w1[t * 64 + j], g);
  gh[(size_t)n * HD + t] = g;
}

// ------------------------------------------------------------------
// final force scatter
// ------------------------------------------------------------------
__global__ __launch_bounds__(256) void force_k(
    const int* __restrict__ row, const int* __restrict__ col,
    const float* __restrict__ pos, const float* __restrict__ dist,
    const float* __restrict__ dd, float* __restrict__ force)
{
  int e = blockIdx.x * 256 + threadIdx.x;
  if (e >= N_EDGES) return;
  int r = row[e], c = col[e];
  float inv = dd[e] / dist[e];
  float fx = (pos[3*r+0] - pos[3*c+0]) * inv;
  float fy = (pos[3*r+1] - pos[3*c+1]) * inv;
  float fz = (pos[3*r+2] - pos[3*c+2]) * inv;
  atomicAdd(&force[3*r+0], -fx);
  atomicAdd(&force[3*r+1], -fy);
  atomicAdd(&force[3*r+2], -fz);
  atomicAdd(&force[3*c+0],  fx);
  atomicAdd(&force[3*c+1],  fy);
  atomicAdd(&force[3*c+2],  fz);
}

// ------------------------------------------------------------------
// host launch
// ------------------------------------------------------------------
static inline int nblk(int m) { return (m + 63) / 64; }

extern "C" void kernel_launch(void* const* d_in, const int* in_sizes, int n_in,
                              void* d_out, int out_size, void* d_ws, size_t ws_size,
                              hipStream_t stream)
{
  const float* pos   = (const float*)d_in[0];
  const int*   z     = (const int*)d_in[1];
  const int*   batch = (const int*)d_in[2];
  const int*   eidx  = (const int*)d_in[3];
  const float* emb   = (const float*)d_in[4];
  const float* mlp_w1 = (const float*)d_in[5];
  const float* mlp_b1 = (const float*)d_in[6];
  const float* mlp_w2 = (const float*)d_in[7];
  const float* mlp_b2 = (const float*)d_in[8];
  const float* lin1_w = (const float*)d_in[9];
  const float* lin2_w = (const float*)d_in[10];
  const float* lin2_b = (const float*)d_in[11];
  const float* blk_w  = (const float*)d_in[12];
  const float* blk_b  = (const float*)d_in[13];
  const float* hw1 = (const float*)d_in[14];
  const float* hb1 = (const float*)d_in[15];
  const float* hw2 = (const float*)d_in[16];
  const float* hb2 = (const float*)d_in[17];

  float* out = (float*)d_out;          // [NMOL] energies ++ [N,3] forces
  float* ws  = (float*)d_ws;

  const int* row = eidx;
  const int* col = eidx + N_EDGES;

  const size_t NH = (size_t)N_ATOMS * HD;
  size_t o = 0;
  float* dist = ws + o; o += N_EDGES;
  float* dd   = ws + o; o += N_EDGES;
  float* hxb[4];
  for (int i = 0; i < 4; i++) { hxb[i] = ws + o; o += NH; }
  float* vbuf[4];
  for (int i = 0; i < 4; i++) { vbuf[i] = ws + o; o += NH; }
  float* hA  = ws + o; o += NH;
  float* hB  = ws + o; o += NH;
  float* agg = ws + o; o += NH;       // fwd agg / bwd dhx / table A,dA temp
  float* g0b = ws + o; o += NH;       // bwd grad ping / table u,D0 temp
  float* g1b = ws + o; o += NH;       // bwd grad pong+dvb / table s temp
  float* dgb = ws + o; o += NH;       // bwd dagg / table t1,P0 temp

  // table: pick NT so everything fits in ws
  int NT = 4096;
  while (NT > 256) {
    size_t need = o + (size_t)NLAY * (NT + 1) * HD * 2;
    if (need * sizeof(float) <= ws_size) break;
    NT >>= 1;
  }
  const int NN = NT + 1;               // nodes per layer
  const float hstep = FCUT / (float)NT;
  const float inv_h = (float)NT / FCUT;
  float* T = ws + o; o += (size_t)NLAY * NN * HD * 2;   // [L][node][ch]{val,der}

  hipMemsetAsync(dd, 0, N_EDGES * sizeof(float), stream);
  hipMemsetAsync(out, 0, (size_t)(NMOL + 3 * N_ATOMS) * sizeof(float), stream);

  geom_k<<<(N_EDGES + 255) / 256, 256, 0, stream>>>(pos, row, col, dist);

  // ---------------- build filter tables (all 4 layers) ----------------
  {
    const size_t LNH = (size_t)NN * HD;   // per-layer node-feature count
    float* Anode  = agg;                  // [NN,128]
    float* dAnode = agg + LNH;            // [NN,128]
    float* t1 = dgb;                      // [4][NN,128]
    float* u  = g0b;                      // [4][NN,128]
    float* s  = g1b;                      // [4][NN,128]
    float* sp = hA;                       // [4][NN,128]
    nodeA_k<<<((int)LNH + 255) / 256, 256, 0, stream>>>(Anode, dAnode, NN, hstep);
    dim3 gB(nblk(NN), NLAY);
    gemm128b_k<<<gB, 256, 0, stream>>>(Anode, 0, mlp_w1, (size_t)HD*HD,
                                       mlp_b1, HD, t1, LNH, NN);
    gemm128b_k<<<gB, 256, 0, stream>>>(dAnode, 0, mlp_w1, (size_t)HD*HD,
                                       nullptr, 0, u, LNH, NN);
    int tot = (int)(NLAY * LNH);
    nodeact_k<<<(tot + 255) / 256, 256, 0, stream>>>(t1, u, s, sp, tot);
    float* P0 = dgb;                      // t1 dead
    float* D0 = g0b;                      // u dead
    gemm128b_k<<<gB, 256, 0, stream>>>(s, LNH, mlp_w2, (size_t)HD*HD,
                                       mlp_b2, HD, P0, LNH, NN);
    gemm128b_k<<<gB, 256, 0, stream>>>(sp, LNH, mlp_w2, (size_t)HD*HD,
                                       nullptr, 0, D0, LNH, NN);
    nodecomb_k<<<(tot + 255) / 256, 256, 0, stream>>>(P0, D0, T, NN, hstep);
  }

  h0_k<<<(N_ATOMS * HD + 255) / 256, 256, 0, stream>>>(emb, z, hA);

  // ---------------- forward ----------------
  float* hcur = hA;
  float* hnxt = hB;
  for (int i = 0; i < NLAY; i++) {
    const float* l1 = lin1_w + (size_t)i * HD * HD;
    const float* l2 = lin2_w + (size_t)i * HD * HD;
    const float* l2b = lin2_b + (size_t)i * HD;
    const float* bw = blk_w + (size_t)i * HD * HD;
    const float* bb = blk_b + (size_t)i * HD;
    const float* Tl = T + (size_t)i * NN * HD * 2;

    gemm128_k<0,0,false><<<nblk(N_ATOMS), 256, 0, stream>>>(hcur, l1, nullptr, nullptr, hxb[i], N_ATOMS);
    hipMemsetAsync(agg, 0, NH * sizeof(float), stream);
    edge_fwd_k<<<(N_EDGES + 3) / 4, 256, 0, stream>>>(row, col, dist, Tl, hxb[i], agg, inv_h, hstep);
    gemm128_k<0,0,false><<<nblk(N_ATOMS), 256, 0, stream>>>(agg, l2, l2b, nullptr, vbuf[i], N_ATOMS);
    gemm128_k<1,1,false><<<nblk(N_ATOMS), 256, 0, stream>>>(vbuf[i], bw, bb, hcur, hnxt, N_ATOMS);
    float* tmp = hcur; hcur = hnxt; hnxt = tmp;
  }

  // head: energies + initial gradient (into g0b)
  head_k<<<N_ATOMS, 128, 0, stream>>>(hcur, hw1, hb1, hw2, hb2, batch, out, g0b);

  // ---------------- backward ----------------
  float* gcur = g0b;
  float* gnxt = g1b;
  for (int i = NLAY - 1; i >= 0; i--) {
    const float* l1 = lin1_w + (size_t)i * HD * HD;
    const float* l2 = lin2_w + (size_t)i * HD * HD;
    const float* bw = blk_w + (size_t)i * HD * HD;
    const float* Tl = T + (size_t)i * NN * HD * 2;
    float* dvb = gnxt;   // dead buffer doubles as dv scratch

    // dv = (g @ bw^T) * sigmoid(v_i)
    gemm128_k<0,2,true><<<nblk(N_ATOMS), 256, 0, stream>>>(gcur, bw, nullptr, vbuf[i], dvb, N_ATOMS);
    // dagg = dv @ l2^T
    gemm128_k<0,0,true><<<nblk(N_ATOMS), 256, 0, stream>>>(dvb, l2, nullptr, nullptr, dgb, N_ATOMS);
    // edge backward: dhx (in agg), dd
    hipMemsetAsync(agg, 0, NH * sizeof(float), stream);
    edge_bwd_k<<<(N_EDGES + 3) / 4, 256, 0, stream>>>(row, col, dist, Tl, dgb, hxb[i], agg, dd, inv_h, hstep);
    if (i > 0) {
      // dh_i = g + dhx @ l1^T   (overwrites dvb's buffer — dvb is dead)
      gemm128_k<0,1,true><<<nblk(N_ATOMS), 256, 0, stream>>>(agg, l1, nullptr, gcur, gnxt, N_ATOMS);
      float* tmp = gcur; gcur = gnxt; gnxt = tmp;
    }
  }

  force_k<<<(N_EDGES + 255) / 256, 256, 0, stream>>>(row, col, pos, dist, dd, out + NMOL);
}

// Round 3
// 1668.432 us; speedup vs baseline: 4.8061x; 1.8556x over previous
//
#include <hip/hip_runtime.h>

#define HD 128

constexpr int N_ATOMS = 20000;
constexpr int N_EDGES = 320000;
constexpr int NLAY   = 4;
constexpr int NMOL   = 200;
constexpr float FCUT  = 5.0f;
constexpr float DELTA = FCUT / 127.0f;
constexpr float GCOEFF = -0.5f / (DELTA * DELTA);
constexpr float PI_F  = 3.14159265358979323846f;
constexpr float LN2F  = 0.6931471805599453f;

__device__ __forceinline__ float sspf(float x) {
  return fmaxf(x, 0.0f) + log1pf(expf(-fabsf(x))) - LN2F;
}
__device__ __forceinline__ float sigmf(float x) {
  return 1.0f / (1.0f + expf(-x));
}

// ------------------------------------------------------------------
// small elementwise kernels
// ------------------------------------------------------------------

__global__ __launch_bounds__(256) void geom_k(
    const float* __restrict__ pos, const int* __restrict__ row,
    const int* __restrict__ col, float* __restrict__ dist)
{
  int e = blockIdx.x * 256 + threadIdx.x;
  if (e >= N_EDGES) return;
  int r = row[e], c = col[e];
  float dx = pos[3*r+0] - pos[3*c+0];
  float dy = pos[3*r+1] - pos[3*c+1];
  float dz = pos[3*r+2] - pos[3*c+2];
  dist[e] = sqrtf(dx*dx + dy*dy + dz*dz);
}

__global__ __launch_bounds__(256) void h0_k(
    const float* __restrict__ emb, const int* __restrict__ z,
    float* __restrict__ h0)
{
  int i = blockIdx.x * 256 + threadIdx.x;
  if (i >= N_ATOMS * HD) return;
  int n = i >> 7, k = i & 127;
  h0[i] = emb[z[n] * HD + k];
}

// ------------------------------------------------------------------
// CSR build: histogram, scan, scatter
// ------------------------------------------------------------------
__global__ __launch_bounds__(256) void hist_k(
    const int* __restrict__ idx, int* __restrict__ cnt)
{
  int e = blockIdx.x * 256 + threadIdx.x;
  if (e >= N_EDGES) return;
  atomicAdd(&cnt[idx[e]], 1);
}

__global__ __launch_bounds__(256) void scan_k(
    const int* __restrict__ cnt, int* __restrict__ ptr)
{
  constexpr int CH = 79;  // 256*79 = 20224 >= 20001
  __shared__ int part[256];
  int t = threadIdx.x;
  int base = t * CH;
  int s = 0;
  for (int i = 0; i < CH; i++) {
    int idx = base + i;
    if (idx < N_ATOMS) s += cnt[idx];
  }
  part[t] = s;
  __syncthreads();
  for (int off = 1; off < 256; off <<= 1) {
    int u = (t >= off) ? part[t - off] : 0;
    __syncthreads();
    part[t] += u;
    __syncthreads();
  }
  int run = part[t] - s;   // exclusive base for this thread
  for (int i = 0; i < CH; i++) {
    int idx = base + i;
    if (idx > N_ATOMS) break;
    ptr[idx] = run;
    if (idx < N_ATOMS) run += cnt[idx];
  }
}

// CSR by col (forward): store source atom + dist
__global__ __launch_bounds__(256) void scat_col_k(
    const int* __restrict__ row, const int* __restrict__ col,
    const float* __restrict__ dist, int* __restrict__ cur,
    int* __restrict__ cother, float* __restrict__ cdist)
{
  int e = blockIdx.x * 256 + threadIdx.x;
  if (e >= N_EDGES) return;
  int p = atomicAdd(&cur[col[e]], 1);
  cother[p] = row[e];
  cdist[p] = dist[e];
}

// CSR by row (backward): store dest atom + edge id + dist
__global__ __launch_bounds__(256) void scat_row_k(
    const int* __restrict__ row, const int* __restrict__ col,
    const float* __restrict__ dist, int* __restrict__ cur,
    int* __restrict__ rother, int* __restrict__ reid,
    float* __restrict__ rdist)
{
  int e = blockIdx.x * 256 + threadIdx.x;
  if (e >= N_EDGES) return;
  int p = atomicAdd(&cur[row[e]], 1);
  rother[p] = col[e];
  reid[p] = e;
  rdist[p] = dist[e];
}

// ------------------------------------------------------------------
// table build: node gaussians A, dA
// ------------------------------------------------------------------
__global__ __launch_bounds__(256) void nodeA_k(
    float* __restrict__ A, float* __restrict__ dA, int nnode, float hstep)
{
  int i = blockIdx.x * 256 + threadIdx.x;
  if (i >= nnode * HD) return;
  int node = i >> 7, g = i & 127;
  float d = (float)node * hstep;
  float t = d - (float)g * DELTA;
  float a = expf(GCOEFF * t * t);
  A[i] = a;
  dA[i] = a * 2.0f * GCOEFF * t;
}

__global__ __launch_bounds__(256) void nodeact_k(
    const float* __restrict__ t1, const float* __restrict__ u,
    float* __restrict__ s, float* __restrict__ sp, int total)
{
  int i = blockIdx.x * 256 + threadIdx.x;
  if (i >= total) return;
  float x = t1[i];
  s[i] = sspf(x);
  sp[i] = sigmf(x) * u[i];
}

__global__ __launch_bounds__(256) void nodecomb_k(
    const float* __restrict__ P0, const float* __restrict__ D0,
    float* __restrict__ T, int nnode, float hstep)
{
  int i = blockIdx.x * 256 + threadIdx.x;
  int total = NLAY * nnode * HD;
  if (i >= total) return;
  int rem = i % (nnode * HD);
  int node = rem >> 7;
  float d = (float)node * hstep;
  float C  = 0.5f * cosf(d * (PI_F / FCUT)) + 0.5f;
  float Cp = -0.5f * sinf(d * (PI_F / FCUT)) * (PI_F / FCUT);
  float p = P0[i], q = D0[i];
  T[(size_t)i * 2 + 0] = p * C;
  T[(size_t)i * 2 + 1] = q * C + p * Cp;
}

// ------------------------------------------------------------------
// generic fp32 GEMM: C[M,128] = epi( op_a(A)[M,128] @ B(^T) + bias )
// ------------------------------------------------------------------
template<int MODE_A, int EPI, bool BT>
__global__ __launch_bounds__(256) void gemm128_k(
    const float* __restrict__ A, const float* __restrict__ B,
    const float* __restrict__ bias, const float* __restrict__ EP1,
    float* __restrict__ C, int M)
{
  __shared__ float As[16][68];
  __shared__ float Bs[16][132];
  int t = threadIdx.x;
  int tx = t & 15, ty = t >> 4;
  int m0 = blockIdx.x * 64;

  float acc[4][8];
#pragma unroll
  for (int r = 0; r < 4; r++)
#pragma unroll
    for (int c = 0; c < 8; c++) acc[r][c] = 0.0f;

  for (int k0 = 0; k0 < HD; k0 += 16) {
    {
      int rrow = t >> 2;
      int kg = (t & 3) * 4;
      int gm = m0 + rrow;
      float4 av = make_float4(0.f, 0.f, 0.f, 0.f);
      if (gm < M) av = *(const float4*)(A + (size_t)gm * HD + k0 + kg);
      if (MODE_A == 1) { av.x = sspf(av.x); av.y = sspf(av.y); av.z = sspf(av.z); av.w = sspf(av.w); }
      As[kg+0][rrow] = av.x; As[kg+1][rrow] = av.y;
      As[kg+2][rrow] = av.z; As[kg+3][rrow] = av.w;
    }
    if (!BT) {
#pragma unroll
      for (int it = 0; it < 2; it++) {
        int f4 = t + it * 256;
        int kk = f4 >> 5;
        int n4 = (f4 & 31) * 4;
        float4 bv = *(const float4*)(B + (size_t)(k0 + kk) * HD + n4);
        *(float4*)&Bs[kk][n4] = bv;
      }
    } else {
#pragma unroll
      for (int it = 0; it < 2; it++) {
        int idx = t + it * 256;
        int n = idx >> 2;
        int kg = (idx & 3) * 4;
        float4 bv = *(const float4*)(B + (size_t)n * HD + k0 + kg);
        Bs[kg+0][n] = bv.x; Bs[kg+1][n] = bv.y;
        Bs[kg+2][n] = bv.z; Bs[kg+3][n] = bv.w;
      }
    }
    __syncthreads();
#pragma unroll
    for (int kk = 0; kk < 16; kk++) {
      float a[4], b[8];
#pragma unroll
      for (int r = 0; r < 4; r++) a[r] = As[kk][ty * 4 + r];
#pragma unroll
      for (int c = 0; c < 8; c++) b[c] = Bs[kk][tx * 8 + c];
#pragma unroll
      for (int r = 0; r < 4; r++)
#pragma unroll
        for (int c = 0; c < 8; c++) acc[r][c] = fmaf(a[r], b[c], acc[r][c]);
    }
    __syncthreads();
  }

  int n0 = tx * 8;
  float bv[8];
#pragma unroll
  for (int c = 0; c < 8; c++) bv[c] = bias ? bias[n0 + c] : 0.0f;
#pragma unroll
  for (int r = 0; r < 4; r++) {
    int gm = m0 + ty * 4 + r;
    if (gm >= M) continue;
    float out[8];
#pragma unroll
    for (int c = 0; c < 8; c++) {
      float x = acc[r][c] + bv[c];
      if (EPI == 1) x += EP1[(size_t)gm * HD + n0 + c];
      if (EPI == 2) x = acc[r][c] * sigmf(EP1[(size_t)gm * HD + n0 + c]);
      out[c] = x;
    }
    *(float4*)(C + (size_t)gm * HD + n0)     = *(float4*)&out[0];
    *(float4*)(C + (size_t)gm * HD + n0 + 4) = *(float4*)&out[4];
  }
}

// batched (over blockIdx.y = layer) plain GEMM with per-layer strides
__global__ __launch_bounds__(256) void gemm128b_k(
    const float* __restrict__ A, size_t astride,
    const float* __restrict__ B, size_t bstride,
    const float* __restrict__ bias, size_t biasstride,
    float* __restrict__ C, size_t cstride, int M)
{
  int l = blockIdx.y;
  A += (size_t)l * astride;
  B += (size_t)l * bstride;
  if (bias) bias += (size_t)l * biasstride;
  C += (size_t)l * cstride;

  __shared__ float As[16][68];
  __shared__ float Bs[16][132];
  int t = threadIdx.x;
  int tx = t & 15, ty = t >> 4;
  int m0 = blockIdx.x * 64;

  float acc[4][8];
#pragma unroll
  for (int r = 0; r < 4; r++)
#pragma unroll
    for (int c = 0; c < 8; c++) acc[r][c] = 0.0f;

  for (int k0 = 0; k0 < HD; k0 += 16) {
    {
      int rrow = t >> 2;
      int kg = (t & 3) * 4;
      int gm = m0 + rrow;
      float4 av = make_float4(0.f, 0.f, 0.f, 0.f);
      if (gm < M) av = *(const float4*)(A + (size_t)gm * HD + k0 + kg);
      As[kg+0][rrow] = av.x; As[kg+1][rrow] = av.y;
      As[kg+2][rrow] = av.z; As[kg+3][rrow] = av.w;
    }
#pragma unroll
    for (int it = 0; it < 2; it++) {
      int f4 = t + it * 256;
      int kk = f4 >> 5;
      int n4 = (f4 & 31) * 4;
      float4 bv = *(const float4*)(B + (size_t)(k0 + kk) * HD + n4);
      *(float4*)&Bs[kk][n4] = bv;
    }
    __syncthreads();
#pragma unroll
    for (int kk = 0; kk < 16; kk++) {
      float a[4], b[8];
#pragma unroll
      for (int r = 0; r < 4; r++) a[r] = As[kk][ty * 4 + r];
#pragma unroll
      for (int c = 0; c < 8; c++) b[c] = Bs[kk][tx * 8 + c];
#pragma unroll
      for (int r = 0; r < 4; r++)
#pragma unroll
        for (int c = 0; c < 8; c++) acc[r][c] = fmaf(a[r], b[c], acc[r][c]);
    }
    __syncthreads();
  }

  int n0 = tx * 8;
  float bv[8];
#pragma unroll
  for (int c = 0; c < 8; c++) bv[c] = bias ? bias[n0 + c] : 0.0f;
#pragma unroll
  for (int r = 0; r < 4; r++) {
    int gm = m0 + ty * 4 + r;
    if (gm >= M) continue;
    float out[8];
#pragma unroll
    for (int c = 0; c < 8; c++) out[c] = acc[r][c] + bv[c];
    *(float4*)(C + (size_t)gm * HD + n0)     = *(float4*)&out[0];
    *(float4*)(C + (size_t)gm * HD + n0 + 4) = *(float4*)&out[4];
  }
}

// ------------------------------------------------------------------
// forward gather: agg[a] = sum_{incoming e} hx[src_e] * P(d_e)
// one wave per atom, 2 channels per lane, no atomics
// ------------------------------------------------------------------
__global__ __launch_bounds__(256) void gath_fwd_k(
    const int* __restrict__ cptr, const int* __restrict__ cother,
    const float* __restrict__ cdist, const float* __restrict__ T,
    const float* __restrict__ hx, float* __restrict__ agg,
    float inv_h, float hstep)
{
  int a = blockIdx.x * 4 + (threadIdx.x >> 6);
  int lane = threadIdx.x & 63;
  if (a >= N_ATOMS) return;
  int beg = cptr[a], end = cptr[a + 1];
  float ax = 0.0f, ay = 0.0f;
  for (int j = beg; j < end; j++) {
    int other = cother[j];
    float d = cdist[j];
    float fi = d * inv_h;
    int i0 = (int)fi;
    float t = fi - (float)i0;
    float t2 = t * t, t3 = t2 * t;
    float a00 = 2.f*t3 - 3.f*t2 + 1.f;
    float a10 = (t3 - 2.f*t2 + t) * hstep;
    float a01 = 3.f*t2 - 2.f*t3;
    float a11 = (t3 - t2) * hstep;
    const float4 q0 = *(const float4*)(T + ((size_t)i0 * HD + 2*lane) * 2);
    const float4 q1 = *(const float4*)(T + ((size_t)(i0+1) * HD + 2*lane) * 2);
    float v0 = a00*q0.x + a10*q0.y + a01*q1.x + a11*q1.y;
    float v1 = a00*q0.z + a10*q0.w + a01*q1.z + a11*q1.w;
    float2 hv = *(const float2*)(hx + (size_t)other * HD + 2*lane);
    ax = fmaf(hv.x, v0, ax);
    ay = fmaf(hv.y, v1, ay);
  }
  *(float2*)(agg + (size_t)a * HD + 2*lane) = make_float2(ax, ay);
}

// ------------------------------------------------------------------
// backward gather: dhx[a] = sum_{outgoing e} dagg[dst_e] * P(d_e)
//                  dd[e] += <dagg[dst_e], hx[a] * P'(d_e)>
// ------------------------------------------------------------------
__global__ __launch_bounds__(256) void gath_bwd_k(
    const int* __restrict__ rptr, const int* __restrict__ rother,
    const int* __restrict__ reid, const float* __restrict__ rdist,
    const float* __restrict__ T, const float* __restrict__ dagg,
    const float* __restrict__ hx, float* __restrict__ dhx,
    float* __restrict__ dd, float inv_h, float hstep)
{
  int a = blockIdx.x * 4 + (threadIdx.x >> 6);
  int lane = threadIdx.x & 63;
  if (a >= N_ATOMS) return;
  int beg = rptr[a], end = rptr[a + 1];
  float2 hv = *(const float2*)(hx + (size_t)a * HD + 2*lane);
  float ax = 0.0f, ay = 0.0f;
  for (int j = beg; j < end; j++) {
    int other = rother[j];
    int eid = reid[j];
    float d = rdist[j];
    float fi = d * inv_h;
    int i0 = (int)fi;
    float t = fi - (float)i0;
    float t2 = t * t, t3 = t2 * t;
    float a00 = 2.f*t3 - 3.f*t2 + 1.f;
    float a10 = (t3 - 2.f*t2 + t) * hstep;
    float a01 = 3.f*t2 - 2.f*t3;
    float a11 = (t3 - t2) * hstep;
    float b00 = (6.f*t2 - 6.f*t) * inv_h;
    float b10 = 3.f*t2 - 4.f*t + 1.f;
    float b01 = -b00;
    float b11 = 3.f*t2 - 2.f*t;
    const float4 q0 = *(const float4*)(T + ((size_t)i0 * HD + 2*lane) * 2);
    const float4 q1 = *(const float4*)(T + ((size_t)(i0+1) * HD + 2*lane) * 2);
    float v0 = a00*q0.x + a10*q0.y + a01*q1.x + a11*q1.y;
    float v1 = a00*q0.z + a10*q0.w + a01*q1.z + a11*q1.w;
    float g0 = b00*q0.x + b10*q0.y + b01*q1.x + b11*q1.y;
    float g1 = b00*q0.z + b10*q0.w + b01*q1.z + b11*q1.w;
    float2 da = *(const float2*)(dagg + (size_t)other * HD + 2*lane);
    ax = fmaf(da.x, v0, ax);
    ay = fmaf(da.y, v1, ay);
    float dot = da.x * hv.x * g0 + da.y * hv.y * g1;
#pragma unroll
    for (int off = 32; off > 0; off >>= 1) dot += __shfl_down(dot, off, 64);
    if (lane == 0) dd[eid] += dot;
  }
  *(float2*)(dhx + (size_t)a * HD + 2*lane) = make_float2(ax, ay);
}

// ------------------------------------------------------------------
// head: energy accumulate + dL/dh4 init
// ------------------------------------------------------------------
__global__ __launch_bounds__(128) void head_k(
    const float* __restrict__ h4, const float* __restrict__ w1,
    const float* __restrict__ b1, const float* __restrict__ w2,
    const float* __restrict__ b2, const int* __restrict__ batch,
    float* __restrict__ energy, float* __restrict__ gh)
{
  __shared__ float hsh[128];
  __shared__ float csh[64];
  __shared__ float psh[64];
  int n = blockIdx.x;
  int t = threadIdx.x;
  hsh[t] = h4[(size_t)n * HD + t];
  __syncthreads();
  if (t < 64) {
    float s = b1[t];
    for (int k = 0; k < 128; k++) s = fmaf(hsh[k], w1[k * 64 + t], s);
    float w2v = w2[t];
    psh[t] = sspf(s) * w2v;
    csh[t] = sigmf(s) * w2v;
  }
  __syncthreads();
  if (t == 0) {
    float s = b2[0];
    for (int j = 0; j < 64; j++) s += psh[j];
    atomicAdd(&energy[batch[n]], s);
  }
  float g = 0.0f;
  for (int j = 0; j < 64; j++) g = fmaf(csh[j], w1[t * 64 + j], g);
  gh[(size_t)n * HD + t] = g;
}

// ------------------------------------------------------------------
// final force scatter
// ------------------------------------------------------------------
__global__ __launch_bounds__(256) void force_k(
    const int* __restrict__ row, const int* __restrict__ col,
    const float* __restrict__ pos, const float* __restrict__ dist,
    const float* __restrict__ dd, float* __restrict__ force)
{
  int e = blockIdx.x * 256 + threadIdx.x;
  if (e >= N_EDGES) return;
  int r = row[e], c = col[e];
  float inv = dd[e] / dist[e];
  float fx = (pos[3*r+0] - pos[3*c+0]) * inv;
  float fy = (pos[3*r+1] - pos[3*c+1]) * inv;
  float fz = (pos[3*r+2] - pos[3*c+2]) * inv;
  atomicAdd(&force[3*r+0], -fx);
  atomicAdd(&force[3*r+1], -fy);
  atomicAdd(&force[3*r+2], -fz);
  atomicAdd(&force[3*c+0],  fx);
  atomicAdd(&force[3*c+1],  fy);
  atomicAdd(&force[3*c+2],  fz);
}

// ------------------------------------------------------------------
// host launch
// ------------------------------------------------------------------
static inline int nblk(int m) { return (m + 63) / 64; }

extern "C" void kernel_launch(void* const* d_in, const int* in_sizes, int n_in,
                              void* d_out, int out_size, void* d_ws, size_t ws_size,
                              hipStream_t stream)
{
  const float* pos   = (const float*)d_in[0];
  const int*   z     = (const int*)d_in[1];
  const int*   batch = (const int*)d_in[2];
  const int*   eidx  = (const int*)d_in[3];
  const float* emb   = (const float*)d_in[4];
  const float* mlp_w1 = (const float*)d_in[5];
  const float* mlp_b1 = (const float*)d_in[6];
  const float* mlp_w2 = (const float*)d_in[7];
  const float* mlp_b2 = (const float*)d_in[8];
  const float* lin1_w = (const float*)d_in[9];
  const float* lin2_w = (const float*)d_in[10];
  const float* lin2_b = (const float*)d_in[11];
  const float* blk_w  = (const float*)d_in[12];
  const float* blk_b  = (const float*)d_in[13];
  const float* hw1 = (const float*)d_in[14];
  const float* hb1 = (const float*)d_in[15];
  const float* hw2 = (const float*)d_in[16];
  const float* hb2 = (const float*)d_in[17];

  float* out = (float*)d_out;          // [NMOL] energies ++ [N,3] forces
  float* ws  = (float*)d_ws;

  const int* row = eidx;
  const int* col = eidx + N_EDGES;

  const size_t NH = (size_t)N_ATOMS * HD;
  size_t o = 0;
  float* dist = ws + o; o += N_EDGES;
  float* dd   = ws + o; o += N_EDGES;
  // CSR structures
  int* cptr   = (int*)(ws + o); o += N_ATOMS + 1;
  int* rptr   = (int*)(ws + o); o += N_ATOMS + 1;
  int* cother = (int*)(ws + o); o += N_EDGES;
  int* rother = (int*)(ws + o); o += N_EDGES;
  int* reid   = (int*)(ws + o); o += N_EDGES;
  float* cdist = ws + o; o += N_EDGES;
  float* rdist = ws + o; o += N_EDGES;
  int* cur0   = (int*)(ws + o); o += N_ATOMS;
  int* cur1   = (int*)(ws + o); o += N_ATOMS;
  // atom feature buffers
  float* hxb[4];
  for (int i = 0; i < 4; i++) { hxb[i] = ws + o; o += NH; }
  float* vbuf[4];
  for (int i = 0; i < 4; i++) { vbuf[i] = ws + o; o += NH; }
  float* hA  = ws + o; o += NH;
  float* hB  = ws + o; o += NH;
  float* agg = ws + o; o += NH;       // fwd agg / bwd dhx / table A,dA temp
  float* g0b = ws + o; o += NH;       // bwd grad ping / table u,D0 temp
  float* g1b = ws + o; o += NH;       // bwd grad pong+dvb / table s temp
  float* dgb = ws + o; o += NH;       // bwd dagg / table t1,P0 temp

  // table: pick NT so everything fits in ws
  int NT = 2048;
  while (NT > 256) {
    size_t need = o + (size_t)NLAY * (NT + 1) * HD * 2;
    if (need * sizeof(float) <= ws_size) break;
    NT >>= 1;
  }
  const int NN = NT + 1;
  const float hstep = FCUT / (float)NT;
  const float inv_h = (float)NT / FCUT;
  float* T = ws + o; o += (size_t)NLAY * NN * HD * 2;   // [L][node][ch]{val,der}

  hipMemsetAsync(dd, 0, N_EDGES * sizeof(float), stream);
  hipMemsetAsync(out, 0, (size_t)(NMOL + 3 * N_ATOMS) * sizeof(float), stream);

  geom_k<<<(N_EDGES + 255) / 256, 256, 0, stream>>>(pos, row, col, dist);

  // ---------------- CSR build (both directions) ----------------
  {
    const int EB = (N_EDGES + 255) / 256;
    hipMemsetAsync(cur0, 0, N_ATOMS * sizeof(int), stream);
    hipMemsetAsync(cur1, 0, N_ATOMS * sizeof(int), stream);
    hist_k<<<EB, 256, 0, stream>>>(col, cur0);
    hist_k<<<EB, 256, 0, stream>>>(row, cur1);
    scan_k<<<1, 256, 0, stream>>>(cur0, cptr);
    scan_k<<<1, 256, 0, stream>>>(cur1, rptr);
    hipMemcpyAsync(cur0, cptr, N_ATOMS * sizeof(int), hipMemcpyDeviceToDevice, stream);
    hipMemcpyAsync(cur1, rptr, N_ATOMS * sizeof(int), hipMemcpyDeviceToDevice, stream);
    scat_col_k<<<EB, 256, 0, stream>>>(row, col, dist, cur0, cother, cdist);
    scat_row_k<<<EB, 256, 0, stream>>>(row, col, dist, cur1, rother, reid, rdist);
  }

  // ---------------- build filter tables (all 4 layers) ----------------
  {
    const size_t LNH = (size_t)NN * HD;
    float* Anode  = agg;
    float* dAnode = agg + LNH;
    float* t1 = dgb;
    float* u  = g0b;
    float* s  = g1b;
    float* sp = hA;
    nodeA_k<<<((int)LNH + 255) / 256, 256, 0, stream>>>(Anode, dAnode, NN, hstep);
    dim3 gB(nblk(NN), NLAY);
    gemm128b_k<<<gB, 256, 0, stream>>>(Anode, 0, mlp_w1, (size_t)HD*HD,
                                       mlp_b1, HD, t1, LNH, NN);
    gemm128b_k<<<gB, 256, 0, stream>>>(dAnode, 0, mlp_w1, (size_t)HD*HD,
                                       nullptr, 0, u, LNH, NN);
    int tot = (int)(NLAY * LNH);
    nodeact_k<<<(tot + 255) / 256, 256, 0, stream>>>(t1, u, s, sp, tot);
    float* P0 = dgb;
    float* D0 = g0b;
    gemm128b_k<<<gB, 256, 0, stream>>>(s, LNH, mlp_w2, (size_t)HD*HD,
                                       mlp_b2, HD, P0, LNH, NN);
    gemm128b_k<<<gB, 256, 0, stream>>>(sp, LNH, mlp_w2, (size_t)HD*HD,
                                       nullptr, 0, D0, LNH, NN);
    nodecomb_k<<<(tot + 255) / 256, 256, 0, stream>>>(P0, D0, T, NN, hstep);
  }

  h0_k<<<(N_ATOMS * HD + 255) / 256, 256, 0, stream>>>(emb, z, hA);

  const int AB = (N_ATOMS + 3) / 4;   // gather blocks (4 waves = 4 atoms each)

  // ---------------- forward ----------------
  float* hcur = hA;
  float* hnxt = hB;
  for (int i = 0; i < NLAY; i++) {
    const float* l1 = lin1_w + (size_t)i * HD * HD;
    const float* l2 = lin2_w + (size_t)i * HD * HD;
    const float* l2b = lin2_b + (size_t)i * HD;
    const float* bw = blk_w + (size_t)i * HD * HD;
    const float* bb = blk_b + (size_t)i * HD;
    const float* Tl = T + (size_t)i * NN * HD * 2;

    gemm128_k<0,0,false><<<nblk(N_ATOMS), 256, 0, stream>>>(hcur, l1, nullptr, nullptr, hxb[i], N_ATOMS);
    gath_fwd_k<<<AB, 256, 0, stream>>>(cptr, cother, cdist, Tl, hxb[i], agg, inv_h, hstep);
    gemm128_k<0,0,false><<<nblk(N_ATOMS), 256, 0, stream>>>(agg, l2, l2b, nullptr, vbuf[i], N_ATOMS);
    gemm128_k<1,1,false><<<nblk(N_ATOMS), 256, 0, stream>>>(vbuf[i], bw, bb, hcur, hnxt, N_ATOMS);
    float* tmp = hcur; hcur = hnxt; hnxt = tmp;
  }

  head_k<<<N_ATOMS, 128, 0, stream>>>(hcur, hw1, hb1, hw2, hb2, batch, out, g0b);

  // ---------------- backward ----------------
  float* gcur = g0b;
  float* gnxt = g1b;
  for (int i = NLAY - 1; i >= 0; i--) {
    const float* l1 = lin1_w + (size_t)i * HD * HD;
    const float* l2 = lin2_w + (size_t)i * HD * HD;
    const float* bw = blk_w + (size_t)i * HD * HD;
    const float* Tl = T + (size_t)i * NN * HD * 2;
    float* dvb = gnxt;

    // dv = (g @ bw^T) * sigmoid(v_i)
    gemm128_k<0,2,true><<<nblk(N_ATOMS), 256, 0, stream>>>(gcur, bw, nullptr, vbuf[i], dvb, N_ATOMS);
    // dagg = dv @ l2^T
    gemm128_k<0,0,true><<<nblk(N_ATOMS), 256, 0, stream>>>(dvb, l2, nullptr, nullptr, dgb, N_ATOMS);
    // edge backward: dhx (into agg) + dd, gather form
    gath_bwd_k<<<AB, 256, 0, stream>>>(rptr, rother, reid, rdist, Tl, dgb, hxb[i], agg, dd, inv_h, hstep);
    if (i > 0) {
      // dh_i = g + dhx @ l1^T
      gemm128_k<0,1,true><<<nblk(N_ATOMS), 256, 0, stream>>>(agg, l1, nullptr, gcur, gnxt, N_ATOMS);
      float* tmp = gcur; gcur = gnxt; gnxt = tmp;
    }
  }

  force_k<<<(N_EDGES + 255) / 256, 256, 0, stream>>>(row, col, pos, dist, dd, out + NMOL);
}

// Round 4
// 1420.103 us; speedup vs baseline: 5.6466x; 1.1749x over previous
//
#include <hip/hip_runtime.h>

#define HD 128

constexpr int N_ATOMS = 20000;
constexpr int N_EDGES = 320000;
constexpr int NLAY   = 4;
constexpr int NMOL   = 200;
constexpr float FCUT  = 5.0f;
constexpr float DELTA = FCUT / 127.0f;
constexpr float GCOEFF = -0.5f / (DELTA * DELTA);
constexpr float PI_F  = 3.14159265358979323846f;
constexpr float LN2F  = 0.6931471805599453f;

__device__ __forceinline__ float sspf(float x) {
  return fmaxf(x, 0.0f) + log1pf(expf(-fabsf(x))) - LN2F;
}
__device__ __forceinline__ float sigmf(float x) {
  return 1.0f / (1.0f + expf(-x));
}

// ------------------------------------------------------------------
// small elementwise kernels
// ------------------------------------------------------------------

__global__ __launch_bounds__(256) void geom_k(
    const float* __restrict__ pos, const int* __restrict__ row,
    const int* __restrict__ col, float* __restrict__ dist)
{
  int e = blockIdx.x * 256 + threadIdx.x;
  if (e >= N_EDGES) return;
  int r = row[e], c = col[e];
  float dx = pos[3*r+0] - pos[3*c+0];
  float dy = pos[3*r+1] - pos[3*c+1];
  float dz = pos[3*r+2] - pos[3*c+2];
  dist[e] = sqrtf(dx*dx + dy*dy + dz*dz);
}

__global__ __launch_bounds__(256) void h0_k(
    const float* __restrict__ emb, const int* __restrict__ z,
    float* __restrict__ h0)
{
  int i = blockIdx.x * 256 + threadIdx.x;
  if (i >= N_ATOMS * HD) return;
  int n = i >> 7, k = i & 127;
  h0[i] = emb[z[n] * HD + k];
}

// ------------------------------------------------------------------
// CSR build: histogram, scan, scatter
// ------------------------------------------------------------------
__global__ __launch_bounds__(256) void hist_k(
    const int* __restrict__ idx, int* __restrict__ cnt)
{
  int e = blockIdx.x * 256 + threadIdx.x;
  if (e >= N_EDGES) return;
  atomicAdd(&cnt[idx[e]], 1);
}

__global__ __launch_bounds__(256) void scan_k(
    const int* __restrict__ cnt, int* __restrict__ ptr)
{
  constexpr int CH = 79;  // 256*79 = 20224 >= 20001
  __shared__ int part[256];
  int t = threadIdx.x;
  int base = t * CH;
  int s = 0;
  for (int i = 0; i < CH; i++) {
    int idx = base + i;
    if (idx < N_ATOMS) s += cnt[idx];
  }
  part[t] = s;
  __syncthreads();
  for (int off = 1; off < 256; off <<= 1) {
    int u = (t >= off) ? part[t - off] : 0;
    __syncthreads();
    part[t] += u;
    __syncthreads();
  }
  int run = part[t] - s;
  for (int i = 0; i < CH; i++) {
    int idx = base + i;
    if (idx > N_ATOMS) break;
    ptr[idx] = run;
    if (idx < N_ATOMS) run += cnt[idx];
  }
}

__global__ __launch_bounds__(256) void scat_col_k(
    const int* __restrict__ row, const int* __restrict__ col,
    const float* __restrict__ dist, int* __restrict__ cur,
    int* __restrict__ cother, float* __restrict__ cdist)
{
  int e = blockIdx.x * 256 + threadIdx.x;
  if (e >= N_EDGES) return;
  int p = atomicAdd(&cur[col[e]], 1);
  cother[p] = row[e];
  cdist[p] = dist[e];
}

__global__ __launch_bounds__(256) void scat_row_k(
    const int* __restrict__ row, const int* __restrict__ col,
    const float* __restrict__ dist, int* __restrict__ cur,
    int* __restrict__ rother, int* __restrict__ reid,
    float* __restrict__ rdist)
{
  int e = blockIdx.x * 256 + threadIdx.x;
  if (e >= N_EDGES) return;
  int p = atomicAdd(&cur[row[e]], 1);
  rother[p] = col[e];
  reid[p] = e;
  rdist[p] = dist[e];
}

// ------------------------------------------------------------------
// table build
// ------------------------------------------------------------------
__global__ __launch_bounds__(256) void nodeA_k(
    float* __restrict__ A, float* __restrict__ dA, int nnode, float hstep)
{
  int i = blockIdx.x * 256 + threadIdx.x;
  if (i >= nnode * HD) return;
  int node = i >> 7, g = i & 127;
  float d = (float)node * hstep;
  float t = d - (float)g * DELTA;
  float a = expf(GCOEFF * t * t);
  A[i] = a;
  dA[i] = a * 2.0f * GCOEFF * t;
}

__global__ __launch_bounds__(256) void nodeact_k(
    const float* __restrict__ t1, const float* __restrict__ u,
    float* __restrict__ s, float* __restrict__ sp, int total)
{
  int i = blockIdx.x * 256 + threadIdx.x;
  if (i >= total) return;
  float x = t1[i];
  s[i] = sspf(x);
  sp[i] = sigmf(x) * u[i];
}

__global__ __launch_bounds__(256) void nodecomb_k(
    const float* __restrict__ P0, const float* __restrict__ D0,
    float* __restrict__ T, int nnode, float hstep)
{
  int i = blockIdx.x * 256 + threadIdx.x;
  int total = NLAY * nnode * HD;
  if (i >= total) return;
  int rem = i % (nnode * HD);
  int node = rem >> 7;
  float d = (float)node * hstep;
  float C  = 0.5f * cosf(d * (PI_F / FCUT)) + 0.5f;
  float Cp = -0.5f * sinf(d * (PI_F / FCUT)) * (PI_F / FCUT);
  float p = P0[i], q = D0[i];
  T[(size_t)i * 2 + 0] = p * C;
  T[(size_t)i * 2 + 1] = q * C + p * Cp;
}

// ------------------------------------------------------------------
// generic fp32 GEMM: C[M,128] = epi( A[M,128] @ B(^T) + bias )
// EPI: 0: acc+bias   1: acc+bias+EP1
// ------------------------------------------------------------------
template<int EPI, bool BT>
__global__ __launch_bounds__(256) void gemm128_k(
    const float* __restrict__ A, const float* __restrict__ B,
    const float* __restrict__ bias, const float* __restrict__ EP1,
    float* __restrict__ C, int M)
{
  __shared__ float As[16][68];
  __shared__ float Bs[16][132];
  int t = threadIdx.x;
  int tx = t & 15, ty = t >> 4;
  int m0 = blockIdx.x * 64;

  float acc[4][8];
#pragma unroll
  for (int r = 0; r < 4; r++)
#pragma unroll
    for (int c = 0; c < 8; c++) acc[r][c] = 0.0f;

  for (int k0 = 0; k0 < HD; k0 += 16) {
    {
      int rrow = t >> 2;
      int kg = (t & 3) * 4;
      int gm = m0 + rrow;
      float4 av = make_float4(0.f, 0.f, 0.f, 0.f);
      if (gm < M) av = *(const float4*)(A + (size_t)gm * HD + k0 + kg);
      As[kg+0][rrow] = av.x; As[kg+1][rrow] = av.y;
      As[kg+2][rrow] = av.z; As[kg+3][rrow] = av.w;
    }
    if (!BT) {
#pragma unroll
      for (int it = 0; it < 2; it++) {
        int f4 = t + it * 256;
        int kk = f4 >> 5;
        int n4 = (f4 & 31) * 4;
        float4 bv = *(const float4*)(B + (size_t)(k0 + kk) * HD + n4);
        *(float4*)&Bs[kk][n4] = bv;
      }
    } else {
#pragma unroll
      for (int it = 0; it < 2; it++) {
        int idx = t + it * 256;
        int n = idx >> 2;
        int kg = (idx & 3) * 4;
        float4 bv = *(const float4*)(B + (size_t)n * HD + k0 + kg);
        Bs[kg+0][n] = bv.x; Bs[kg+1][n] = bv.y;
        Bs[kg+2][n] = bv.z; Bs[kg+3][n] = bv.w;
      }
    }
    __syncthreads();
#pragma unroll
    for (int kk = 0; kk < 16; kk++) {
      float a[4], b[8];
#pragma unroll
      for (int r = 0; r < 4; r++) a[r] = As[kk][ty * 4 + r];
#pragma unroll
      for (int c = 0; c < 8; c++) b[c] = Bs[kk][tx * 8 + c];
#pragma unroll
      for (int r = 0; r < 4; r++)
#pragma unroll
        for (int c = 0; c < 8; c++) acc[r][c] = fmaf(a[r], b[c], acc[r][c]);
    }
    __syncthreads();
  }

  int n0 = tx * 8;
  float bv[8];
#pragma unroll
  for (int c = 0; c < 8; c++) bv[c] = bias ? bias[n0 + c] : 0.0f;
#pragma unroll
  for (int r = 0; r < 4; r++) {
    int gm = m0 + ty * 4 + r;
    if (gm >= M) continue;
    float out[8];
#pragma unroll
    for (int c = 0; c < 8; c++) {
      float x = acc[r][c] + bv[c];
      if (EPI == 1) x += EP1[(size_t)gm * HD + n0 + c];
      out[c] = x;
    }
    *(float4*)(C + (size_t)gm * HD + n0)     = *(float4*)&out[0];
    *(float4*)(C + (size_t)gm * HD + n0 + 4) = *(float4*)&out[4];
  }
}

// batched (over blockIdx.y = layer) plain GEMM for table build
__global__ __launch_bounds__(256) void gemm128b_k(
    const float* __restrict__ A, size_t astride,
    const float* __restrict__ B, size_t bstride,
    const float* __restrict__ bias, size_t biasstride,
    float* __restrict__ C, size_t cstride, int M)
{
  int l = blockIdx.y;
  A += (size_t)l * astride;
  B += (size_t)l * bstride;
  if (bias) bias += (size_t)l * biasstride;
  C += (size_t)l * cstride;

  __shared__ float As[16][68];
  __shared__ float Bs[16][132];
  int t = threadIdx.x;
  int tx = t & 15, ty = t >> 4;
  int m0 = blockIdx.x * 64;

  float acc[4][8];
#pragma unroll
  for (int r = 0; r < 4; r++)
#pragma unroll
    for (int c = 0; c < 8; c++) acc[r][c] = 0.0f;

  for (int k0 = 0; k0 < HD; k0 += 16) {
    {
      int rrow = t >> 2;
      int kg = (t & 3) * 4;
      int gm = m0 + rrow;
      float4 av = make_float4(0.f, 0.f, 0.f, 0.f);
      if (gm < M) av = *(const float4*)(A + (size_t)gm * HD + k0 + kg);
      As[kg+0][rrow] = av.x; As[kg+1][rrow] = av.y;
      As[kg+2][rrow] = av.z; As[kg+3][rrow] = av.w;
    }
#pragma unroll
    for (int it = 0; it < 2; it++) {
      int f4 = t + it * 256;
      int kk = f4 >> 5;
      int n4 = (f4 & 31) * 4;
      float4 bv = *(const float4*)(B + (size_t)(k0 + kk) * HD + n4);
      *(float4*)&Bs[kk][n4] = bv;
    }
    __syncthreads();
#pragma unroll
    for (int kk = 0; kk < 16; kk++) {
      float a[4], b[8];
#pragma unroll
      for (int r = 0; r < 4; r++) a[r] = As[kk][ty * 4 + r];
#pragma unroll
      for (int c = 0; c < 8; c++) b[c] = Bs[kk][tx * 8 + c];
#pragma unroll
      for (int r = 0; r < 4; r++)
#pragma unroll
        for (int c = 0; c < 8; c++) acc[r][c] = fmaf(a[r], b[c], acc[r][c]);
    }
    __syncthreads();
  }

  int n0 = tx * 8;
  float bv[8];
#pragma unroll
  for (int c = 0; c < 8; c++) bv[c] = bias ? bias[n0 + c] : 0.0f;
#pragma unroll
  for (int r = 0; r < 4; r++) {
    int gm = m0 + ty * 4 + r;
    if (gm >= M) continue;
    float out[8];
#pragma unroll
    for (int c = 0; c < 8; c++) out[c] = acc[r][c] + bv[c];
    *(float4*)(C + (size_t)gm * HD + n0)     = *(float4*)&out[0];
    *(float4*)(C + (size_t)gm * HD + n0 + 4) = *(float4*)&out[4];
  }
}

// ------------------------------------------------------------------
// fused fwd tail: V = agg@l2 + l2b (store), h' = h + ssp(V)@bw + bb
// ------------------------------------------------------------------
__global__ __launch_bounds__(256) void ftail_k(
    const float* __restrict__ agg, const float* __restrict__ l2,
    const float* __restrict__ l2b, const float* __restrict__ bw,
    const float* __restrict__ bb, const float* __restrict__ h,
    float* __restrict__ vbuf, float* __restrict__ hout, int M)
{
  __shared__ float As[16][68];
  __shared__ float Bs[16][132];
  __shared__ float Ss[64][132];
  int t = threadIdx.x;
  int tx = t & 15, ty = t >> 4;
  int m0 = blockIdx.x * 64;

  float acc[4][8];
#pragma unroll
  for (int r = 0; r < 4; r++)
#pragma unroll
    for (int c = 0; c < 8; c++) acc[r][c] = 0.0f;

  // phase 1: V = agg @ l2
  for (int k0 = 0; k0 < HD; k0 += 16) {
    {
      int rrow = t >> 2;
      int kg = (t & 3) * 4;
      int gm = m0 + rrow;
      float4 av = make_float4(0.f, 0.f, 0.f, 0.f);
      if (gm < M) av = *(const float4*)(agg + (size_t)gm * HD + k0 + kg);
      As[kg+0][rrow] = av.x; As[kg+1][rrow] = av.y;
      As[kg+2][rrow] = av.z; As[kg+3][rrow] = av.w;
    }
#pragma unroll
    for (int it = 0; it < 2; it++) {
      int f4 = t + it * 256;
      int kk = f4 >> 5;
      int n4 = (f4 & 31) * 4;
      float4 bv = *(const float4*)(l2 + (size_t)(k0 + kk) * HD + n4);
      *(float4*)&Bs[kk][n4] = bv;
    }
    __syncthreads();
#pragma unroll
    for (int kk = 0; kk < 16; kk++) {
      float a[4], b[8];
#pragma unroll
      for (int r = 0; r < 4; r++) a[r] = As[kk][ty * 4 + r];
#pragma unroll
      for (int c = 0; c < 8; c++) b[c] = Bs[kk][tx * 8 + c];
#pragma unroll
      for (int r = 0; r < 4; r++)
#pragma unroll
        for (int c = 0; c < 8; c++) acc[r][c] = fmaf(a[r], b[c], acc[r][c]);
    }
    __syncthreads();
  }

  // epilogue 1: write V, stash ssp(V) in LDS
  int n0 = tx * 8;
  {
    float l2bv[8];
#pragma unroll
    for (int c = 0; c < 8; c++) l2bv[c] = l2b[n0 + c];
#pragma unroll
    for (int r = 0; r < 4; r++) {
      int lr = ty * 4 + r;
      int gm = m0 + lr;
      float vv[8];
#pragma unroll
      for (int c = 0; c < 8; c++) {
        float x = acc[r][c] + l2bv[c];
        vv[c] = x;
        Ss[lr][n0 + c] = sspf(x);
      }
      if (gm < M) {
        *(float4*)(vbuf + (size_t)gm * HD + n0)     = *(float4*)&vv[0];
        *(float4*)(vbuf + (size_t)gm * HD + n0 + 4) = *(float4*)&vv[4];
      }
    }
  }
  __syncthreads();

  // phase 2: h' = h + ssp(V) @ bw + bb
#pragma unroll
  for (int r = 0; r < 4; r++)
#pragma unroll
    for (int c = 0; c < 8; c++) acc[r][c] = 0.0f;

  for (int k0 = 0; k0 < HD; k0 += 16) {
#pragma unroll
    for (int it = 0; it < 2; it++) {
      int f4 = t + it * 256;
      int kk = f4 >> 5;
      int n4 = (f4 & 31) * 4;
      float4 bv = *(const float4*)(bw + (size_t)(k0 + kk) * HD + n4);
      *(float4*)&Bs[kk][n4] = bv;
    }
    __syncthreads();
#pragma unroll
    for (int kk = 0; kk < 16; kk++) {
      float a[4], b[8];
#pragma unroll
      for (int r = 0; r < 4; r++) a[r] = Ss[ty * 4 + r][k0 + kk];
#pragma unroll
      for (int c = 0; c < 8; c++) b[c] = Bs[kk][tx * 8 + c];
#pragma unroll
      for (int r = 0; r < 4; r++)
#pragma unroll
        for (int c = 0; c < 8; c++) acc[r][c] = fmaf(a[r], b[c], acc[r][c]);
    }
    __syncthreads();
  }

  {
    float bbv[8];
#pragma unroll
    for (int c = 0; c < 8; c++) bbv[c] = bb[n0 + c];
#pragma unroll
    for (int r = 0; r < 4; r++) {
      int gm = m0 + ty * 4 + r;
      if (gm >= M) continue;
      float ov[8];
      float4 h0v = *(const float4*)(h + (size_t)gm * HD + n0);
      float4 h1v = *(const float4*)(h + (size_t)gm * HD + n0 + 4);
      ov[0] = acc[r][0] + bbv[0] + h0v.x;
      ov[1] = acc[r][1] + bbv[1] + h0v.y;
      ov[2] = acc[r][2] + bbv[2] + h0v.z;
      ov[3] = acc[r][3] + bbv[3] + h0v.w;
      ov[4] = acc[r][4] + bbv[4] + h1v.x;
      ov[5] = acc[r][5] + bbv[5] + h1v.y;
      ov[6] = acc[r][6] + bbv[6] + h1v.z;
      ov[7] = acc[r][7] + bbv[7] + h1v.w;
      *(float4*)(hout + (size_t)gm * HD + n0)     = *(float4*)&ov[0];
      *(float4*)(hout + (size_t)gm * HD + n0 + 4) = *(float4*)&ov[4];
    }
  }
}

// ------------------------------------------------------------------
// fused bwd head: dv = (g@bw^T)*sigm(v), dagg = dv@l2^T
// ------------------------------------------------------------------
__global__ __launch_bounds__(256) void bhead_k(
    const float* __restrict__ g, const float* __restrict__ bw,
    const float* __restrict__ v, const float* __restrict__ l2,
    float* __restrict__ dagg, int M)
{
  __shared__ float As[16][68];
  __shared__ float Bs[16][132];
  __shared__ float Ss[64][132];
  int t = threadIdx.x;
  int tx = t & 15, ty = t >> 4;
  int m0 = blockIdx.x * 64;

  float acc[4][8];
#pragma unroll
  for (int r = 0; r < 4; r++)
#pragma unroll
    for (int c = 0; c < 8; c++) acc[r][c] = 0.0f;

  // phase 1: X = g @ bw^T
  for (int k0 = 0; k0 < HD; k0 += 16) {
    {
      int rrow = t >> 2;
      int kg = (t & 3) * 4;
      int gm = m0 + rrow;
      float4 av = make_float4(0.f, 0.f, 0.f, 0.f);
      if (gm < M) av = *(const float4*)(g + (size_t)gm * HD + k0 + kg);
      As[kg+0][rrow] = av.x; As[kg+1][rrow] = av.y;
      As[kg+2][rrow] = av.z; As[kg+3][rrow] = av.w;
    }
#pragma unroll
    for (int it = 0; it < 2; it++) {
      int idx = t + it * 256;
      int n = idx >> 2;
      int kg = (idx & 3) * 4;
      float4 bv = *(const float4*)(bw + (size_t)n * HD + k0 + kg);
      Bs[kg+0][n] = bv.x; Bs[kg+1][n] = bv.y;
      Bs[kg+2][n] = bv.z; Bs[kg+3][n] = bv.w;
    }
    __syncthreads();
#pragma unroll
    for (int kk = 0; kk < 16; kk++) {
      float a[4], b[8];
#pragma unroll
      for (int r = 0; r < 4; r++) a[r] = As[kk][ty * 4 + r];
#pragma unroll
      for (int c = 0; c < 8; c++) b[c] = Bs[kk][tx * 8 + c];
#pragma unroll
      for (int r = 0; r < 4; r++)
#pragma unroll
        for (int c = 0; c < 8; c++) acc[r][c] = fmaf(a[r], b[c], acc[r][c]);
    }
    __syncthreads();
  }

  // epilogue 1: dv = X * sigm(v) into LDS
  int n0 = tx * 8;
#pragma unroll
  for (int r = 0; r < 4; r++) {
    int lr = ty * 4 + r;
    int gm = m0 + lr;
    float4 v0v = make_float4(0.f,0.f,0.f,0.f), v1v = make_float4(0.f,0.f,0.f,0.f);
    if (gm < M) {
      v0v = *(const float4*)(v + (size_t)gm * HD + n0);
      v1v = *(const float4*)(v + (size_t)gm * HD + n0 + 4);
    }
    Ss[lr][n0 + 0] = acc[r][0] * sigmf(v0v.x);
    Ss[lr][n0 + 1] = acc[r][1] * sigmf(v0v.y);
    Ss[lr][n0 + 2] = acc[r][2] * sigmf(v0v.z);
    Ss[lr][n0 + 3] = acc[r][3] * sigmf(v0v.w);
    Ss[lr][n0 + 4] = acc[r][4] * sigmf(v1v.x);
    Ss[lr][n0 + 5] = acc[r][5] * sigmf(v1v.y);
    Ss[lr][n0 + 6] = acc[r][6] * sigmf(v1v.z);
    Ss[lr][n0 + 7] = acc[r][7] * sigmf(v1v.w);
  }
  __syncthreads();

  // phase 2: dagg = dv @ l2^T
#pragma unroll
  for (int r = 0; r < 4; r++)
#pragma unroll
    for (int c = 0; c < 8; c++) acc[r][c] = 0.0f;

  for (int k0 = 0; k0 < HD; k0 += 16) {
#pragma unroll
    for (int it = 0; it < 2; it++) {
      int idx = t + it * 256;
      int n = idx >> 2;
      int kg = (idx & 3) * 4;
      float4 bv = *(const float4*)(l2 + (size_t)n * HD + k0 + kg);
      Bs[kg+0][n] = bv.x; Bs[kg+1][n] = bv.y;
      Bs[kg+2][n] = bv.z; Bs[kg+3][n] = bv.w;
    }
    __syncthreads();
#pragma unroll
    for (int kk = 0; kk < 16; kk++) {
      float a[4], b[8];
#pragma unroll
      for (int r = 0; r < 4; r++) a[r] = Ss[ty * 4 + r][k0 + kk];
#pragma unroll
      for (int c = 0; c < 8; c++) b[c] = Bs[kk][tx * 8 + c];
#pragma unroll
      for (int r = 0; r < 4; r++)
#pragma unroll
        for (int c = 0; c < 8; c++) acc[r][c] = fmaf(a[r], b[c], acc[r][c]);
    }
    __syncthreads();
  }

#pragma unroll
  for (int r = 0; r < 4; r++) {
    int gm = m0 + ty * 4 + r;
    if (gm >= M) continue;
    *(float4*)(dagg + (size_t)gm * HD + n0)     = *(float4*)&acc[r][0];
    *(float4*)(dagg + (size_t)gm * HD + n0 + 4) = *(float4*)&acc[r][4];
  }
}

// ------------------------------------------------------------------
// forward gather: agg[a] = sum_in hx[src] * P(d); 32 lanes x 4ch,
// two half-waves split the edge list
// ------------------------------------------------------------------
__global__ __launch_bounds__(256) void gath_fwd_k(
    const int* __restrict__ cptr, const int* __restrict__ cother,
    const float* __restrict__ cdist, const float* __restrict__ T,
    const float* __restrict__ hx, float* __restrict__ agg,
    float inv_h, float hstep)
{
  int a = blockIdx.x * 4 + (threadIdx.x >> 6);
  if (a >= N_ATOMS) return;
  int half = (threadIdx.x >> 5) & 1;
  int ch = (threadIdx.x & 31) * 4;
  int beg = cptr[a], end = cptr[a + 1];
  float s0 = 0.f, s1 = 0.f, s2 = 0.f, s3 = 0.f;
  for (int j = beg + half; j < end; j += 2) {
    int other = cother[j];
    float d = cdist[j];
    float fi = d * inv_h;
    int i0 = (int)fi;
    float t = fi - (float)i0;
    float t2 = t * t, t3 = t2 * t;
    float a00 = 2.f*t3 - 3.f*t2 + 1.f;
    float a10 = (t3 - 2.f*t2 + t) * hstep;
    float a01 = 3.f*t2 - 2.f*t3;
    float a11 = (t3 - t2) * hstep;
    const float* tp = T + ((size_t)i0 * HD + ch) * 2;
    float4 q0a = *(const float4*)(tp);
    float4 q0b = *(const float4*)(tp + 4);
    float4 q1a = *(const float4*)(tp + 2 * HD);
    float4 q1b = *(const float4*)(tp + 2 * HD + 4);
    float4 hv = *(const float4*)(hx + (size_t)other * HD + ch);
    float v0 = a00*q0a.x + a10*q0a.y + a01*q1a.x + a11*q1a.y;
    float v1 = a00*q0a.z + a10*q0a.w + a01*q1a.z + a11*q1a.w;
    float v2 = a00*q0b.x + a10*q0b.y + a01*q1b.x + a11*q1b.y;
    float v3 = a00*q0b.z + a10*q0b.w + a01*q1b.z + a11*q1b.w;
    s0 = fmaf(hv.x, v0, s0);
    s1 = fmaf(hv.y, v1, s1);
    s2 = fmaf(hv.z, v2, s2);
    s3 = fmaf(hv.w, v3, s3);
  }
  s0 += __shfl_xor(s0, 32, 64);
  s1 += __shfl_xor(s1, 32, 64);
  s2 += __shfl_xor(s2, 32, 64);
  s3 += __shfl_xor(s3, 32, 64);
  if (half == 0)
    *(float4*)(agg + (size_t)a * HD + ch) = make_float4(s0, s1, s2, s3);
}

// ------------------------------------------------------------------
// backward gather: dhx[a] = sum_out dagg[dst]*P; dd[e] += <dagg,hx[a]*P'>
// ------------------------------------------------------------------
__global__ __launch_bounds__(256) void gath_bwd_k(
    const int* __restrict__ rptr, const int* __restrict__ rother,
    const int* __restrict__ reid, const float* __restrict__ rdist,
    const float* __restrict__ T, const float* __restrict__ dagg,
    const float* __restrict__ hx, float* __restrict__ dhx,
    float* __restrict__ dd, float inv_h, float hstep)
{
  int a = blockIdx.x * 4 + (threadIdx.x >> 6);
  if (a >= N_ATOMS) return;
  int half = (threadIdx.x >> 5) & 1;
  int l32 = threadIdx.x & 31;
  int ch = l32 * 4;
  int beg = rptr[a], end = rptr[a + 1];
  float4 hv = *(const float4*)(hx + (size_t)a * HD + ch);
  float s0 = 0.f, s1 = 0.f, s2 = 0.f, s3 = 0.f;
  for (int j = beg + half; j < end; j += 2) {
    int other = rother[j];
    int eid = reid[j];
    float d = rdist[j];
    float fi = d * inv_h;
    int i0 = (int)fi;
    float t = fi - (float)i0;
    float t2 = t * t, t3 = t2 * t;
    float a00 = 2.f*t3 - 3.f*t2 + 1.f;
    float a10 = (t3 - 2.f*t2 + t) * hstep;
    float a01 = 3.f*t2 - 2.f*t3;
    float a11 = (t3 - t2) * hstep;
    float b00 = (6.f*t2 - 6.f*t) * inv_h;
    float b10 = 3.f*t2 - 4.f*t + 1.f;
    float b01 = -b00;
    float b11 = 3.f*t2 - 2.f*t;
    const float* tp = T + ((size_t)i0 * HD + ch) * 2;
    float4 q0a = *(const float4*)(tp);
    float4 q0b = *(const float4*)(tp + 4);
    float4 q1a = *(const float4*)(tp + 2 * HD);
    float4 q1b = *(const float4*)(tp + 2 * HD + 4);
    float4 da = *(const float4*)(dagg + (size_t)other * HD + ch);
    float v0 = a00*q0a.x + a10*q0a.y + a01*q1a.x + a11*q1a.y;
    float v1 = a00*q0a.z + a10*q0a.w + a01*q1a.z + a11*q1a.w;
    float v2 = a00*q0b.x + a10*q0b.y + a01*q1b.x + a11*q1b.y;
    float v3 = a00*q0b.z + a10*q0b.w + a01*q1b.z + a11*q1b.w;
    float g0 = b00*q0a.x + b10*q0a.y + b01*q1a.x + b11*q1a.y;
    float g1 = b00*q0a.z + b10*q0a.w + b01*q1a.z + b11*q1a.w;
    float g2 = b00*q0b.x + b10*q0b.y + b01*q1b.x + b11*q1b.y;
    float g3 = b00*q0b.z + b10*q0b.w + b01*q1b.z + b11*q1b.w;
    s0 = fmaf(da.x, v0, s0);
    s1 = fmaf(da.y, v1, s1);
    s2 = fmaf(da.z, v2, s2);
    s3 = fmaf(da.w, v3, s3);
    float dot = da.x*hv.x*g0 + da.y*hv.y*g1 + da.z*hv.z*g2 + da.w*hv.w*g3;
#pragma unroll
    for (int off = 16; off > 0; off >>= 1) dot += __shfl_down(dot, off, 32);
    if (l32 == 0) dd[eid] += dot;
  }
  s0 += __shfl_xor(s0, 32, 64);
  s1 += __shfl_xor(s1, 32, 64);
  s2 += __shfl_xor(s2, 32, 64);
  s3 += __shfl_xor(s3, 32, 64);
  if (half == 0)
    *(float4*)(dhx + (size_t)a * HD + ch) = make_float4(s0, s1, s2, s3);
}

// ------------------------------------------------------------------
// head part 1: s = h4@hw1 + hb1 (64x64 tile, K=128);
// energy += ssp(s)@hw2 + hb2 per atom; cs = sigm(s)*hw2
// ------------------------------------------------------------------
__global__ __launch_bounds__(256) void head1_k(
    const float* __restrict__ h4, const float* __restrict__ hw1,
    const float* __restrict__ hb1, const float* __restrict__ hw2,
    const float* __restrict__ hb2, const int* __restrict__ batch,
    float* __restrict__ energy, float* __restrict__ cs)
{
  __shared__ float As[16][68];
  __shared__ float Bs[16][68];
  __shared__ float red[64][17];
  int t = threadIdx.x;
  int tx = t & 15, ty = t >> 4;
  int m0 = blockIdx.x * 64;

  float acc[4][4];
#pragma unroll
  for (int r = 0; r < 4; r++)
#pragma unroll
    for (int c = 0; c < 4; c++) acc[r][c] = 0.0f;

  for (int k0 = 0; k0 < HD; k0 += 16) {
    {
      int rrow = t >> 2;
      int kg = (t & 3) * 4;
      int gm = m0 + rrow;
      float4 av = make_float4(0.f, 0.f, 0.f, 0.f);
      if (gm < N_ATOMS) av = *(const float4*)(h4 + (size_t)gm * HD + k0 + kg);
      As[kg+0][rrow] = av.x; As[kg+1][rrow] = av.y;
      As[kg+2][rrow] = av.z; As[kg+3][rrow] = av.w;
    }
    {
      int kk = t >> 4;
      int n4 = (t & 15) * 4;
      float4 bv = *(const float4*)(hw1 + (size_t)(k0 + kk) * 64 + n4);
      *(float4*)&Bs[kk][n4] = bv;
    }
    __syncthreads();
#pragma unroll
    for (int kk = 0; kk < 16; kk++) {
      float a[4], b[4];
#pragma unroll
      for (int r = 0; r < 4; r++) a[r] = As[kk][ty * 4 + r];
#pragma unroll
      for (int c = 0; c < 4; c++) b[c] = Bs[kk][tx * 4 + c];
#pragma unroll
      for (int r = 0; r < 4; r++)
#pragma unroll
        for (int c = 0; c < 4; c++) acc[r][c] = fmaf(a[r], b[c], acc[r][c]);
    }
    __syncthreads();
  }

  int n0 = tx * 4;
  float b1v[4], w2v[4];
#pragma unroll
  for (int c = 0; c < 4; c++) { b1v[c] = hb1[n0 + c]; w2v[c] = hw2[n0 + c]; }
  float hb2v = hb2[0];

#pragma unroll
  for (int r = 0; r < 4; r++) {
    int gm = m0 + ty * 4 + r;
    float p = 0.0f;
    float c4[4];
#pragma unroll
    for (int c = 0; c < 4; c++) {
      float x = acc[r][c] + b1v[c];
      p += sspf(x) * w2v[c];
      c4[c] = sigmf(x) * w2v[c];
    }
    if (gm < N_ATOMS)
      *(float4*)(cs + (size_t)gm * 64 + n0) = *(float4*)&c4[0];
    red[ty * 4 + r][tx] = p;
  }
  __syncthreads();
  if (t < 64) {
    int gm = m0 + t;
    if (gm < N_ATOMS) {
      float s = hb2v;
#pragma unroll
      for (int j = 0; j < 16; j++) s += red[t][j];
      atomicAdd(&energy[batch[gm]], s);
    }
  }
}

// ------------------------------------------------------------------
// head part 2: gh = cs @ hw1^T   (M x 128, K = 64)
// ------------------------------------------------------------------
__global__ __launch_bounds__(256) void head2_k(
    const float* __restrict__ cs, const float* __restrict__ hw1,
    float* __restrict__ gh, int M)
{
  __shared__ float As[16][68];
  __shared__ float Bs[16][132];
  int t = threadIdx.x;
  int tx = t & 15, ty = t >> 4;
  int m0 = blockIdx.x * 64;

  float acc[4][8];
#pragma unroll
  for (int r = 0; r < 4; r++)
#pragma unroll
    for (int c = 0; c < 8; c++) acc[r][c] = 0.0f;

  for (int j0 = 0; j0 < 64; j0 += 16) {
    {
      int rrow = t >> 2;
      int jg = (t & 3) * 4;
      int gm = m0 + rrow;
      float4 av = make_float4(0.f, 0.f, 0.f, 0.f);
      if (gm < M) av = *(const float4*)(cs + (size_t)gm * 64 + j0 + jg);
      As[jg+0][rrow] = av.x; As[jg+1][rrow] = av.y;
      As[jg+2][rrow] = av.z; As[jg+3][rrow] = av.w;
    }
#pragma unroll
    for (int it = 0; it < 2; it++) {
      int idx = t + it * 256;
      int n = idx >> 2;
      int jg = (idx & 3) * 4;
      float4 bv = *(const float4*)(hw1 + (size_t)n * 64 + j0 + jg);
      Bs[jg+0][n] = bv.x; Bs[jg+1][n] = bv.y;
      Bs[jg+2][n] = bv.z; Bs[jg+3][n] = bv.w;
    }
    __syncthreads();
#pragma unroll
    for (int kk = 0; kk < 16; kk++) {
      float a[4], b[8];
#pragma unroll
      for (int r = 0; r < 4; r++) a[r] = As[kk][ty * 4 + r];
#pragma unroll
      for (int c = 0; c < 8; c++) b[c] = Bs[kk][tx * 8 + c];
#pragma unroll
      for (int r = 0; r < 4; r++)
#pragma unroll
        for (int c = 0; c < 8; c++) acc[r][c] = fmaf(a[r], b[c], acc[r][c]);
    }
    __syncthreads();
  }

  int n0 = tx * 8;
#pragma unroll
  for (int r = 0; r < 4; r++) {
    int gm = m0 + ty * 4 + r;
    if (gm >= M) continue;
    *(float4*)(gh + (size_t)gm * HD + n0)     = *(float4*)&acc[r][0];
    *(float4*)(gh + (size_t)gm * HD + n0 + 4) = *(float4*)&acc[r][4];
  }
}

// ------------------------------------------------------------------
// final force scatter
// ------------------------------------------------------------------
__global__ __launch_bounds__(256) void force_k(
    const int* __restrict__ row, const int* __restrict__ col,
    const float* __restrict__ pos, const float* __restrict__ dist,
    const float* __restrict__ dd, float* __restrict__ force)
{
  int e = blockIdx.x * 256 + threadIdx.x;
  if (e >= N_EDGES) return;
  int r = row[e], c = col[e];
  float inv = dd[e] / dist[e];
  float fx = (pos[3*r+0] - pos[3*c+0]) * inv;
  float fy = (pos[3*r+1] - pos[3*c+1]) * inv;
  float fz = (pos[3*r+2] - pos[3*c+2]) * inv;
  atomicAdd(&force[3*r+0], -fx);
  atomicAdd(&force[3*r+1], -fy);
  atomicAdd(&force[3*r+2], -fz);
  atomicAdd(&force[3*c+0],  fx);
  atomicAdd(&force[3*c+1],  fy);
  atomicAdd(&force[3*c+2],  fz);
}

// ------------------------------------------------------------------
// host launch
// ------------------------------------------------------------------
static inline int nblk(int m) { return (m + 63) / 64; }

extern "C" void kernel_launch(void* const* d_in, const int* in_sizes, int n_in,
                              void* d_out, int out_size, void* d_ws, size_t ws_size,
                              hipStream_t stream)
{
  const float* pos   = (const float*)d_in[0];
  const int*   z     = (const int*)d_in[1];
  const int*   batch = (const int*)d_in[2];
  const int*   eidx  = (const int*)d_in[3];
  const float* emb   = (const float*)d_in[4];
  const float* mlp_w1 = (const float*)d_in[5];
  const float* mlp_b1 = (const float*)d_in[6];
  const float* mlp_w2 = (const float*)d_in[7];
  const float* mlp_b2 = (const float*)d_in[8];
  const float* lin1_w = (const float*)d_in[9];
  const float* lin2_w = (const float*)d_in[10];
  const float* lin2_b = (const float*)d_in[11];
  const float* blk_w  = (const float*)d_in[12];
  const float* blk_b  = (const float*)d_in[13];
  const float* hw1 = (const float*)d_in[14];
  const float* hb1 = (const float*)d_in[15];
  const float* hw2 = (const float*)d_in[16];
  const float* hb2 = (const float*)d_in[17];

  float* out = (float*)d_out;          // [NMOL] energies ++ [N,3] forces
  float* ws  = (float*)d_ws;

  const int* row = eidx;
  const int* col = eidx + N_EDGES;

  const size_t NH = (size_t)N_ATOMS * HD;
  size_t o = 0;
  float* dist = ws + o; o += N_EDGES;
  float* dd   = ws + o; o += N_EDGES;
  int* cptr   = (int*)(ws + o); o += N_ATOMS + 1;
  int* rptr   = (int*)(ws + o); o += N_ATOMS + 1;
  int* cother = (int*)(ws + o); o += N_EDGES;
  int* rother = (int*)(ws + o); o += N_EDGES;
  int* reid   = (int*)(ws + o); o += N_EDGES;
  float* cdist = ws + o; o += N_EDGES;
  float* rdist = ws + o; o += N_EDGES;
  int* cur0   = (int*)(ws + o); o += N_ATOMS;
  int* cur1   = (int*)(ws + o); o += N_ATOMS;
  float* hxb[4];
  for (int i = 0; i < 4; i++) { hxb[i] = ws + o; o += NH; }
  float* vbuf[4];
  for (int i = 0; i < 4; i++) { vbuf[i] = ws + o; o += NH; }
  float* hA  = ws + o; o += NH;
  float* hB  = ws + o; o += NH;
  float* agg = ws + o; o += NH;       // fwd agg / bwd dhx / table temps
  float* g0b = ws + o; o += NH;
  float* g1b = ws + o; o += NH;
  float* dgb = ws + o; o += NH;       // dagg / head cs / table temps

  // table: pick NT so everything fits in ws
  int NT = 1024;
  while (NT > 128) {
    size_t need = o + (size_t)NLAY * (NT + 1) * HD * 2;
    if (need * sizeof(float) <= ws_size) break;
    NT >>= 1;
  }
  const int NN = NT + 1;
  const float hstep = FCUT / (float)NT;
  const float inv_h = (float)NT / FCUT;
  float* T = ws + o; o += (size_t)NLAY * NN * HD * 2;   // [L][node][ch]{val,der}

  hipMemsetAsync(dd, 0, N_EDGES * sizeof(float), stream);
  hipMemsetAsync(out, 0, (size_t)(NMOL + 3 * N_ATOMS) * sizeof(float), stream);

  geom_k<<<(N_EDGES + 255) / 256, 256, 0, stream>>>(pos, row, col, dist);

  // ---------------- CSR build (both directions) ----------------
  {
    const int EB = (N_EDGES + 255) / 256;
    hipMemsetAsync(cur0, 0, N_ATOMS * sizeof(int), stream);
    hipMemsetAsync(cur1, 0, N_ATOMS * sizeof(int), stream);
    hist_k<<<EB, 256, 0, stream>>>(col, cur0);
    hist_k<<<EB, 256, 0, stream>>>(row, cur1);
    scan_k<<<1, 256, 0, stream>>>(cur0, cptr);
    scan_k<<<1, 256, 0, stream>>>(cur1, rptr);
    hipMemcpyAsync(cur0, cptr, N_ATOMS * sizeof(int), hipMemcpyDeviceToDevice, stream);
    hipMemcpyAsync(cur1, rptr, N_ATOMS * sizeof(int), hipMemcpyDeviceToDevice, stream);
    scat_col_k<<<EB, 256, 0, stream>>>(row, col, dist, cur0, cother, cdist);
    scat_row_k<<<EB, 256, 0, stream>>>(row, col, dist, cur1, rother, reid, rdist);
  }

  // ---------------- build filter tables (all 4 layers) ----------------
  {
    const size_t LNH = (size_t)NN * HD;
    float* Anode  = agg;
    float* dAnode = agg + LNH;
    float* t1 = dgb;
    float* u  = g0b;
    float* s  = g1b;
    float* sp = hA;
    nodeA_k<<<((int)LNH + 255) / 256, 256, 0, stream>>>(Anode, dAnode, NN, hstep);
    dim3 gB(nblk(NN), NLAY);
    gemm128b_k<<<gB, 256, 0, stream>>>(Anode, 0, mlp_w1, (size_t)HD*HD,
                                       mlp_b1, HD, t1, LNH, NN);
    gemm128b_k<<<gB, 256, 0, stream>>>(dAnode, 0, mlp_w1, (size_t)HD*HD,
                                       nullptr, 0, u, LNH, NN);
    int tot = (int)(NLAY * LNH);
    nodeact_k<<<(tot + 255) / 256, 256, 0, stream>>>(t1, u, s, sp, tot);
    float* P0 = dgb;
    float* D0 = g0b;
    gemm128b_k<<<gB, 256, 0, stream>>>(s, LNH, mlp_w2, (size_t)HD*HD,
                                       mlp_b2, HD, P0, LNH, NN);
    gemm128b_k<<<gB, 256, 0, stream>>>(sp, LNH, mlp_w2, (size_t)HD*HD,
                                       nullptr, 0, D0, LNH, NN);
    nodecomb_k<<<(tot + 255) / 256, 256, 0, stream>>>(P0, D0, T, NN, hstep);
  }

  h0_k<<<(N_ATOMS * HD + 255) / 256, 256, 0, stream>>>(emb, z, hA);

  const int AB = (N_ATOMS + 3) / 4;
  const int GB = nblk(N_ATOMS);

  // ---------------- forward ----------------
  float* hcur = hA;
  float* hnxt = hB;
  for (int i = 0; i < NLAY; i++) {
    const float* l1 = lin1_w + (size_t)i * HD * HD;
    const float* l2 = lin2_w + (size_t)i * HD * HD;
    const float* l2b = lin2_b + (size_t)i * HD;
    const float* bw = blk_w + (size_t)i * HD * HD;
    const float* bb = blk_b + (size_t)i * HD;
    const float* Tl = T + (size_t)i * NN * HD * 2;

    gemm128_k<0,false><<<GB, 256, 0, stream>>>(hcur, l1, nullptr, nullptr, hxb[i], N_ATOMS);
    gath_fwd_k<<<AB, 256, 0, stream>>>(cptr, cother, cdist, Tl, hxb[i], agg, inv_h, hstep);
    ftail_k<<<GB, 256, 0, stream>>>(agg, l2, l2b, bw, bb, hcur, vbuf[i], hnxt, N_ATOMS);
    float* tmp = hcur; hcur = hnxt; hnxt = tmp;
  }

  // ---------------- head ----------------
  float* cs = dgb;   // [N_ATOMS,64] scratch, dgb free here
  head1_k<<<GB, 256, 0, stream>>>(hcur, hw1, hb1, hw2, hb2, batch, out, cs);
  head2_k<<<GB, 256, 0, stream>>>(cs, hw1, g0b, N_ATOMS);

  // ---------------- backward ----------------
  float* gcur = g0b;
  float* gnxt = g1b;
  for (int i = NLAY - 1; i >= 0; i--) {
    const float* l1 = lin1_w + (size_t)i * HD * HD;
    const float* l2 = lin2_w + (size_t)i * HD * HD;
    const float* bw = blk_w + (size_t)i * HD * HD;
    const float* Tl = T + (size_t)i * NN * HD * 2;

    bhead_k<<<GB, 256, 0, stream>>>(gcur, bw, vbuf[i], l2, dgb, N_ATOMS);
    gath_bwd_k<<<AB, 256, 0, stream>>>(rptr, rother, reid, rdist, Tl, dgb, hxb[i], agg, dd, inv_h, hstep);
    if (i > 0) {
      gemm128_k<1,true><<<GB, 256, 0, stream>>>(agg, l1, nullptr, gcur, gnxt, N_ATOMS);
      float* tmp = gcur; gcur = gnxt; gnxt = tmp;
    }
  }

  force_k<<<(N_EDGES + 255) / 256, 256, 0, stream>>>(row, col, pos, dist, dd, out + NMOL);
}

// Round 5
// 1307.336 us; speedup vs baseline: 6.1336x; 1.0863x over previous
//
#include <hip/hip_runtime.h>

#define HD 128

constexpr int N_ATOMS = 20000;
constexpr int N_EDGES = 320000;
constexpr int NLAY   = 4;
constexpr int NMOL   = 200;
constexpr float FCUT  = 5.0f;
constexpr float DELTA = FCUT / 127.0f;
constexpr float GCOEFF = -0.5f / (DELTA * DELTA);
constexpr float PI_F  = 3.14159265358979323846f;
constexpr float LN2F  = 0.6931471805599453f;

__device__ __forceinline__ float sspf(float x) {
  return fmaxf(x, 0.0f) + log1pf(expf(-fabsf(x))) - LN2F;
}
__device__ __forceinline__ float sigmf(float x) {
  return 1.0f / (1.0f + expf(-x));
}

// ------------------------------------------------------------------
// small elementwise kernels
// ------------------------------------------------------------------

__global__ __launch_bounds__(256) void geom_k(
    const float* __restrict__ pos, const int* __restrict__ row,
    const int* __restrict__ col, float* __restrict__ dist)
{
  int e = blockIdx.x * 256 + threadIdx.x;
  if (e >= N_EDGES) return;
  int r = row[e], c = col[e];
  float dx = pos[3*r+0] - pos[3*c+0];
  float dy = pos[3*r+1] - pos[3*c+1];
  float dz = pos[3*r+2] - pos[3*c+2];
  dist[e] = sqrtf(dx*dx + dy*dy + dz*dz);
}

__global__ __launch_bounds__(256) void h0_k(
    const float* __restrict__ emb, const int* __restrict__ z,
    float* __restrict__ h0)
{
  int i = blockIdx.x * 256 + threadIdx.x;
  if (i >= N_ATOMS * HD) return;
  int n = i >> 7, k = i & 127;
  h0[i] = emb[z[n] * HD + k];
}

// ------------------------------------------------------------------
// CSR build: histogram, scan, scatter
// ------------------------------------------------------------------
__global__ __launch_bounds__(256) void hist_k(
    const int* __restrict__ idx, int* __restrict__ cnt)
{
  int e = blockIdx.x * 256 + threadIdx.x;
  if (e >= N_EDGES) return;
  atomicAdd(&cnt[idx[e]], 1);
}

__global__ __launch_bounds__(256) void scan_k(
    const int* __restrict__ cnt, int* __restrict__ ptr)
{
  constexpr int CH = 79;  // 256*79 = 20224 >= 20001
  __shared__ int part[256];
  int t = threadIdx.x;
  int base = t * CH;
  int s = 0;
  for (int i = 0; i < CH; i++) {
    int idx = base + i;
    if (idx < N_ATOMS) s += cnt[idx];
  }
  part[t] = s;
  __syncthreads();
  for (int off = 1; off < 256; off <<= 1) {
    int u = (t >= off) ? part[t - off] : 0;
    __syncthreads();
    part[t] += u;
    __syncthreads();
  }
  int run = part[t] - s;
  for (int i = 0; i < CH; i++) {
    int idx = base + i;
    if (idx > N_ATOMS) break;
    ptr[idx] = run;
    if (idx < N_ATOMS) run += cnt[idx];
  }
}

// CSR by row (backward + force): also records edge -> row-slot map
__global__ __launch_bounds__(256) void scat_row_k(
    const int* __restrict__ row, const int* __restrict__ col,
    const float* __restrict__ dist, int* __restrict__ cur,
    int* __restrict__ rother, float* __restrict__ rdist,
    int* __restrict__ slotof)
{
  int e = blockIdx.x * 256 + threadIdx.x;
  if (e >= N_EDGES) return;
  int p = atomicAdd(&cur[row[e]], 1);
  rother[p] = col[e];
  rdist[p] = dist[e];
  slotof[e] = p;
}

// CSR by col (forward + force): stores row-slot of the edge
__global__ __launch_bounds__(256) void scat_col_k(
    const int* __restrict__ row, const int* __restrict__ col,
    const float* __restrict__ dist, int* __restrict__ cur,
    int* __restrict__ cother, float* __restrict__ cdist,
    const int* __restrict__ slotof, int* __restrict__ cslot)
{
  int e = blockIdx.x * 256 + threadIdx.x;
  if (e >= N_EDGES) return;
  int p = atomicAdd(&cur[col[e]], 1);
  cother[p] = row[e];
  cdist[p] = dist[e];
  cslot[p] = slotof[e];
}

// ------------------------------------------------------------------
// table build
// ------------------------------------------------------------------
__global__ __launch_bounds__(256) void nodeA_k(
    float* __restrict__ A, float* __restrict__ dA, int nnode, float hstep)
{
  int i = blockIdx.x * 256 + threadIdx.x;
  if (i >= nnode * HD) return;
  int node = i >> 7, g = i & 127;
  float d = (float)node * hstep;
  float t = d - (float)g * DELTA;
  float a = expf(GCOEFF * t * t);
  A[i] = a;
  dA[i] = a * 2.0f * GCOEFF * t;
}

__global__ __launch_bounds__(256) void nodeact_k(
    const float* __restrict__ t1, const float* __restrict__ u,
    float* __restrict__ s, float* __restrict__ sp, int total)
{
  int i = blockIdx.x * 256 + threadIdx.x;
  if (i >= total) return;
  float x = t1[i];
  s[i] = sspf(x);
  sp[i] = sigmf(x) * u[i];
}

__global__ __launch_bounds__(256) void nodecomb_k(
    const float* __restrict__ P0, const float* __restrict__ D0,
    float* __restrict__ T, int nnode, float hstep)
{
  int i = blockIdx.x * 256 + threadIdx.x;
  int total = NLAY * nnode * HD;
  if (i >= total) return;
  int rem = i % (nnode * HD);
  int node = rem >> 7;
  float d = (float)node * hstep;
  float C  = 0.5f * cosf(d * (PI_F / FCUT)) + 0.5f;
  float Cp = -0.5f * sinf(d * (PI_F / FCUT)) * (PI_F / FCUT);
  float p = P0[i], q = D0[i];
  T[(size_t)i * 2 + 0] = p * C;
  T[(size_t)i * 2 + 1] = q * C + p * Cp;
}

// ------------------------------------------------------------------
// generic fp32 GEMM: C[M,128] = epi( A[M,128] @ B(^T) + bias )
// EPI: 0: acc+bias   1: acc+bias+EP1
// ------------------------------------------------------------------
template<int EPI, bool BT>
__global__ __launch_bounds__(256) void gemm128_k(
    const float* __restrict__ A, const float* __restrict__ B,
    const float* __restrict__ bias, const float* __restrict__ EP1,
    float* __restrict__ C, int M)
{
  __shared__ float As[16][68];
  __shared__ float Bs[16][132];
  int t = threadIdx.x;
  int tx = t & 15, ty = t >> 4;
  int m0 = blockIdx.x * 64;

  float acc[4][8];
#pragma unroll
  for (int r = 0; r < 4; r++)
#pragma unroll
    for (int c = 0; c < 8; c++) acc[r][c] = 0.0f;

  for (int k0 = 0; k0 < HD; k0 += 16) {
    {
      int rrow = t >> 2;
      int kg = (t & 3) * 4;
      int gm = m0 + rrow;
      float4 av = make_float4(0.f, 0.f, 0.f, 0.f);
      if (gm < M) av = *(const float4*)(A + (size_t)gm * HD + k0 + kg);
      As[kg+0][rrow] = av.x; As[kg+1][rrow] = av.y;
      As[kg+2][rrow] = av.z; As[kg+3][rrow] = av.w;
    }
    if (!BT) {
#pragma unroll
      for (int it = 0; it < 2; it++) {
        int f4 = t + it * 256;
        int kk = f4 >> 5;
        int n4 = (f4 & 31) * 4;
        float4 bv = *(const float4*)(B + (size_t)(k0 + kk) * HD + n4);
        *(float4*)&Bs[kk][n4] = bv;
      }
    } else {
#pragma unroll
      for (int it = 0; it < 2; it++) {
        int idx = t + it * 256;
        int n = idx >> 2;
        int kg = (idx & 3) * 4;
        float4 bv = *(const float4*)(B + (size_t)n * HD + k0 + kg);
        Bs[kg+0][n] = bv.x; Bs[kg+1][n] = bv.y;
        Bs[kg+2][n] = bv.z; Bs[kg+3][n] = bv.w;
      }
    }
    __syncthreads();
#pragma unroll
    for (int kk = 0; kk < 16; kk++) {
      float a[4], b[8];
#pragma unroll
      for (int r = 0; r < 4; r++) a[r] = As[kk][ty * 4 + r];
#pragma unroll
      for (int c = 0; c < 8; c++) b[c] = Bs[kk][tx * 8 + c];
#pragma unroll
      for (int r = 0; r < 4; r++)
#pragma unroll
        for (int c = 0; c < 8; c++) acc[r][c] = fmaf(a[r], b[c], acc[r][c]);
    }
    __syncthreads();
  }

  int n0 = tx * 8;
  float bv[8];
#pragma unroll
  for (int c = 0; c < 8; c++) bv[c] = bias ? bias[n0 + c] : 0.0f;
#pragma unroll
  for (int r = 0; r < 4; r++) {
    int gm = m0 + ty * 4 + r;
    if (gm >= M) continue;
    float out[8];
#pragma unroll
    for (int c = 0; c < 8; c++) {
      float x = acc[r][c] + bv[c];
      if (EPI == 1) x += EP1[(size_t)gm * HD + n0 + c];
      out[c] = x;
    }
    *(float4*)(C + (size_t)gm * HD + n0)     = *(float4*)&out[0];
    *(float4*)(C + (size_t)gm * HD + n0 + 4) = *(float4*)&out[4];
  }
}

// batched (over blockIdx.y = layer) plain GEMM for table build
__global__ __launch_bounds__(256) void gemm128b_k(
    const float* __restrict__ A, size_t astride,
    const float* __restrict__ B, size_t bstride,
    const float* __restrict__ bias, size_t biasstride,
    float* __restrict__ C, size_t cstride, int M)
{
  int l = blockIdx.y;
  A += (size_t)l * astride;
  B += (size_t)l * bstride;
  if (bias) bias += (size_t)l * biasstride;
  C += (size_t)l * cstride;

  __shared__ float As[16][68];
  __shared__ float Bs[16][132];
  int t = threadIdx.x;
  int tx = t & 15, ty = t >> 4;
  int m0 = blockIdx.x * 64;

  float acc[4][8];
#pragma unroll
  for (int r = 0; r < 4; r++)
#pragma unroll
    for (int c = 0; c < 8; c++) acc[r][c] = 0.0f;

  for (int k0 = 0; k0 < HD; k0 += 16) {
    {
      int rrow = t >> 2;
      int kg = (t & 3) * 4;
      int gm = m0 + rrow;
      float4 av = make_float4(0.f, 0.f, 0.f, 0.f);
      if (gm < M) av = *(const float4*)(A + (size_t)gm * HD + k0 + kg);
      As[kg+0][rrow] = av.x; As[kg+1][rrow] = av.y;
      As[kg+2][rrow] = av.z; As[kg+3][rrow] = av.w;
    }
#pragma unroll
    for (int it = 0; it < 2; it++) {
      int f4 = t + it * 256;
      int kk = f4 >> 5;
      int n4 = (f4 & 31) * 4;
      float4 bv = *(const float4*)(B + (size_t)(k0 + kk) * HD + n4);
      *(float4*)&Bs[kk][n4] = bv;
    }
    __syncthreads();
#pragma unroll
    for (int kk = 0; kk < 16; kk++) {
      float a[4], b[8];
#pragma unroll
      for (int r = 0; r < 4; r++) a[r] = As[kk][ty * 4 + r];
#pragma unroll
      for (int c = 0; c < 8; c++) b[c] = Bs[kk][tx * 8 + c];
#pragma unroll
      for (int r = 0; r < 4; r++)
#pragma unroll
        for (int c = 0; c < 8; c++) acc[r][c] = fmaf(a[r], b[c], acc[r][c]);
    }
    __syncthreads();
  }

  int n0 = tx * 8;
  float bv[8];
#pragma unroll
  for (int c = 0; c < 8; c++) bv[c] = bias ? bias[n0 + c] : 0.0f;
#pragma unroll
  for (int r = 0; r < 4; r++) {
    int gm = m0 + ty * 4 + r;
    if (gm >= M) continue;
    float out[8];
#pragma unroll
    for (int c = 0; c < 8; c++) out[c] = acc[r][c] + bv[c];
    *(float4*)(C + (size_t)gm * HD + n0)     = *(float4*)&out[0];
    *(float4*)(C + (size_t)gm * HD + n0 + 4) = *(float4*)&out[4];
  }
}

// ------------------------------------------------------------------
// fused fwd tail: V = agg@l2 + l2b (store), h' = h + ssp(V)@bw + bb
// ------------------------------------------------------------------
__global__ __launch_bounds__(256) void ftail_k(
    const float* __restrict__ agg, const float* __restrict__ l2,
    const float* __restrict__ l2b, const float* __restrict__ bw,
    const float* __restrict__ bb, const float* __restrict__ h,
    float* __restrict__ vbuf, float* __restrict__ hout, int M)
{
  __shared__ float As[16][68];
  __shared__ float Bs[16][132];
  __shared__ float Ss[64][132];
  int t = threadIdx.x;
  int tx = t & 15, ty = t >> 4;
  int m0 = blockIdx.x * 64;

  float acc[4][8];
#pragma unroll
  for (int r = 0; r < 4; r++)
#pragma unroll
    for (int c = 0; c < 8; c++) acc[r][c] = 0.0f;

  for (int k0 = 0; k0 < HD; k0 += 16) {
    {
      int rrow = t >> 2;
      int kg = (t & 3) * 4;
      int gm = m0 + rrow;
      float4 av = make_float4(0.f, 0.f, 0.f, 0.f);
      if (gm < M) av = *(const float4*)(agg + (size_t)gm * HD + k0 + kg);
      As[kg+0][rrow] = av.x; As[kg+1][rrow] = av.y;
      As[kg+2][rrow] = av.z; As[kg+3][rrow] = av.w;
    }
#pragma unroll
    for (int it = 0; it < 2; it++) {
      int f4 = t + it * 256;
      int kk = f4 >> 5;
      int n4 = (f4 & 31) * 4;
      float4 bv = *(const float4*)(l2 + (size_t)(k0 + kk) * HD + n4);
      *(float4*)&Bs[kk][n4] = bv;
    }
    __syncthreads();
#pragma unroll
    for (int kk = 0; kk < 16; kk++) {
      float a[4], b[8];
#pragma unroll
      for (int r = 0; r < 4; r++) a[r] = As[kk][ty * 4 + r];
#pragma unroll
      for (int c = 0; c < 8; c++) b[c] = Bs[kk][tx * 8 + c];
#pragma unroll
      for (int r = 0; r < 4; r++)
#pragma unroll
        for (int c = 0; c < 8; c++) acc[r][c] = fmaf(a[r], b[c], acc[r][c]);
    }
    __syncthreads();
  }

  int n0 = tx * 8;
  {
    float l2bv[8];
#pragma unroll
    for (int c = 0; c < 8; c++) l2bv[c] = l2b[n0 + c];
#pragma unroll
    for (int r = 0; r < 4; r++) {
      int lr = ty * 4 + r;
      int gm = m0 + lr;
      float vv[8];
#pragma unroll
      for (int c = 0; c < 8; c++) {
        float x = acc[r][c] + l2bv[c];
        vv[c] = x;
        Ss[lr][n0 + c] = sspf(x);
      }
      if (gm < M) {
        *(float4*)(vbuf + (size_t)gm * HD + n0)     = *(float4*)&vv[0];
        *(float4*)(vbuf + (size_t)gm * HD + n0 + 4) = *(float4*)&vv[4];
      }
    }
  }
  __syncthreads();

#pragma unroll
  for (int r = 0; r < 4; r++)
#pragma unroll
    for (int c = 0; c < 8; c++) acc[r][c] = 0.0f;

  for (int k0 = 0; k0 < HD; k0 += 16) {
#pragma unroll
    for (int it = 0; it < 2; it++) {
      int f4 = t + it * 256;
      int kk = f4 >> 5;
      int n4 = (f4 & 31) * 4;
      float4 bv = *(const float4*)(bw + (size_t)(k0 + kk) * HD + n4);
      *(float4*)&Bs[kk][n4] = bv;
    }
    __syncthreads();
#pragma unroll
    for (int kk = 0; kk < 16; kk++) {
      float a[4], b[8];
#pragma unroll
      for (int r = 0; r < 4; r++) a[r] = Ss[ty * 4 + r][k0 + kk];
#pragma unroll
      for (int c = 0; c < 8; c++) b[c] = Bs[kk][tx * 8 + c];
#pragma unroll
      for (int r = 0; r < 4; r++)
#pragma unroll
        for (int c = 0; c < 8; c++) acc[r][c] = fmaf(a[r], b[c], acc[r][c]);
    }
    __syncthreads();
  }

  {
    float bbv[8];
#pragma unroll
    for (int c = 0; c < 8; c++) bbv[c] = bb[n0 + c];
#pragma unroll
    for (int r = 0; r < 4; r++) {
      int gm = m0 + ty * 4 + r;
      if (gm >= M) continue;
      float ov[8];
      float4 h0v = *(const float4*)(h + (size_t)gm * HD + n0);
      float4 h1v = *(const float4*)(h + (size_t)gm * HD + n0 + 4);
      ov[0] = acc[r][0] + bbv[0] + h0v.x;
      ov[1] = acc[r][1] + bbv[1] + h0v.y;
      ov[2] = acc[r][2] + bbv[2] + h0v.z;
      ov[3] = acc[r][3] + bbv[3] + h0v.w;
      ov[4] = acc[r][4] + bbv[4] + h1v.x;
      ov[5] = acc[r][5] + bbv[5] + h1v.y;
      ov[6] = acc[r][6] + bbv[6] + h1v.z;
      ov[7] = acc[r][7] + bbv[7] + h1v.w;
      *(float4*)(hout + (size_t)gm * HD + n0)     = *(float4*)&ov[0];
      *(float4*)(hout + (size_t)gm * HD + n0 + 4) = *(float4*)&ov[4];
    }
  }
}

// ------------------------------------------------------------------
// fused bwd head: dv = (g@bw^T)*sigm(v), dagg = dv@l2^T
// ------------------------------------------------------------------
__global__ __launch_bounds__(256) void bhead_k(
    const float* __restrict__ g, const float* __restrict__ bw,
    const float* __restrict__ v, const float* __restrict__ l2,
    float* __restrict__ dagg, int M)
{
  __shared__ float As[16][68];
  __shared__ float Bs[16][132];
  __shared__ float Ss[64][132];
  int t = threadIdx.x;
  int tx = t & 15, ty = t >> 4;
  int m0 = blockIdx.x * 64;

  float acc[4][8];
#pragma unroll
  for (int r = 0; r < 4; r++)
#pragma unroll
    for (int c = 0; c < 8; c++) acc[r][c] = 0.0f;

  for (int k0 = 0; k0 < HD; k0 += 16) {
    {
      int rrow = t >> 2;
      int kg = (t & 3) * 4;
      int gm = m0 + rrow;
      float4 av = make_float4(0.f, 0.f, 0.f, 0.f);
      if (gm < M) av = *(const float4*)(g + (size_t)gm * HD + k0 + kg);
      As[kg+0][rrow] = av.x; As[kg+1][rrow] = av.y;
      As[kg+2][rrow] = av.z; As[kg+3][rrow] = av.w;
    }
#pragma unroll
    for (int it = 0; it < 2; it++) {
      int idx = t + it * 256;
      int n = idx >> 2;
      int kg = (idx & 3) * 4;
      float4 bv = *(const float4*)(bw + (size_t)n * HD + k0 + kg);
      Bs[kg+0][n] = bv.x; Bs[kg+1][n] = bv.y;
      Bs[kg+2][n] = bv.z; Bs[kg+3][n] = bv.w;
    }
    __syncthreads();
#pragma unroll
    for (int kk = 0; kk < 16; kk++) {
      float a[4], b[8];
#pragma unroll
      for (int r = 0; r < 4; r++) a[r] = As[kk][ty * 4 + r];
#pragma unroll
      for (int c = 0; c < 8; c++) b[c] = Bs[kk][tx * 8 + c];
#pragma unroll
      for (int r = 0; r < 4; r++)
#pragma unroll
        for (int c = 0; c < 8; c++) acc[r][c] = fmaf(a[r], b[c], acc[r][c]);
    }
    __syncthreads();
  }

  int n0 = tx * 8;
#pragma unroll
  for (int r = 0; r < 4; r++) {
    int lr = ty * 4 + r;
    int gm = m0 + lr;
    float4 v0v = make_float4(0.f,0.f,0.f,0.f), v1v = make_float4(0.f,0.f,0.f,0.f);
    if (gm < M) {
      v0v = *(const float4*)(v + (size_t)gm * HD + n0);
      v1v = *(const float4*)(v + (size_t)gm * HD + n0 + 4);
    }
    Ss[lr][n0 + 0] = acc[r][0] * sigmf(v0v.x);
    Ss[lr][n0 + 1] = acc[r][1] * sigmf(v0v.y);
    Ss[lr][n0 + 2] = acc[r][2] * sigmf(v0v.z);
    Ss[lr][n0 + 3] = acc[r][3] * sigmf(v0v.w);
    Ss[lr][n0 + 4] = acc[r][4] * sigmf(v1v.x);
    Ss[lr][n0 + 5] = acc[r][5] * sigmf(v1v.y);
    Ss[lr][n0 + 6] = acc[r][6] * sigmf(v1v.z);
    Ss[lr][n0 + 7] = acc[r][7] * sigmf(v1v.w);
  }
  __syncthreads();

#pragma unroll
  for (int r = 0; r < 4; r++)
#pragma unroll
    for (int c = 0; c < 8; c++) acc[r][c] = 0.0f;

  for (int k0 = 0; k0 < HD; k0 += 16) {
#pragma unroll
    for (int it = 0; it < 2; it++) {
      int idx = t + it * 256;
      int n = idx >> 2;
      int kg = (idx & 3) * 4;
      float4 bv = *(const float4*)(l2 + (size_t)n * HD + k0 + kg);
      Bs[kg+0][n] = bv.x; Bs[kg+1][n] = bv.y;
      Bs[kg+2][n] = bv.z; Bs[kg+3][n] = bv.w;
    }
    __syncthreads();
#pragma unroll
    for (int kk = 0; kk < 16; kk++) {
      float a[4], b[8];
#pragma unroll
      for (int r = 0; r < 4; r++) a[r] = Ss[ty * 4 + r][k0 + kk];
#pragma unroll
      for (int c = 0; c < 8; c++) b[c] = Bs[kk][tx * 8 + c];
#pragma unroll
      for (int r = 0; r < 4; r++)
#pragma unroll
        for (int c = 0; c < 8; c++) acc[r][c] = fmaf(a[r], b[c], acc[r][c]);
    }
    __syncthreads();
  }

#pragma unroll
  for (int r = 0; r < 4; r++) {
    int gm = m0 + ty * 4 + r;
    if (gm >= M) continue;
    *(float4*)(dagg + (size_t)gm * HD + n0)     = *(float4*)&acc[r][0];
    *(float4*)(dagg + (size_t)gm * HD + n0 + 4) = *(float4*)&acc[r][4];
  }
}

// ------------------------------------------------------------------
// forward gather: agg[a] = sum_in hx[src] * P(d); 32 lanes x 4ch,
// two half-waves split the edge list
// ------------------------------------------------------------------
__global__ __launch_bounds__(256) void gath_fwd_k(
    const int* __restrict__ cptr, const int* __restrict__ cother,
    const float* __restrict__ cdist, const float* __restrict__ T,
    const float* __restrict__ hx, float* __restrict__ agg,
    float inv_h, float hstep)
{
  int a = blockIdx.x * 4 + (threadIdx.x >> 6);
  if (a >= N_ATOMS) return;
  int half = (threadIdx.x >> 5) & 1;
  int ch = (threadIdx.x & 31) * 4;
  int beg = cptr[a], end = cptr[a + 1];
  float s0 = 0.f, s1 = 0.f, s2 = 0.f, s3 = 0.f;
  for (int j = beg + half; j < end; j += 2) {
    int other = cother[j];
    float d = cdist[j];
    float fi = d * inv_h;
    int i0 = (int)fi;
    float t = fi - (float)i0;
    float t2 = t * t, t3 = t2 * t;
    float a00 = 2.f*t3 - 3.f*t2 + 1.f;
    float a10 = (t3 - 2.f*t2 + t) * hstep;
    float a01 = 3.f*t2 - 2.f*t3;
    float a11 = (t3 - t2) * hstep;
    const float* tp = T + ((size_t)i0 * HD + ch) * 2;
    float4 q0a = *(const float4*)(tp);
    float4 q0b = *(const float4*)(tp + 4);
    float4 q1a = *(const float4*)(tp + 2 * HD);
    float4 q1b = *(const float4*)(tp + 2 * HD + 4);
    float4 hv = *(const float4*)(hx + (size_t)other * HD + ch);
    float v0 = a00*q0a.x + a10*q0a.y + a01*q1a.x + a11*q1a.y;
    float v1 = a00*q0a.z + a10*q0a.w + a01*q1a.z + a11*q1a.w;
    float v2 = a00*q0b.x + a10*q0b.y + a01*q1b.x + a11*q1b.y;
    float v3 = a00*q0b.z + a10*q0b.w + a01*q1b.z + a11*q1b.w;
    s0 = fmaf(hv.x, v0, s0);
    s1 = fmaf(hv.y, v1, s1);
    s2 = fmaf(hv.z, v2, s2);
    s3 = fmaf(hv.w, v3, s3);
  }
  s0 += __shfl_xor(s0, 32, 64);
  s1 += __shfl_xor(s1, 32, 64);
  s2 += __shfl_xor(s2, 32, 64);
  s3 += __shfl_xor(s3, 32, 64);
  if (half == 0)
    *(float4*)(agg + (size_t)a * HD + ch) = make_float4(s0, s1, s2, s3);
}

// ------------------------------------------------------------------
// backward gather: dhx[a] = sum_out dagg[dst]*P;
// ddslot[j] += <dagg,hx[a]*P'>  (row-CSR slot-indexed, no scatter)
// ------------------------------------------------------------------
__global__ __launch_bounds__(256) void gath_bwd_k(
    const int* __restrict__ rptr, const int* __restrict__ rother,
    const float* __restrict__ rdist, const float* __restrict__ T,
    const float* __restrict__ dagg, const float* __restrict__ hx,
    float* __restrict__ dhx, float* __restrict__ ddslot,
    float inv_h, float hstep)
{
  int a = blockIdx.x * 4 + (threadIdx.x >> 6);
  if (a >= N_ATOMS) return;
  int half = (threadIdx.x >> 5) & 1;
  int l32 = threadIdx.x & 31;
  int ch = l32 * 4;
  int beg = rptr[a], end = rptr[a + 1];
  float4 hv = *(const float4*)(hx + (size_t)a * HD + ch);
  float s0 = 0.f, s1 = 0.f, s2 = 0.f, s3 = 0.f;
  for (int j = beg + half; j < end; j += 2) {
    int other = rother[j];
    float d = rdist[j];
    float fi = d * inv_h;
    int i0 = (int)fi;
    float t = fi - (float)i0;
    float t2 = t * t, t3 = t2 * t;
    float a00 = 2.f*t3 - 3.f*t2 + 1.f;
    float a10 = (t3 - 2.f*t2 + t) * hstep;
    float a01 = 3.f*t2 - 2.f*t3;
    float a11 = (t3 - t2) * hstep;
    float b00 = (6.f*t2 - 6.f*t) * inv_h;
    float b10 = 3.f*t2 - 4.f*t + 1.f;
    float b01 = -b00;
    float b11 = 3.f*t2 - 2.f*t;
    const float* tp = T + ((size_t)i0 * HD + ch) * 2;
    float4 q0a = *(const float4*)(tp);
    float4 q0b = *(const float4*)(tp + 4);
    float4 q1a = *(const float4*)(tp + 2 * HD);
    float4 q1b = *(const float4*)(tp + 2 * HD + 4);
    float4 da = *(const float4*)(dagg + (size_t)other * HD + ch);
    float v0 = a00*q0a.x + a10*q0a.y + a01*q1a.x + a11*q1a.y;
    float v1 = a00*q0a.z + a10*q0a.w + a01*q1a.z + a11*q1a.w;
    float v2 = a00*q0b.x + a10*q0b.y + a01*q1b.x + a11*q1b.y;
    float v3 = a00*q0b.z + a10*q0b.w + a01*q1b.z + a11*q1b.w;
    float g0 = b00*q0a.x + b10*q0a.y + b01*q1a.x + b11*q1a.y;
    float g1 = b00*q0a.z + b10*q0a.w + b01*q1a.z + b11*q1a.w;
    float g2 = b00*q0b.x + b10*q0b.y + b01*q1b.x + b11*q1b.y;
    float g3 = b00*q0b.z + b10*q0b.w + b01*q1b.z + b11*q1b.w;
    s0 = fmaf(da.x, v0, s0);
    s1 = fmaf(da.y, v1, s1);
    s2 = fmaf(da.z, v2, s2);
    s3 = fmaf(da.w, v3, s3);
    float dot = da.x*hv.x*g0 + da.y*hv.y*g1 + da.z*hv.z*g2 + da.w*hv.w*g3;
#pragma unroll
    for (int off = 16; off > 0; off >>= 1) dot += __shfl_down(dot, off, 32);
    if (l32 == 0) ddslot[j] += dot;
  }
  s0 += __shfl_xor(s0, 32, 64);
  s1 += __shfl_xor(s1, 32, 64);
  s2 += __shfl_xor(s2, 32, 64);
  s3 += __shfl_xor(s3, 32, 64);
  if (half == 0)
    *(float4*)(dhx + (size_t)a * HD + ch) = make_float4(s0, s1, s2, s3);
}

// ------------------------------------------------------------------
// head part 1: s = h4@hw1 + hb1; energy; cs = sigm(s)*hw2
// ------------------------------------------------------------------
__global__ __launch_bounds__(256) void head1_k(
    const float* __restrict__ h4, const float* __restrict__ hw1,
    const float* __restrict__ hb1, const float* __restrict__ hw2,
    const float* __restrict__ hb2, const int* __restrict__ batch,
    float* __restrict__ energy, float* __restrict__ cs)
{
  __shared__ float As[16][68];
  __shared__ float Bs[16][68];
  __shared__ float red[64][17];
  int t = threadIdx.x;
  int tx = t & 15, ty = t >> 4;
  int m0 = blockIdx.x * 64;

  float acc[4][4];
#pragma unroll
  for (int r = 0; r < 4; r++)
#pragma unroll
    for (int c = 0; c < 4; c++) acc[r][c] = 0.0f;

  for (int k0 = 0; k0 < HD; k0 += 16) {
    {
      int rrow = t >> 2;
      int kg = (t & 3) * 4;
      int gm = m0 + rrow;
      float4 av = make_float4(0.f, 0.f, 0.f, 0.f);
      if (gm < N_ATOMS) av = *(const float4*)(h4 + (size_t)gm * HD + k0 + kg);
      As[kg+0][rrow] = av.x; As[kg+1][rrow] = av.y;
      As[kg+2][rrow] = av.z; As[kg+3][rrow] = av.w;
    }
    {
      int kk = t >> 4;
      int n4 = (t & 15) * 4;
      float4 bv = *(const float4*)(hw1 + (size_t)(k0 + kk) * 64 + n4);
      *(float4*)&Bs[kk][n4] = bv;
    }
    __syncthreads();
#pragma unroll
    for (int kk = 0; kk < 16; kk++) {
      float a[4], b[4];
#pragma unroll
      for (int r = 0; r < 4; r++) a[r] = As[kk][ty * 4 + r];
#pragma unroll
      for (int c = 0; c < 4; c++) b[c] = Bs[kk][tx * 4 + c];
#pragma unroll
      for (int r = 0; r < 4; r++)
#pragma unroll
        for (int c = 0; c < 4; c++) acc[r][c] = fmaf(a[r], b[c], acc[r][c]);
    }
    __syncthreads();
  }

  int n0 = tx * 4;
  float b1v[4], w2v[4];
#pragma unroll
  for (int c = 0; c < 4; c++) { b1v[c] = hb1[n0 + c]; w2v[c] = hw2[n0 + c]; }
  float hb2v = hb2[0];

#pragma unroll
  for (int r = 0; r < 4; r++) {
    int gm = m0 + ty * 4 + r;
    float p = 0.0f;
    float c4[4];
#pragma unroll
    for (int c = 0; c < 4; c++) {
      float x = acc[r][c] + b1v[c];
      p += sspf(x) * w2v[c];
      c4[c] = sigmf(x) * w2v[c];
    }
    if (gm < N_ATOMS)
      *(float4*)(cs + (size_t)gm * 64 + n0) = *(float4*)&c4[0];
    red[ty * 4 + r][tx] = p;
  }
  __syncthreads();
  if (t < 64) {
    int gm = m0 + t;
    if (gm < N_ATOMS) {
      float s = hb2v;
#pragma unroll
      for (int j = 0; j < 16; j++) s += red[t][j];
      atomicAdd(&energy[batch[gm]], s);
    }
  }
}

// ------------------------------------------------------------------
// head part 2: gh = cs @ hw1^T   (M x 128, K = 64)
// ------------------------------------------------------------------
__global__ __launch_bounds__(256) void head2_k(
    const float* __restrict__ cs, const float* __restrict__ hw1,
    float* __restrict__ gh, int M)
{
  __shared__ float As[16][68];
  __shared__ float Bs[16][132];
  int t = threadIdx.x;
  int tx = t & 15, ty = t >> 4;
  int m0 = blockIdx.x * 64;

  float acc[4][8];
#pragma unroll
  for (int r = 0; r < 4; r++)
#pragma unroll
    for (int c = 0; c < 8; c++) acc[r][c] = 0.0f;

  for (int j0 = 0; j0 < 64; j0 += 16) {
    {
      int rrow = t >> 2;
      int jg = (t & 3) * 4;
      int gm = m0 + rrow;
      float4 av = make_float4(0.f, 0.f, 0.f, 0.f);
      if (gm < M) av = *(const float4*)(cs + (size_t)gm * 64 + j0 + jg);
      As[jg+0][rrow] = av.x; As[jg+1][rrow] = av.y;
      As[jg+2][rrow] = av.z; As[jg+3][rrow] = av.w;
    }
#pragma unroll
    for (int it = 0; it < 2; it++) {
      int idx = t + it * 256;
      int n = idx >> 2;
      int jg = (idx & 3) * 4;
      float4 bv = *(const float4*)(hw1 + (size_t)n * 64 + j0 + jg);
      Bs[jg+0][n] = bv.x; Bs[jg+1][n] = bv.y;
      Bs[jg+2][n] = bv.z; Bs[jg+3][n] = bv.w;
    }
    __syncthreads();
#pragma unroll
    for (int kk = 0; kk < 16; kk++) {
      float a[4], b[8];
#pragma unroll
      for (int r = 0; r < 4; r++) a[r] = As[kk][ty * 4 + r];
#pragma unroll
      for (int c = 0; c < 8; c++) b[c] = Bs[kk][tx * 8 + c];
#pragma unroll
      for (int r = 0; r < 4; r++)
#pragma unroll
        for (int c = 0; c < 8; c++) acc[r][c] = fmaf(a[r], b[c], acc[r][c]);
    }
    __syncthreads();
  }

  int n0 = tx * 8;
#pragma unroll
  for (int r = 0; r < 4; r++) {
    int gm = m0 + ty * 4 + r;
    if (gm >= M) continue;
    *(float4*)(gh + (size_t)gm * HD + n0)     = *(float4*)&acc[r][0];
    *(float4*)(gh + (size_t)gm * HD + n0 + 4) = *(float4*)&acc[r][4];
  }
}

// ------------------------------------------------------------------
// force gather: one thread per atom, both CSR directions, no atomics
// force[a] = -sum_{incident e} ddslot(e) * (pos[a]-pos[other]) / d
// ------------------------------------------------------------------
__global__ __launch_bounds__(256) void forceg_k(
    const int* __restrict__ rptr, const int* __restrict__ rother,
    const float* __restrict__ rdist,
    const int* __restrict__ cptr, const int* __restrict__ cother,
    const float* __restrict__ cdist, const int* __restrict__ cslot,
    const float* __restrict__ ddslot, const float* __restrict__ pos,
    float* __restrict__ force)
{
  int a = blockIdx.x * 256 + threadIdx.x;
  if (a >= N_ATOMS) return;
  float px = pos[3*a+0], py = pos[3*a+1], pz = pos[3*a+2];
  float fx = 0.f, fy = 0.f, fz = 0.f;
  int beg = rptr[a], end = rptr[a+1];
  for (int j = beg; j < end; j++) {
    int o = rother[j];
    float w = ddslot[j] / rdist[j];
    fx -= w * (px - pos[3*o+0]);
    fy -= w * (py - pos[3*o+1]);
    fz -= w * (pz - pos[3*o+2]);
  }
  beg = cptr[a]; end = cptr[a+1];
  for (int j = beg; j < end; j++) {
    int o = cother[j];
    float w = ddslot[cslot[j]] / cdist[j];
    fx -= w * (px - pos[3*o+0]);
    fy -= w * (py - pos[3*o+1]);
    fz -= w * (pz - pos[3*o+2]);
  }
  force[3*a+0] = fx;
  force[3*a+1] = fy;
  force[3*a+2] = fz;
}

// ------------------------------------------------------------------
// host launch
// ------------------------------------------------------------------
static inline int nblk(int m) { return (m + 63) / 64; }

extern "C" void kernel_launch(void* const* d_in, const int* in_sizes, int n_in,
                              void* d_out, int out_size, void* d_ws, size_t ws_size,
                              hipStream_t stream)
{
  const float* pos   = (const float*)d_in[0];
  const int*   z     = (const int*)d_in[1];
  const int*   batch = (const int*)d_in[2];
  const int*   eidx  = (const int*)d_in[3];
  const float* emb   = (const float*)d_in[4];
  const float* mlp_w1 = (const float*)d_in[5];
  const float* mlp_b1 = (const float*)d_in[6];
  const float* mlp_w2 = (const float*)d_in[7];
  const float* mlp_b2 = (const float*)d_in[8];
  const float* lin1_w = (const float*)d_in[9];
  const float* lin2_w = (const float*)d_in[10];
  const float* lin2_b = (const float*)d_in[11];
  const float* blk_w  = (const float*)d_in[12];
  const float* blk_b  = (const float*)d_in[13];
  const float* hw1 = (const float*)d_in[14];
  const float* hb1 = (const float*)d_in[15];
  const float* hw2 = (const float*)d_in[16];
  const float* hb2 = (const float*)d_in[17];

  float* out = (float*)d_out;          // [NMOL] energies ++ [N,3] forces
  float* ws  = (float*)d_ws;

  const int* row = eidx;
  const int* col = eidx + N_EDGES;

  const size_t NH = (size_t)N_ATOMS * HD;
  size_t o = 0;
  float* dist   = ws + o; o += N_EDGES;
  float* ddslot = ws + o; o += N_EDGES;
  int* cptr   = (int*)(ws + o); o += N_ATOMS + 1;
  int* rptr   = (int*)(ws + o); o += N_ATOMS + 1;
  int* cother = (int*)(ws + o); o += N_EDGES;
  int* rother = (int*)(ws + o); o += N_EDGES;
  int* slotof = (int*)(ws + o); o += N_EDGES;
  int* cslot  = (int*)(ws + o); o += N_EDGES;
  float* cdist = ws + o; o += N_EDGES;
  float* rdist = ws + o; o += N_EDGES;
  int* cur0   = (int*)(ws + o); o += N_ATOMS;
  int* cur1   = (int*)(ws + o); o += N_ATOMS;
  float* hxb[4];
  for (int i = 0; i < 4; i++) { hxb[i] = ws + o; o += NH; }
  float* vbuf[4];
  for (int i = 0; i < 4; i++) { vbuf[i] = ws + o; o += NH; }
  float* hA  = ws + o; o += NH;
  float* hB  = ws + o; o += NH;
  float* agg = ws + o; o += NH;       // fwd agg / bwd dhx / table temps
  float* g0b = ws + o; o += NH;
  float* g1b = ws + o; o += NH;
  float* dgb = ws + o; o += NH;       // dagg / head cs / table temps

  // table: pick NT so everything fits in ws
  int NT = 1024;
  while (NT > 128) {
    size_t need = o + (size_t)NLAY * (NT + 1) * HD * 2;
    if (need * sizeof(float) <= ws_size) break;
    NT >>= 1;
  }
  const int NN = NT + 1;
  const float hstep = FCUT / (float)NT;
  const float inv_h = (float)NT / FCUT;
  float* T = ws + o; o += (size_t)NLAY * NN * HD * 2;   // [L][node][ch]{val,der}

  hipMemsetAsync(ddslot, 0, N_EDGES * sizeof(float), stream);
  hipMemsetAsync(out, 0, (size_t)NMOL * sizeof(float), stream);

  geom_k<<<(N_EDGES + 255) / 256, 256, 0, stream>>>(pos, row, col, dist);

  // ---------------- CSR build (both directions) ----------------
  {
    const int EB = (N_EDGES + 255) / 256;
    hipMemsetAsync(cur0, 0, N_ATOMS * sizeof(int), stream);
    hipMemsetAsync(cur1, 0, N_ATOMS * sizeof(int), stream);
    hist_k<<<EB, 256, 0, stream>>>(col, cur0);
    hist_k<<<EB, 256, 0, stream>>>(row, cur1);
    scan_k<<<1, 256, 0, stream>>>(cur0, cptr);
    scan_k<<<1, 256, 0, stream>>>(cur1, rptr);
    hipMemcpyAsync(cur0, cptr, N_ATOMS * sizeof(int), hipMemcpyDeviceToDevice, stream);
    hipMemcpyAsync(cur1, rptr, N_ATOMS * sizeof(int), hipMemcpyDeviceToDevice, stream);
    scat_row_k<<<EB, 256, 0, stream>>>(row, col, dist, cur1, rother, rdist, slotof);
    scat_col_k<<<EB, 256, 0, stream>>>(row, col, dist, cur0, cother, cdist, slotof, cslot);
  }

  // ---------------- build filter tables (all 4 layers) ----------------
  {
    const size_t LNH = (size_t)NN * HD;
    float* Anode  = agg;
    float* dAnode = agg + LNH;
    float* t1 = dgb;
    float* u  = g0b;
    float* s  = g1b;
    float* sp = hA;
    nodeA_k<<<((int)LNH + 255) / 256, 256, 0, stream>>>(Anode, dAnode, NN, hstep);
    dim3 gB(nblk(NN), NLAY);
    gemm128b_k<<<gB, 256, 0, stream>>>(Anode, 0, mlp_w1, (size_t)HD*HD,
                                       mlp_b1, HD, t1, LNH, NN);
    gemm128b_k<<<gB, 256, 0, stream>>>(dAnode, 0, mlp_w1, (size_t)HD*HD,
                                       nullptr, 0, u, LNH, NN);
    int tot = (int)(NLAY * LNH);
    nodeact_k<<<(tot + 255) / 256, 256, 0, stream>>>(t1, u, s, sp, tot);
    float* P0 = dgb;
    float* D0 = g0b;
    gemm128b_k<<<gB, 256, 0, stream>>>(s, LNH, mlp_w2, (size_t)HD*HD,
                                       mlp_b2, HD, P0, LNH, NN);
    gemm128b_k<<<gB, 256, 0, stream>>>(sp, LNH, mlp_w2, (size_t)HD*HD,
                                       nullptr, 0, D0, LNH, NN);
    nodecomb_k<<<(tot + 255) / 256, 256, 0, stream>>>(P0, D0, T, NN, hstep);
  }

  h0_k<<<(N_ATOMS * HD + 255) / 256, 256, 0, stream>>>(emb, z, hA);

  const int AB = (N_ATOMS + 3) / 4;
  const int GB = nblk(N_ATOMS);

  // ---------------- forward ----------------
  float* hcur = hA;
  float* hnxt = hB;
  for (int i = 0; i < NLAY; i++) {
    const float* l1 = lin1_w + (size_t)i * HD * HD;
    const float* l2 = lin2_w + (size_t)i * HD * HD;
    const float* l2b = lin2_b + (size_t)i * HD;
    const float* bw = blk_w + (size_t)i * HD * HD;
    const float* bb = blk_b + (size_t)i * HD;
    const float* Tl = T + (size_t)i * NN * HD * 2;

    gemm128_k<0,false><<<GB, 256, 0, stream>>>(hcur, l1, nullptr, nullptr, hxb[i], N_ATOMS);
    gath_fwd_k<<<AB, 256, 0, stream>>>(cptr, cother, cdist, Tl, hxb[i], agg, inv_h, hstep);
    ftail_k<<<GB, 256, 0, stream>>>(agg, l2, l2b, bw, bb, hcur, vbuf[i], hnxt, N_ATOMS);
    float* tmp = hcur; hcur = hnxt; hnxt = tmp;
  }

  // ---------------- head ----------------
  float* cs = dgb;   // [N_ATOMS,64] scratch, dgb free here
  head1_k<<<GB, 256, 0, stream>>>(hcur, hw1, hb1, hw2, hb2, batch, out, cs);
  head2_k<<<GB, 256, 0, stream>>>(cs, hw1, g0b, N_ATOMS);

  // ---------------- backward ----------------
  float* gcur = g0b;
  float* gnxt = g1b;
  for (int i = NLAY - 1; i >= 0; i--) {
    const float* l1 = lin1_w + (size_t)i * HD * HD;
    const float* l2 = lin2_w + (size_t)i * HD * HD;
    const float* bw = blk_w + (size_t)i * HD * HD;
    const float* Tl = T + (size_t)i * NN * HD * 2;

    bhead_k<<<GB, 256, 0, stream>>>(gcur, bw, vbuf[i], l2, dgb, N_ATOMS);
    gath_bwd_k<<<AB, 256, 0, stream>>>(rptr, rother, rdist, Tl, dgb, hxb[i], agg, ddslot, inv_h, hstep);
    if (i > 0) {
      gemm128_k<1,true><<<GB, 256, 0, stream>>>(agg, l1, nullptr, gcur, gnxt, N_ATOMS);
      float* tmp = gcur; gcur = gnxt; gnxt = tmp;
    }
  }

  forceg_k<<<(N_ATOMS + 255) / 256, 256, 0, stream>>>(
      rptr, rother, rdist, cptr, cother, cdist, cslot, ddslot, pos, out + NMOL);
}

// Round 6
// 1168.975 us; speedup vs baseline: 6.8596x; 1.1184x over previous
//
#include <hip/hip_runtime.h>

#define HD 128

constexpr int N_ATOMS = 20000;
constexpr int N_EDGES = 320000;
constexpr int NLAY   = 4;
constexpr int NMOL   = 200;
constexpr float FCUT  = 5.0f;
constexpr float DELTA = FCUT / 127.0f;
constexpr float GCOEFF = -0.5f / (DELTA * DELTA);
constexpr float PI_F  = 3.14159265358979323846f;
constexpr float LN2F  = 0.6931471805599453f;

__device__ __forceinline__ float sspf(float x) {
  return fmaxf(x, 0.0f) + log1pf(expf(-fabsf(x))) - LN2F;
}
__device__ __forceinline__ float sigmf(float x) {
  return 1.0f / (1.0f + expf(-x));
}

// bf16 pack/unpack (round-to-nearest-even)
__device__ __forceinline__ unsigned bfpack(float a, float b) {
  unsigned ua = __float_as_uint(a);
  unsigned ub = __float_as_uint(b);
  ua = (ua + 0x7FFFu + ((ua >> 16) & 1u)) >> 16;
  ub = (ub + 0x7FFFu + ((ub >> 16) & 1u)) >> 16;
  return (ub << 16) | ua;
}
__device__ __forceinline__ float bflo(unsigned p) { return __uint_as_float(p << 16); }
__device__ __forceinline__ float bfhi(unsigned p) { return __uint_as_float(p & 0xFFFF0000u); }

// ------------------------------------------------------------------
// small elementwise kernels
// ------------------------------------------------------------------

__global__ __launch_bounds__(256) void geom_k(
    const float* __restrict__ pos, const int* __restrict__ row,
    const int* __restrict__ col, float* __restrict__ dist)
{
  int e = blockIdx.x * 256 + threadIdx.x;
  if (e >= N_EDGES) return;
  int r = row[e], c = col[e];
  float dx = pos[3*r+0] - pos[3*c+0];
  float dy = pos[3*r+1] - pos[3*c+1];
  float dz = pos[3*r+2] - pos[3*c+2];
  dist[e] = sqrtf(dx*dx + dy*dy + dz*dz);
}

__global__ __launch_bounds__(256) void h0_k(
    const float* __restrict__ emb, const int* __restrict__ z,
    float* __restrict__ h0)
{
  int i = blockIdx.x * 256 + threadIdx.x;
  if (i >= N_ATOMS * HD) return;
  int n = i >> 7, k = i & 127;
  h0[i] = emb[z[n] * HD + k];
}

// ------------------------------------------------------------------
// CSR build: histogram, scan, scatter
// ------------------------------------------------------------------
__global__ __launch_bounds__(256) void hist_k(
    const int* __restrict__ idx, int* __restrict__ cnt)
{
  int e = blockIdx.x * 256 + threadIdx.x;
  if (e >= N_EDGES) return;
  atomicAdd(&cnt[idx[e]], 1);
}

__global__ __launch_bounds__(256) void scan_k(
    const int* __restrict__ cnt, int* __restrict__ ptr)
{
  constexpr int CH = 79;  // 256*79 = 20224 >= 20001
  __shared__ int part[256];
  int t = threadIdx.x;
  int base = t * CH;
  int s = 0;
  for (int i = 0; i < CH; i++) {
    int idx = base + i;
    if (idx < N_ATOMS) s += cnt[idx];
  }
  part[t] = s;
  __syncthreads();
  for (int off = 1; off < 256; off <<= 1) {
    int u = (t >= off) ? part[t - off] : 0;
    __syncthreads();
    part[t] += u;
    __syncthreads();
  }
  int run = part[t] - s;
  for (int i = 0; i < CH; i++) {
    int idx = base + i;
    if (idx > N_ATOMS) break;
    ptr[idx] = run;
    if (idx < N_ATOMS) run += cnt[idx];
  }
}

// CSR by row (backward + force): also records edge -> row-slot map
__global__ __launch_bounds__(256) void scat_row_k(
    const int* __restrict__ row, const int* __restrict__ col,
    const float* __restrict__ dist, int* __restrict__ cur,
    int* __restrict__ rother, float* __restrict__ rdist,
    int* __restrict__ slotof)
{
  int e = blockIdx.x * 256 + threadIdx.x;
  if (e >= N_EDGES) return;
  int p = atomicAdd(&cur[row[e]], 1);
  rother[p] = col[e];
  rdist[p] = dist[e];
  slotof[e] = p;
}

// CSR by col (forward + force): stores row-slot of the edge
__global__ __launch_bounds__(256) void scat_col_k(
    const int* __restrict__ row, const int* __restrict__ col,
    const float* __restrict__ dist, int* __restrict__ cur,
    int* __restrict__ cother, float* __restrict__ cdist,
    const int* __restrict__ slotof, int* __restrict__ cslot)
{
  int e = blockIdx.x * 256 + threadIdx.x;
  if (e >= N_EDGES) return;
  int p = atomicAdd(&cur[col[e]], 1);
  cother[p] = row[e];
  cdist[p] = dist[e];
  cslot[p] = slotof[e];
}

// ------------------------------------------------------------------
// table build
// ------------------------------------------------------------------
__global__ __launch_bounds__(256) void nodeA_k(
    float* __restrict__ A, float* __restrict__ dA, int nnode, float hstep)
{
  int i = blockIdx.x * 256 + threadIdx.x;
  if (i >= nnode * HD) return;
  int node = i >> 7, g = i & 127;
  float d = (float)node * hstep;
  float t = d - (float)g * DELTA;
  float a = expf(GCOEFF * t * t);
  A[i] = a;
  dA[i] = a * 2.0f * GCOEFF * t;
}

__global__ __launch_bounds__(256) void nodeact_k(
    const float* __restrict__ t1, const float* __restrict__ u,
    float* __restrict__ s, float* __restrict__ sp, int total)
{
  int i = blockIdx.x * 256 + threadIdx.x;
  if (i >= total) return;
  float x = t1[i];
  s[i] = sspf(x);
  sp[i] = sigmf(x) * u[i];
}

// T[l][node][ch] = bf16 pair { P0*C (lo) , D0*C + P0*C' (hi) }
__global__ __launch_bounds__(256) void nodecomb_k(
    const float* __restrict__ P0, const float* __restrict__ D0,
    unsigned* __restrict__ T, int nnode, float hstep)
{
  int i = blockIdx.x * 256 + threadIdx.x;
  int total = NLAY * nnode * HD;
  if (i >= total) return;
  int rem = i % (nnode * HD);
  int node = rem >> 7;
  float d = (float)node * hstep;
  float C  = 0.5f * cosf(d * (PI_F / FCUT)) + 0.5f;
  float Cp = -0.5f * sinf(d * (PI_F / FCUT)) * (PI_F / FCUT);
  float p = P0[i], q = D0[i];
  T[i] = bfpack(p * C, q * C + p * Cp);
}

// ------------------------------------------------------------------
// generic fp32 GEMM: C[M,128] = epi( A[M,128] @ B(^T) + bias )
// EPI: 0: acc+bias   1: acc+bias+EP1
// OB : output bf16 (packed pairs) instead of fp32
// ------------------------------------------------------------------
template<int EPI, bool BT, bool OB>
__global__ __launch_bounds__(256) void gemm128_k(
    const float* __restrict__ A, const float* __restrict__ B,
    const float* __restrict__ bias, const float* __restrict__ EP1,
    float* __restrict__ C, int M)
{
  __shared__ float As[16][68];
  __shared__ float Bs[16][132];
  int t = threadIdx.x;
  int tx = t & 15, ty = t >> 4;
  int m0 = blockIdx.x * 64;

  float acc[4][8];
#pragma unroll
  for (int r = 0; r < 4; r++)
#pragma unroll
    for (int c = 0; c < 8; c++) acc[r][c] = 0.0f;

  for (int k0 = 0; k0 < HD; k0 += 16) {
    {
      int rrow = t >> 2;
      int kg = (t & 3) * 4;
      int gm = m0 + rrow;
      float4 av = make_float4(0.f, 0.f, 0.f, 0.f);
      if (gm < M) av = *(const float4*)(A + (size_t)gm * HD + k0 + kg);
      As[kg+0][rrow] = av.x; As[kg+1][rrow] = av.y;
      As[kg+2][rrow] = av.z; As[kg+3][rrow] = av.w;
    }
    if (!BT) {
#pragma unroll
      for (int it = 0; it < 2; it++) {
        int f4 = t + it * 256;
        int kk = f4 >> 5;
        int n4 = (f4 & 31) * 4;
        float4 bv = *(const float4*)(B + (size_t)(k0 + kk) * HD + n4);
        *(float4*)&Bs[kk][n4] = bv;
      }
    } else {
#pragma unroll
      for (int it = 0; it < 2; it++) {
        int idx = t + it * 256;
        int n = idx >> 2;
        int kg = (idx & 3) * 4;
        float4 bv = *(const float4*)(B + (size_t)n * HD + k0 + kg);
        Bs[kg+0][n] = bv.x; Bs[kg+1][n] = bv.y;
        Bs[kg+2][n] = bv.z; Bs[kg+3][n] = bv.w;
      }
    }
    __syncthreads();
#pragma unroll
    for (int kk = 0; kk < 16; kk++) {
      float a[4], b[8];
#pragma unroll
      for (int r = 0; r < 4; r++) a[r] = As[kk][ty * 4 + r];
#pragma unroll
      for (int c = 0; c < 8; c++) b[c] = Bs[kk][tx * 8 + c];
#pragma unroll
      for (int r = 0; r < 4; r++)
#pragma unroll
        for (int c = 0; c < 8; c++) acc[r][c] = fmaf(a[r], b[c], acc[r][c]);
    }
    __syncthreads();
  }

  int n0 = tx * 8;
  float bv[8];
#pragma unroll
  for (int c = 0; c < 8; c++) bv[c] = bias ? bias[n0 + c] : 0.0f;
#pragma unroll
  for (int r = 0; r < 4; r++) {
    int gm = m0 + ty * 4 + r;
    if (gm >= M) continue;
    float out[8];
#pragma unroll
    for (int c = 0; c < 8; c++) {
      float x = acc[r][c] + bv[c];
      if (EPI == 1) x += EP1[(size_t)gm * HD + n0 + c];
      out[c] = x;
    }
    if (OB) {
      uint4 pk;
      pk.x = bfpack(out[0], out[1]);
      pk.y = bfpack(out[2], out[3]);
      pk.z = bfpack(out[4], out[5]);
      pk.w = bfpack(out[6], out[7]);
      *(uint4*)((unsigned*)C + (size_t)gm * 64 + tx * 4) = pk;
    } else {
      *(float4*)(C + (size_t)gm * HD + n0)     = *(float4*)&out[0];
      *(float4*)(C + (size_t)gm * HD + n0 + 4) = *(float4*)&out[4];
    }
  }
}

// batched (over blockIdx.y = layer) plain GEMM for table build
__global__ __launch_bounds__(256) void gemm128b_k(
    const float* __restrict__ A, size_t astride,
    const float* __restrict__ B, size_t bstride,
    const float* __restrict__ bias, size_t biasstride,
    float* __restrict__ C, size_t cstride, int M)
{
  int l = blockIdx.y;
  A += (size_t)l * astride;
  B += (size_t)l * bstride;
  if (bias) bias += (size_t)l * biasstride;
  C += (size_t)l * cstride;

  __shared__ float As[16][68];
  __shared__ float Bs[16][132];
  int t = threadIdx.x;
  int tx = t & 15, ty = t >> 4;
  int m0 = blockIdx.x * 64;

  float acc[4][8];
#pragma unroll
  for (int r = 0; r < 4; r++)
#pragma unroll
    for (int c = 0; c < 8; c++) acc[r][c] = 0.0f;

  for (int k0 = 0; k0 < HD; k0 += 16) {
    {
      int rrow = t >> 2;
      int kg = (t & 3) * 4;
      int gm = m0 + rrow;
      float4 av = make_float4(0.f, 0.f, 0.f, 0.f);
      if (gm < M) av = *(const float4*)(A + (size_t)gm * HD + k0 + kg);
      As[kg+0][rrow] = av.x; As[kg+1][rrow] = av.y;
      As[kg+2][rrow] = av.z; As[kg+3][rrow] = av.w;
    }
#pragma unroll
    for (int it = 0; it < 2; it++) {
      int f4 = t + it * 256;
      int kk = f4 >> 5;
      int n4 = (f4 & 31) * 4;
      float4 bv = *(const float4*)(B + (size_t)(k0 + kk) * HD + n4);
      *(float4*)&Bs[kk][n4] = bv;
    }
    __syncthreads();
#pragma unroll
    for (int kk = 0; kk < 16; kk++) {
      float a[4], b[8];
#pragma unroll
      for (int r = 0; r < 4; r++) a[r] = As[kk][ty * 4 + r];
#pragma unroll
      for (int c = 0; c < 8; c++) b[c] = Bs[kk][tx * 8 + c];
#pragma unroll
      for (int r = 0; r < 4; r++)
#pragma unroll
        for (int c = 0; c < 8; c++) acc[r][c] = fmaf(a[r], b[c], acc[r][c]);
    }
    __syncthreads();
  }

  int n0 = tx * 8;
  float bv[8];
#pragma unroll
  for (int c = 0; c < 8; c++) bv[c] = bias ? bias[n0 + c] : 0.0f;
#pragma unroll
  for (int r = 0; r < 4; r++) {
    int gm = m0 + ty * 4 + r;
    if (gm >= M) continue;
    float out[8];
#pragma unroll
    for (int c = 0; c < 8; c++) out[c] = acc[r][c] + bv[c];
    *(float4*)(C + (size_t)gm * HD + n0)     = *(float4*)&out[0];
    *(float4*)(C + (size_t)gm * HD + n0 + 4) = *(float4*)&out[4];
  }
}

// ------------------------------------------------------------------
// fused fwd tail: V = agg@l2 + l2b (store), h' = h + ssp(V)@bw + bb
// ------------------------------------------------------------------
__global__ __launch_bounds__(256) void ftail_k(
    const float* __restrict__ agg, const float* __restrict__ l2,
    const float* __restrict__ l2b, const float* __restrict__ bw,
    const float* __restrict__ bb, const float* __restrict__ h,
    float* __restrict__ vbuf, float* __restrict__ hout, int M)
{
  __shared__ float As[16][68];
  __shared__ float Bs[16][132];
  __shared__ float Ss[64][132];
  int t = threadIdx.x;
  int tx = t & 15, ty = t >> 4;
  int m0 = blockIdx.x * 64;

  float acc[4][8];
#pragma unroll
  for (int r = 0; r < 4; r++)
#pragma unroll
    for (int c = 0; c < 8; c++) acc[r][c] = 0.0f;

  for (int k0 = 0; k0 < HD; k0 += 16) {
    {
      int rrow = t >> 2;
      int kg = (t & 3) * 4;
      int gm = m0 + rrow;
      float4 av = make_float4(0.f, 0.f, 0.f, 0.f);
      if (gm < M) av = *(const float4*)(agg + (size_t)gm * HD + k0 + kg);
      As[kg+0][rrow] = av.x; As[kg+1][rrow] = av.y;
      As[kg+2][rrow] = av.z; As[kg+3][rrow] = av.w;
    }
#pragma unroll
    for (int it = 0; it < 2; it++) {
      int f4 = t + it * 256;
      int kk = f4 >> 5;
      int n4 = (f4 & 31) * 4;
      float4 bv = *(const float4*)(l2 + (size_t)(k0 + kk) * HD + n4);
      *(float4*)&Bs[kk][n4] = bv;
    }
    __syncthreads();
#pragma unroll
    for (int kk = 0; kk < 16; kk++) {
      float a[4], b[8];
#pragma unroll
      for (int r = 0; r < 4; r++) a[r] = As[kk][ty * 4 + r];
#pragma unroll
      for (int c = 0; c < 8; c++) b[c] = Bs[kk][tx * 8 + c];
#pragma unroll
      for (int r = 0; r < 4; r++)
#pragma unroll
        for (int c = 0; c < 8; c++) acc[r][c] = fmaf(a[r], b[c], acc[r][c]);
    }
    __syncthreads();
  }

  int n0 = tx * 8;
  {
    float l2bv[8];
#pragma unroll
    for (int c = 0; c < 8; c++) l2bv[c] = l2b[n0 + c];
#pragma unroll
    for (int r = 0; r < 4; r++) {
      int lr = ty * 4 + r;
      int gm = m0 + lr;
      float vv[8];
#pragma unroll
      for (int c = 0; c < 8; c++) {
        float x = acc[r][c] + l2bv[c];
        vv[c] = x;
        Ss[lr][n0 + c] = sspf(x);
      }
      if (gm < M) {
        *(float4*)(vbuf + (size_t)gm * HD + n0)     = *(float4*)&vv[0];
        *(float4*)(vbuf + (size_t)gm * HD + n0 + 4) = *(float4*)&vv[4];
      }
    }
  }
  __syncthreads();

#pragma unroll
  for (int r = 0; r < 4; r++)
#pragma unroll
    for (int c = 0; c < 8; c++) acc[r][c] = 0.0f;

  for (int k0 = 0; k0 < HD; k0 += 16) {
#pragma unroll
    for (int it = 0; it < 2; it++) {
      int f4 = t + it * 256;
      int kk = f4 >> 5;
      int n4 = (f4 & 31) * 4;
      float4 bv = *(const float4*)(bw + (size_t)(k0 + kk) * HD + n4);
      *(float4*)&Bs[kk][n4] = bv;
    }
    __syncthreads();
#pragma unroll
    for (int kk = 0; kk < 16; kk++) {
      float a[4], b[8];
#pragma unroll
      for (int r = 0; r < 4; r++) a[r] = Ss[ty * 4 + r][k0 + kk];
#pragma unroll
      for (int c = 0; c < 8; c++) b[c] = Bs[kk][tx * 8 + c];
#pragma unroll
      for (int r = 0; r < 4; r++)
#pragma unroll
        for (int c = 0; c < 8; c++) acc[r][c] = fmaf(a[r], b[c], acc[r][c]);
    }
    __syncthreads();
  }

  {
    float bbv[8];
#pragma unroll
    for (int c = 0; c < 8; c++) bbv[c] = bb[n0 + c];
#pragma unroll
    for (int r = 0; r < 4; r++) {
      int gm = m0 + ty * 4 + r;
      if (gm >= M) continue;
      float ov[8];
      float4 h0v = *(const float4*)(h + (size_t)gm * HD + n0);
      float4 h1v = *(const float4*)(h + (size_t)gm * HD + n0 + 4);
      ov[0] = acc[r][0] + bbv[0] + h0v.x;
      ov[1] = acc[r][1] + bbv[1] + h0v.y;
      ov[2] = acc[r][2] + bbv[2] + h0v.z;
      ov[3] = acc[r][3] + bbv[3] + h0v.w;
      ov[4] = acc[r][4] + bbv[4] + h1v.x;
      ov[5] = acc[r][5] + bbv[5] + h1v.y;
      ov[6] = acc[r][6] + bbv[6] + h1v.z;
      ov[7] = acc[r][7] + bbv[7] + h1v.w;
      *(float4*)(hout + (size_t)gm * HD + n0)     = *(float4*)&ov[0];
      *(float4*)(hout + (size_t)gm * HD + n0 + 4) = *(float4*)&ov[4];
    }
  }
}

// ------------------------------------------------------------------
// fused bwd head: dv = (g@bw^T)*sigm(v), dagg = dv@l2^T (bf16 out)
// ------------------------------------------------------------------
__global__ __launch_bounds__(256) void bhead_k(
    const float* __restrict__ g, const float* __restrict__ bw,
    const float* __restrict__ v, const float* __restrict__ l2,
    unsigned* __restrict__ dagg, int M)
{
  __shared__ float As[16][68];
  __shared__ float Bs[16][132];
  __shared__ float Ss[64][132];
  int t = threadIdx.x;
  int tx = t & 15, ty = t >> 4;
  int m0 = blockIdx.x * 64;

  float acc[4][8];
#pragma unroll
  for (int r = 0; r < 4; r++)
#pragma unroll
    for (int c = 0; c < 8; c++) acc[r][c] = 0.0f;

  for (int k0 = 0; k0 < HD; k0 += 16) {
    {
      int rrow = t >> 2;
      int kg = (t & 3) * 4;
      int gm = m0 + rrow;
      float4 av = make_float4(0.f, 0.f, 0.f, 0.f);
      if (gm < M) av = *(const float4*)(g + (size_t)gm * HD + k0 + kg);
      As[kg+0][rrow] = av.x; As[kg+1][rrow] = av.y;
      As[kg+2][rrow] = av.z; As[kg+3][rrow] = av.w;
    }
#pragma unroll
    for (int it = 0; it < 2; it++) {
      int idx = t + it * 256;
      int n = idx >> 2;
      int kg = (idx & 3) * 4;
      float4 bv = *(const float4*)(bw + (size_t)n * HD + k0 + kg);
      Bs[kg+0][n] = bv.x; Bs[kg+1][n] = bv.y;
      Bs[kg+2][n] = bv.z; Bs[kg+3][n] = bv.w;
    }
    __syncthreads();
#pragma unroll
    for (int kk = 0; kk < 16; kk++) {
      float a[4], b[8];
#pragma unroll
      for (int r = 0; r < 4; r++) a[r] = As[kk][ty * 4 + r];
#pragma unroll
      for (int c = 0; c < 8; c++) b[c] = Bs[kk][tx * 8 + c];
#pragma unroll
      for (int r = 0; r < 4; r++)
#pragma unroll
        for (int c = 0; c < 8; c++) acc[r][c] = fmaf(a[r], b[c], acc[r][c]);
    }
    __syncthreads();
  }

  int n0 = tx * 8;
#pragma unroll
  for (int r = 0; r < 4; r++) {
    int lr = ty * 4 + r;
    int gm = m0 + lr;
    float4 v0v = make_float4(0.f,0.f,0.f,0.f), v1v = make_float4(0.f,0.f,0.f,0.f);
    if (gm < M) {
      v0v = *(const float4*)(v + (size_t)gm * HD + n0);
      v1v = *(const float4*)(v + (size_t)gm * HD + n0 + 4);
    }
    Ss[lr][n0 + 0] = acc[r][0] * sigmf(v0v.x);
    Ss[lr][n0 + 1] = acc[r][1] * sigmf(v0v.y);
    Ss[lr][n0 + 2] = acc[r][2] * sigmf(v0v.z);
    Ss[lr][n0 + 3] = acc[r][3] * sigmf(v0v.w);
    Ss[lr][n0 + 4] = acc[r][4] * sigmf(v1v.x);
    Ss[lr][n0 + 5] = acc[r][5] * sigmf(v1v.y);
    Ss[lr][n0 + 6] = acc[r][6] * sigmf(v1v.z);
    Ss[lr][n0 + 7] = acc[r][7] * sigmf(v1v.w);
  }
  __syncthreads();

#pragma unroll
  for (int r = 0; r < 4; r++)
#pragma unroll
    for (int c = 0; c < 8; c++) acc[r][c] = 0.0f;

  for (int k0 = 0; k0 < HD; k0 += 16) {
#pragma unroll
    for (int it = 0; it < 2; it++) {
      int idx = t + it * 256;
      int n = idx >> 2;
      int kg = (idx & 3) * 4;
      float4 bv = *(const float4*)(l2 + (size_t)n * HD + k0 + kg);
      Bs[kg+0][n] = bv.x; Bs[kg+1][n] = bv.y;
      Bs[kg+2][n] = bv.z; Bs[kg+3][n] = bv.w;
    }
    __syncthreads();
#pragma unroll
    for (int kk = 0; kk < 16; kk++) {
      float a[4], b[8];
#pragma unroll
      for (int r = 0; r < 4; r++) a[r] = Ss[ty * 4 + r][k0 + kk];
#pragma unroll
      for (int c = 0; c < 8; c++) b[c] = Bs[kk][tx * 8 + c];
#pragma unroll
      for (int r = 0; r < 4; r++)
#pragma unroll
        for (int c = 0; c < 8; c++) acc[r][c] = fmaf(a[r], b[c], acc[r][c]);
    }
    __syncthreads();
  }

#pragma unroll
  for (int r = 0; r < 4; r++) {
    int gm = m0 + ty * 4 + r;
    if (gm >= M) continue;
    uint4 pk;
    pk.x = bfpack(acc[r][0], acc[r][1]);
    pk.y = bfpack(acc[r][2], acc[r][3]);
    pk.z = bfpack(acc[r][4], acc[r][5]);
    pk.w = bfpack(acc[r][6], acc[r][7]);
    *(uint4*)(dagg + (size_t)gm * 64 + tx * 4) = pk;
  }
}

// ------------------------------------------------------------------
// forward gather: agg[a] = sum_in hx[src] * P(d); bf16 table + hx
// ------------------------------------------------------------------
__global__ __launch_bounds__(256) void gath_fwd_k(
    const int* __restrict__ cptr, const int* __restrict__ cother,
    const float* __restrict__ cdist, const unsigned* __restrict__ T,
    const unsigned* __restrict__ hx, float* __restrict__ agg,
    float inv_h, float hstep)
{
  int a = blockIdx.x * 4 + (threadIdx.x >> 6);
  if (a >= N_ATOMS) return;
  int half = (threadIdx.x >> 5) & 1;
  int l32 = threadIdx.x & 31;
  int ch = l32 * 4;
  int beg = cptr[a], end = cptr[a + 1];
  float s0 = 0.f, s1 = 0.f, s2 = 0.f, s3 = 0.f;
  for (int j = beg + half; j < end; j += 2) {
    int other = cother[j];
    float d = cdist[j];
    float fi = d * inv_h;
    int i0 = (int)fi;
    float t = fi - (float)i0;
    float t2 = t * t, t3 = t2 * t;
    float a00 = 2.f*t3 - 3.f*t2 + 1.f;
    float a10 = (t3 - 2.f*t2 + t) * hstep;
    float a01 = 3.f*t2 - 2.f*t3;
    float a11 = (t3 - t2) * hstep;
    const unsigned* tp = T + (size_t)i0 * HD + ch;
    uint4 q0 = *(const uint4*)(tp);
    uint4 q1 = *(const uint4*)(tp + HD);
    uint2 hp = *(const uint2*)(hx + (size_t)other * 64 + l32 * 2);
    float v0 = a00*bflo(q0.x) + a10*bfhi(q0.x) + a01*bflo(q1.x) + a11*bfhi(q1.x);
    float v1 = a00*bflo(q0.y) + a10*bfhi(q0.y) + a01*bflo(q1.y) + a11*bfhi(q1.y);
    float v2 = a00*bflo(q0.z) + a10*bfhi(q0.z) + a01*bflo(q1.z) + a11*bfhi(q1.z);
    float v3 = a00*bflo(q0.w) + a10*bfhi(q0.w) + a01*bflo(q1.w) + a11*bfhi(q1.w);
    s0 = fmaf(bflo(hp.x), v0, s0);
    s1 = fmaf(bfhi(hp.x), v1, s1);
    s2 = fmaf(bflo(hp.y), v2, s2);
    s3 = fmaf(bfhi(hp.y), v3, s3);
  }
  s0 += __shfl_xor(s0, 32, 64);
  s1 += __shfl_xor(s1, 32, 64);
  s2 += __shfl_xor(s2, 32, 64);
  s3 += __shfl_xor(s3, 32, 64);
  if (half == 0)
    *(float4*)(agg + (size_t)a * HD + ch) = make_float4(s0, s1, s2, s3);
}

// ------------------------------------------------------------------
// backward gather: dhx[a] = sum_out dagg[dst]*P;
// ddslot[j] += <dagg,hx[a]*P'>   (bf16 table, hx, dagg)
// ------------------------------------------------------------------
__global__ __launch_bounds__(256) void gath_bwd_k(
    const int* __restrict__ rptr, const int* __restrict__ rother,
    const float* __restrict__ rdist, const unsigned* __restrict__ T,
    const unsigned* __restrict__ dagg, const unsigned* __restrict__ hx,
    float* __restrict__ dhx, float* __restrict__ ddslot,
    float inv_h, float hstep)
{
  int a = blockIdx.x * 4 + (threadIdx.x >> 6);
  if (a >= N_ATOMS) return;
  int half = (threadIdx.x >> 5) & 1;
  int l32 = threadIdx.x & 31;
  int ch = l32 * 4;
  int beg = rptr[a], end = rptr[a + 1];
  uint2 hp = *(const uint2*)(hx + (size_t)a * 64 + l32 * 2);
  float h0 = bflo(hp.x), h1 = bfhi(hp.x), h2 = bflo(hp.y), h3 = bfhi(hp.y);
  float s0 = 0.f, s1 = 0.f, s2 = 0.f, s3 = 0.f;
  for (int j = beg + half; j < end; j += 2) {
    int other = rother[j];
    float d = rdist[j];
    float fi = d * inv_h;
    int i0 = (int)fi;
    float t = fi - (float)i0;
    float t2 = t * t, t3 = t2 * t;
    float a00 = 2.f*t3 - 3.f*t2 + 1.f;
    float a10 = (t3 - 2.f*t2 + t) * hstep;
    float a01 = 3.f*t2 - 2.f*t3;
    float a11 = (t3 - t2) * hstep;
    float b00 = (6.f*t2 - 6.f*t) * inv_h;
    float b10 = 3.f*t2 - 4.f*t + 1.f;
    float b01 = -b00;
    float b11 = 3.f*t2 - 2.f*t;
    const unsigned* tp = T + (size_t)i0 * HD + ch;
    uint4 q0 = *(const uint4*)(tp);
    uint4 q1 = *(const uint4*)(tp + HD);
    uint2 dp = *(const uint2*)(dagg + (size_t)other * 64 + l32 * 2);
    float da0 = bflo(dp.x), da1 = bfhi(dp.x), da2 = bflo(dp.y), da3 = bfhi(dp.y);
    float v0 = a00*bflo(q0.x) + a10*bfhi(q0.x) + a01*bflo(q1.x) + a11*bfhi(q1.x);
    float v1 = a00*bflo(q0.y) + a10*bfhi(q0.y) + a01*bflo(q1.y) + a11*bfhi(q1.y);
    float v2 = a00*bflo(q0.z) + a10*bfhi(q0.z) + a01*bflo(q1.z) + a11*bfhi(q1.z);
    float v3 = a00*bflo(q0.w) + a10*bfhi(q0.w) + a01*bflo(q1.w) + a11*bfhi(q1.w);
    float g0 = b00*bflo(q0.x) + b10*bfhi(q0.x) + b01*bflo(q1.x) + b11*bfhi(q1.x);
    float g1 = b00*bflo(q0.y) + b10*bfhi(q0.y) + b01*bflo(q1.y) + b11*bfhi(q1.y);
    float g2 = b00*bflo(q0.z) + b10*bfhi(q0.z) + b01*bflo(q1.z) + b11*bfhi(q1.z);
    float g3 = b00*bflo(q0.w) + b10*bfhi(q0.w) + b01*bflo(q1.w) + b11*bfhi(q1.w);
    s0 = fmaf(da0, v0, s0);
    s1 = fmaf(da1, v1, s1);
    s2 = fmaf(da2, v2, s2);
    s3 = fmaf(da3, v3, s3);
    float dot = da0*h0*g0 + da1*h1*g1 + da2*h2*g2 + da3*h3*g3;
#pragma unroll
    for (int off = 16; off > 0; off >>= 1) dot += __shfl_down(dot, off, 32);
    if (l32 == 0) ddslot[j] += dot;
  }
  s0 += __shfl_xor(s0, 32, 64);
  s1 += __shfl_xor(s1, 32, 64);
  s2 += __shfl_xor(s2, 32, 64);
  s3 += __shfl_xor(s3, 32, 64);
  if (half == 0)
    *(float4*)(dhx + (size_t)a * HD + ch) = make_float4(s0, s1, s2, s3);
}

// ------------------------------------------------------------------
// fused head: s = h4@hw1 + hb1; ea[a] = ssp(s)@hw2 + hb2 (plain store);
// gh = (sigm(s)*hw2) @ hw1^T
// ------------------------------------------------------------------
__global__ __launch_bounds__(256) void headf_k(
    const float* __restrict__ h4, const float* __restrict__ hw1,
    const float* __restrict__ hb1, const float* __restrict__ hw2,
    const float* __restrict__ hb2, float* __restrict__ ea,
    float* __restrict__ gh)
{
  __shared__ float As[16][68];
  __shared__ float Bs[16][132];
  __shared__ float Ss[64][68];
  __shared__ float red[64][17];
  int t = threadIdx.x;
  int tx = t & 15, ty = t >> 4;
  int m0 = blockIdx.x * 64;

  // phase 1: s = h4 @ hw1 (64 cols), K = 128
  float acc4[4][4];
#pragma unroll
  for (int r = 0; r < 4; r++)
#pragma unroll
    for (int c = 0; c < 4; c++) acc4[r][c] = 0.0f;

  for (int k0 = 0; k0 < HD; k0 += 16) {
    {
      int rrow = t >> 2;
      int kg = (t & 3) * 4;
      int gm = m0 + rrow;
      float4 av = make_float4(0.f, 0.f, 0.f, 0.f);
      if (gm < N_ATOMS) av = *(const float4*)(h4 + (size_t)gm * HD + k0 + kg);
      As[kg+0][rrow] = av.x; As[kg+1][rrow] = av.y;
      As[kg+2][rrow] = av.z; As[kg+3][rrow] = av.w;
    }
    if (t < 256) {
      int kk = t >> 4;
      int n4 = (t & 15) * 4;
      float4 bv = *(const float4*)(hw1 + (size_t)(k0 + kk) * 64 + n4);
      *(float4*)&Bs[kk][n4] = bv;
    }
    __syncthreads();
#pragma unroll
    for (int kk = 0; kk < 16; kk++) {
      float a[4], b[4];
#pragma unroll
      for (int r = 0; r < 4; r++) a[r] = As[kk][ty * 4 + r];
#pragma unroll
      for (int c = 0; c < 4; c++) b[c] = Bs[kk][tx * 4 + c];
#pragma unroll
      for (int r = 0; r < 4; r++)
#pragma unroll
        for (int c = 0; c < 4; c++) acc4[r][c] = fmaf(a[r], b[c], acc4[r][c]);
    }
    __syncthreads();
  }

  {
    int n0 = tx * 4;
    float b1v[4], w2v[4];
#pragma unroll
    for (int c = 0; c < 4; c++) { b1v[c] = hb1[n0 + c]; w2v[c] = hw2[n0 + c]; }
#pragma unroll
    for (int r = 0; r < 4; r++) {
      int lr = ty * 4 + r;
      float p = 0.0f;
#pragma unroll
      for (int c = 0; c < 4; c++) {
        float x = acc4[r][c] + b1v[c];
        p += sspf(x) * w2v[c];
        Ss[lr][n0 + c] = sigmf(x) * w2v[c];
      }
      red[lr][tx] = p;
    }
  }
  __syncthreads();
  if (t < 64) {
    int gm = m0 + t;
    if (gm < N_ATOMS) {
      float s = hb2[0];
#pragma unroll
      for (int j = 0; j < 16; j++) s += red[t][j];
      ea[gm] = s;
    }
  }

  // phase 2: gh = cs @ hw1^T (128 cols), K = 64; cs in Ss
  float acc[4][8];
#pragma unroll
  for (int r = 0; r < 4; r++)
#pragma unroll
    for (int c = 0; c < 8; c++) acc[r][c] = 0.0f;

  for (int j0 = 0; j0 < 64; j0 += 16) {
#pragma unroll
    for (int it = 0; it < 2; it++) {
      int idx = t + it * 256;
      int n = idx >> 2;
      int jg = (idx & 3) * 4;
      float4 bv = *(const float4*)(hw1 + (size_t)n * 64 + j0 + jg);
      Bs[jg+0][n] = bv.x; Bs[jg+1][n] = bv.y;
      Bs[jg+2][n] = bv.z; Bs[jg+3][n] = bv.w;
    }
    __syncthreads();
#pragma unroll
    for (int kk = 0; kk < 16; kk++) {
      float a[4], b[8];
#pragma unroll
      for (int r = 0; r < 4; r++) a[r] = Ss[ty * 4 + r][j0 + kk];
#pragma unroll
      for (int c = 0; c < 8; c++) b[c] = Bs[kk][tx * 8 + c];
#pragma unroll
      for (int r = 0; r < 4; r++)
#pragma unroll
        for (int c = 0; c < 8; c++) acc[r][c] = fmaf(a[r], b[c], acc[r][c]);
    }
    __syncthreads();
  }

  int n0 = tx * 8;
#pragma unroll
  for (int r = 0; r < 4; r++) {
    int gm = m0 + ty * 4 + r;
    if (gm >= N_ATOMS) continue;
    *(float4*)(gh + (size_t)gm * HD + n0)     = *(float4*)&acc[r][0];
    *(float4*)(gh + (size_t)gm * HD + n0 + 4) = *(float4*)&acc[r][4];
  }
}

// ------------------------------------------------------------------
// per-molecule energy reduction (batch is sorted; binary search bounds)
// ------------------------------------------------------------------
__global__ __launch_bounds__(64) void ered_k(
    const int* __restrict__ batch, const float* __restrict__ ea,
    float* __restrict__ energy)
{
  int m = blockIdx.x;
  int lo = 0, hi = N_ATOMS;
  while (lo < hi) { int mid = (lo + hi) >> 1; if (batch[mid] < m) lo = mid + 1; else hi = mid; }
  int beg = lo;
  lo = beg; hi = N_ATOMS;
  while (lo < hi) { int mid = (lo + hi) >> 1; if (batch[mid] < m + 1) lo = mid + 1; else hi = mid; }
  int end = lo;
  float s = 0.0f;
  for (int i = beg + threadIdx.x; i < end; i += 64) s += ea[i];
#pragma unroll
  for (int off = 32; off > 0; off >>= 1) s += __shfl_down(s, off, 64);
  if (threadIdx.x == 0) energy[m] = s;
}

// ------------------------------------------------------------------
// force gather: 8 lanes per atom, both CSR directions, no atomics
// ------------------------------------------------------------------
__global__ __launch_bounds__(256) void forceg_k(
    const int* __restrict__ rptr, const int* __restrict__ rother,
    const float* __restrict__ rdist,
    const int* __restrict__ cptr, const int* __restrict__ cother,
    const float* __restrict__ cdist, const int* __restrict__ cslot,
    const float* __restrict__ ddslot, const float* __restrict__ pos,
    float* __restrict__ force)
{
  int idx = blockIdx.x * 256 + threadIdx.x;
  int a = idx >> 3;
  int g = idx & 7;
  if (a >= N_ATOMS) return;
  float px = pos[3*a+0], py = pos[3*a+1], pz = pos[3*a+2];
  float fx = 0.f, fy = 0.f, fz = 0.f;
  int beg = rptr[a], end = rptr[a+1];
  for (int j = beg + g; j < end; j += 8) {
    int o = rother[j];
    float w = ddslot[j] / rdist[j];
    fx -= w * (px - pos[3*o+0]);
    fy -= w * (py - pos[3*o+1]);
    fz -= w * (pz - pos[3*o+2]);
  }
  beg = cptr[a]; end = cptr[a+1];
  for (int j = beg + g; j < end; j += 8) {
    int o = cother[j];
    float w = ddslot[cslot[j]] / cdist[j];
    fx -= w * (px - pos[3*o+0]);
    fy -= w * (py - pos[3*o+1]);
    fz -= w * (pz - pos[3*o+2]);
  }
#pragma unroll
  for (int off = 4; off > 0; off >>= 1) {
    fx += __shfl_down(fx, off, 8);
    fy += __shfl_down(fy, off, 8);
    fz += __shfl_down(fz, off, 8);
  }
  if (g == 0) {
    force[3*a+0] = fx;
    force[3*a+1] = fy;
    force[3*a+2] = fz;
  }
}

// ------------------------------------------------------------------
// host launch
// ------------------------------------------------------------------
static inline int nblk(int m) { return (m + 63) / 64; }

extern "C" void kernel_launch(void* const* d_in, const int* in_sizes, int n_in,
                              void* d_out, int out_size, void* d_ws, size_t ws_size,
                              hipStream_t stream)
{
  const float* pos   = (const float*)d_in[0];
  const int*   z     = (const int*)d_in[1];
  const int*   batch = (const int*)d_in[2];
  const int*   eidx  = (const int*)d_in[3];
  const float* emb   = (const float*)d_in[4];
  const float* mlp_w1 = (const float*)d_in[5];
  const float* mlp_b1 = (const float*)d_in[6];
  const float* mlp_w2 = (const float*)d_in[7];
  const float* mlp_b2 = (const float*)d_in[8];
  const float* lin1_w = (const float*)d_in[9];
  const float* lin2_w = (const float*)d_in[10];
  const float* lin2_b = (const float*)d_in[11];
  const float* blk_w  = (const float*)d_in[12];
  const float* blk_b  = (const float*)d_in[13];
  const float* hw1 = (const float*)d_in[14];
  const float* hb1 = (const float*)d_in[15];
  const float* hw2 = (const float*)d_in[16];
  const float* hb2 = (const float*)d_in[17];

  float* out = (float*)d_out;          // [NMOL] energies ++ [N,3] forces
  float* ws  = (float*)d_ws;

  const int* row = eidx;
  const int* col = eidx + N_EDGES;

  const size_t NH = (size_t)N_ATOMS * HD;
  size_t o = 0;
  float* dist   = ws + o; o += N_EDGES;
  float* ddslot = ws + o; o += N_EDGES;
  int* cptr   = (int*)(ws + o); o += N_ATOMS + 1;
  int* rptr   = (int*)(ws + o); o += N_ATOMS + 1;
  int* cother = (int*)(ws + o); o += N_EDGES;
  int* rother = (int*)(ws + o); o += N_EDGES;
  int* slotof = (int*)(ws + o); o += N_EDGES;
  int* cslot  = (int*)(ws + o); o += N_EDGES;
  float* cdist = ws + o; o += N_EDGES;
  float* rdist = ws + o; o += N_EDGES;
  int* cur0   = (int*)(ws + o); o += N_ATOMS;
  int* cur1   = (int*)(ws + o); o += N_ATOMS;
  float* hxb[4];   // stored as bf16 pairs (uint, 64/row)
  for (int i = 0; i < 4; i++) { hxb[i] = ws + o; o += NH; }
  float* vbuf[4];
  for (int i = 0; i < 4; i++) { vbuf[i] = ws + o; o += NH; }
  float* hA  = ws + o; o += NH;
  float* hB  = ws + o; o += NH;
  float* agg = ws + o; o += NH;       // fwd agg / bwd dhx / table temps
  float* g0b = ws + o; o += NH;
  float* g1b = ws + o; o += NH;
  float* dgb = ws + o; o += NH;       // dagg(bf16) / ea / table temps

  // table: bf16 pairs, 1 uint per (node,ch)
  int NT = 1024;
  while (NT > 128) {
    size_t need = o + (size_t)NLAY * (NT + 1) * HD;
    if (need * sizeof(float) <= ws_size) break;
    NT >>= 1;
  }
  const int NN = NT + 1;
  const float hstep = FCUT / (float)NT;
  const float inv_h = (float)NT / FCUT;
  unsigned* T = (unsigned*)(ws + o); o += (size_t)NLAY * NN * HD;

  hipMemsetAsync(ddslot, 0, N_EDGES * sizeof(float), stream);

  geom_k<<<(N_EDGES + 255) / 256, 256, 0, stream>>>(pos, row, col, dist);

  // ---------------- CSR build (both directions) ----------------
  {
    const int EB = (N_EDGES + 255) / 256;
    hipMemsetAsync(cur0, 0, N_ATOMS * sizeof(int), stream);
    hipMemsetAsync(cur1, 0, N_ATOMS * sizeof(int), stream);
    hist_k<<<EB, 256, 0, stream>>>(col, cur0);
    hist_k<<<EB, 256, 0, stream>>>(row, cur1);
    scan_k<<<1, 256, 0, stream>>>(cur0, cptr);
    scan_k<<<1, 256, 0, stream>>>(cur1, rptr);
    hipMemcpyAsync(cur0, cptr, N_ATOMS * sizeof(int), hipMemcpyDeviceToDevice, stream);
    hipMemcpyAsync(cur1, rptr, N_ATOMS * sizeof(int), hipMemcpyDeviceToDevice, stream);
    scat_row_k<<<EB, 256, 0, stream>>>(row, col, dist, cur1, rother, rdist, slotof);
    scat_col_k<<<EB, 256, 0, stream>>>(row, col, dist, cur0, cother, cdist, slotof, cslot);
  }

  // ---------------- build filter tables (all 4 layers) ----------------
  {
    const size_t LNH = (size_t)NN * HD;
    float* Anode  = agg;
    float* dAnode = agg + LNH;
    float* t1 = dgb;
    float* u  = g0b;
    float* s  = g1b;
    float* sp = hA;
    nodeA_k<<<((int)LNH + 255) / 256, 256, 0, stream>>>(Anode, dAnode, NN, hstep);
    dim3 gB(nblk(NN), NLAY);
    gemm128b_k<<<gB, 256, 0, stream>>>(Anode, 0, mlp_w1, (size_t)HD*HD,
                                       mlp_b1, HD, t1, LNH, NN);
    gemm128b_k<<<gB, 256, 0, stream>>>(dAnode, 0, mlp_w1, (size_t)HD*HD,
                                       nullptr, 0, u, LNH, NN);
    int tot = (int)(NLAY * LNH);
    nodeact_k<<<(tot + 255) / 256, 256, 0, stream>>>(t1, u, s, sp, tot);
    float* P0 = dgb;
    float* D0 = g0b;
    gemm128b_k<<<gB, 256, 0, stream>>>(s, LNH, mlp_w2, (size_t)HD*HD,
                                       mlp_b2, HD, P0, LNH, NN);
    gemm128b_k<<<gB, 256, 0, stream>>>(sp, LNH, mlp_w2, (size_t)HD*HD,
                                       nullptr, 0, D0, LNH, NN);
    nodecomb_k<<<(tot + 255) / 256, 256, 0, stream>>>(P0, D0, T, NN, hstep);
  }

  h0_k<<<(N_ATOMS * HD + 255) / 256, 256, 0, stream>>>(emb, z, hA);

  const int AB = (N_ATOMS + 3) / 4;
  const int GB = nblk(N_ATOMS);

  // ---------------- forward ----------------
  float* hcur = hA;
  float* hnxt = hB;
  for (int i = 0; i < NLAY; i++) {
    const float* l1 = lin1_w + (size_t)i * HD * HD;
    const float* l2 = lin2_w + (size_t)i * HD * HD;
    const float* l2b = lin2_b + (size_t)i * HD;
    const float* bw = blk_w + (size_t)i * HD * HD;
    const float* bb = blk_b + (size_t)i * HD;
    const unsigned* Tl = T + (size_t)i * NN * HD;

    gemm128_k<0,false,true><<<GB, 256, 0, stream>>>(hcur, l1, nullptr, nullptr, hxb[i], N_ATOMS);
    gath_fwd_k<<<AB, 256, 0, stream>>>(cptr, cother, cdist, Tl, (const unsigned*)hxb[i], agg, inv_h, hstep);
    ftail_k<<<GB, 256, 0, stream>>>(agg, l2, l2b, bw, bb, hcur, vbuf[i], hnxt, N_ATOMS);
    float* tmp = hcur; hcur = hnxt; hnxt = tmp;
  }

  // ---------------- head (fused) + per-molecule energy ----------------
  float* ea = dgb;   // per-atom energy scratch; dgb free here
  headf_k<<<GB, 256, 0, stream>>>(hcur, hw1, hb1, hw2, hb2, ea, g0b);
  ered_k<<<NMOL, 64, 0, stream>>>(batch, ea, out);

  // ---------------- backward ----------------
  float* gcur = g0b;
  float* gnxt = g1b;
  for (int i = NLAY - 1; i >= 0; i--) {
    const float* l1 = lin1_w + (size_t)i * HD * HD;
    const float* l2 = lin2_w + (size_t)i * HD * HD;
    const float* bw = blk_w + (size_t)i * HD * HD;
    const unsigned* Tl = T + (size_t)i * NN * HD;

    bhead_k<<<GB, 256, 0, stream>>>(gcur, bw, vbuf[i], l2, (unsigned*)dgb, N_ATOMS);
    gath_bwd_k<<<AB, 256, 0, stream>>>(rptr, rother, rdist, Tl, (const unsigned*)dgb,
                                       (const unsigned*)hxb[i], agg, ddslot, inv_h, hstep);
    if (i > 0) {
      gemm128_k<1,true,false><<<GB, 256, 0, stream>>>(agg, l1, nullptr, gcur, gnxt, N_ATOMS);
      float* tmp = gcur; gcur = gnxt; gnxt = tmp;
    }
  }

  forceg_k<<<(N_ATOMS * 8 + 255) / 256, 256, 0, stream>>>(
      rptr, rother, rdist, cptr, cother, cdist, cslot, ddslot, pos, out + NMOL);
}